// Round 8
// baseline (503.339 us; speedup 1.0000x reference)
//
#include <hip/hip_runtime.h>
#include <cfloat>
#include <cstdint>

#define NB 32
#define NP 1024
#define NK 20
#define NPTS 32768  // NB*NP

// ---------------------------------------------------------------------------
// d2[p] = sum x^2, SINGLE sequential FMA chain (order-matched with kdist's
// per-acc chain so diagonal dist = fmaf(-2,d2p,2*d2p) = exact 0).
// ---------------------------------------------------------------------------
__global__ __launch_bounds__(256) void kd2(const float* __restrict__ x, int dim,
                                           float* __restrict__ d2) {
  int p = blockIdx.x * 256 + threadIdx.x;
  if (p >= NPTS) return;
  if (dim == 64) {
    const float4* xr = (const float4*)(x + (size_t)p * 64);
    float s = 0.f;
#pragma unroll
    for (int dq = 0; dq < 16; dq++) {
      float4 v = xr[dq];
      s = fmaf(v.x, v.x, s);
      s = fmaf(v.y, v.y, s);
      s = fmaf(v.z, v.z, s);
      s = fmaf(v.w, v.w, s);
    }
    d2[p] = s;
  } else {
    float s = 0.f;
#pragma unroll
    for (int d = 0; d < 3; d++) {
      float v = x[p * 3 + d];
      s = fmaf(v, v, s);
    }
    d2[p] = s;
  }
}

// ---------------------------------------------------------------------------
// kdist: full per-cloud distance matrix, 128x128 tile per block.
// ---------------------------------------------------------------------------
template <int DIM>
__global__ __launch_bounds__(256) void kdist(const float* __restrict__ x,
                                             const float* __restrict__ d2,
                                             int c0, float* __restrict__ D) {
  constexpr int KC = (DIM == 64) ? 32 : 3;
  __shared__ float As[KC][132];
  __shared__ float Bs[KC][132];
  const int tid = threadIdx.x;
  const int cloud = blockIdx.x >> 6;  // within chunk
  const int t = blockIdx.x & 63;
  const int tr0 = (t >> 3) * 128, tc0 = (t & 7) * 128;
  const int cb = (c0 + cloud) * 1024;
  const int tr = tid >> 4, tc = tid & 15;

  float acc[8][8];
#pragma unroll
  for (int i = 0; i < 8; i++)
#pragma unroll
    for (int j = 0; j < 8; j++) acc[i][j] = 0.f;

  for (int kc = 0; kc < DIM; kc += KC) {
    __syncthreads();
    if constexpr (DIM == 64) {
      const int row = tid >> 1, seg = tid & 1;
      const float4* sa = (const float4*)(x + (size_t)(cb + tr0 + row) * 64 + kc + seg * 16);
      const float4* sb = (const float4*)(x + (size_t)(cb + tc0 + row) * 64 + kc + seg * 16);
#pragma unroll
      for (int i = 0; i < 4; i++) {
        float4 va = sa[i];
        float4 vb = sb[i];
        const int k0 = seg * 16 + i * 4;
        As[k0 + 0][row] = va.x;
        As[k0 + 1][row] = va.y;
        As[k0 + 2][row] = va.z;
        As[k0 + 3][row] = va.w;
        Bs[k0 + 0][row] = vb.x;
        Bs[k0 + 1][row] = vb.y;
        Bs[k0 + 2][row] = vb.z;
        Bs[k0 + 3][row] = vb.w;
      }
    } else {
      if (tid < 128) {
#pragma unroll
        for (int d = 0; d < 3; d++) {
          As[d][tid] = x[(size_t)(cb + tr0 + tid) * 3 + d];
          Bs[d][tid] = x[(size_t)(cb + tc0 + tid) * 3 + d];
        }
      }
    }
    __syncthreads();
#pragma unroll
    for (int k = 0; k < KC; k++) {
      float a[8], b[8];
      *(float4*)&a[0] = *(const float4*)&As[k][tr * 8];
      *(float4*)&a[4] = *(const float4*)&As[k][tr * 8 + 4];
      *(float4*)&b[0] = *(const float4*)&Bs[k][tc * 8];
      *(float4*)&b[4] = *(const float4*)&Bs[k][tc * 8 + 4];
#pragma unroll
      for (int i = 0; i < 8; i++)
#pragma unroll
        for (int j = 0; j < 8; j++) acc[i][j] = fmaf(a[i], b[j], acc[i][j]);
    }
  }
  float d2r[8], d2c[8];
#pragma unroll
  for (int i = 0; i < 8; i++) d2r[i] = d2[cb + tr0 + tr * 8 + i];
#pragma unroll
  for (int j = 0; j < 8; j++) d2c[j] = d2[cb + tc0 + tc * 8 + j];
#pragma unroll
  for (int i = 0; i < 8; i++) {
    float o[8];
#pragma unroll
    for (int j = 0; j < 8; j++) o[j] = fmaf(-2.f, acc[i][j], d2r[i] + d2c[j]);
    float* dst = &D[(size_t)(cloud * 1024 + tr0 + tr * 8 + i) * 1024 + tc0 + tc * 8];
    *(float4*)&dst[0] = *(const float4*)&o[0];
    *(float4*)&dst[4] = *(const float4*)&o[4];
  }
}

// ---------------------------------------------------------------------------
// kselect: exact top-20 via pivot selection (keys distinct by construction).
// ---------------------------------------------------------------------------
__global__ __launch_bounds__(256) void kselect(const float* __restrict__ D,
                                               int c0, int* __restrict__ idxo) {
  __shared__ unsigned long long lw[4][64];
  const int lane = threadIdx.x & 63;
  const int sub = threadIdx.x >> 6;
  const int pchunk = blockIdx.x * 4 + sub;  // point within chunk
  const int pg = c0 * 1024 + pchunk;        // global point
  const int gbase = (pg >> 10) << 10;       // cloud base (global)

  unsigned long long key[16];
  const float4* dr = (const float4*)(D + (size_t)pchunk * 1024 + lane * 4);
#pragma unroll
  for (int i = 0; i < 4; i++) {
    float4 d4 = dr[i * 64];  // q = i*256 + lane*4 ..+3
    float dv[4] = {d4.x, d4.y, d4.z, d4.w};
#pragma unroll
    for (int j = 0; j < 4; j++) {
      unsigned int u = __float_as_uint(dv[j]);
      u ^= (((int)u >> 31) | 0x80000000u);  // sortable transform
      key[i * 4 + j] = ((unsigned long long)u << 10) | (unsigned)(i * 256 + lane * 4 + j);
    }
  }

  unsigned long long mn = key[0], mx = key[0];
#pragma unroll
  for (int i = 1; i < 16; i++) {
    mn = key[i] < mn ? key[i] : mn;
    mx = key[i] > mx ? key[i] : mx;
  }
#pragma unroll
  for (int s = 1; s < 64; s <<= 1) {
    unsigned long long a = __shfl_xor(mn, s, 64);
    unsigned long long b = __shfl_xor(mx, s, 64);
    mn = a < mn ? a : mn;
    mx = b > mx ? b : mx;
  }
  unsigned long long lo = mn, hi = mx + 1, mid = hi;
  bool found = false;
  for (int it = 0; it < 48 && !found; ++it) {
    unsigned long long m2 = lo + ((hi - lo) >> 1);
    int cnt = 0;
#pragma unroll
    for (int i = 0; i < 16; i++) cnt += (key[i] < m2) ? 1 : 0;
#pragma unroll
    for (int s = 1; s < 64; s <<= 1) cnt += __shfl_xor(cnt, s, 64);
    if (cnt < 20)
      lo = m2;
    else if (cnt > 63)
      hi = m2;
    else {
      mid = m2;
      found = true;
    }
  }

  unsigned int mask = 0;
#pragma unroll
  for (int i = 0; i < 16; i++) mask |= (key[i] < mid) ? (1u << i) : 0u;
  const int lc = __popc(mask);
  int x = lc;
#pragma unroll
  for (int s = 1; s < 64; s <<= 1) {
    int y = __shfl_up(x, s, 64);
    if (lane >= s) x += y;
  }
  int off = x - lc;                    // exclusive prefix
  const int ctot = __shfl(x, 63, 64);  // total candidates
  const int c = ctot < 64 ? ctot : 64;
  unsigned long long* w = lw[sub];
#pragma unroll
  for (int i = 0; i < 16; i++) {
    if ((mask & (1u << i)) && off < 64) {
      w[off] = key[i];
      off++;
    }
  }
  __builtin_amdgcn_wave_barrier();

  const unsigned long long K = w[lane < c ? lane : 0];
  int rank = 0;
  for (int m = 0; m < c; m++) {
    const unsigned long long Km = w[m];  // broadcast read
    rank += (K > Km) ? 1 : 0;
  }
  if (lane < c && rank < NK)
    idxo[(size_t)pg * NK + rank] = gbase + (int)(K & 1023u);
}

// ---------------------------------------------------------------------------
// FALLBACK kNN (used only if ws_size can't fit a 1-cloud distance matrix).
// ---------------------------------------------------------------------------
template <int DIM>
__global__ __launch_bounds__(256) void kknn(const float* __restrict__ x,
                                            const float* __restrict__ d2,
                                            int* __restrict__ idxo) {
  constexpr int STR = (DIM == 64) ? 68 : 4;
  __shared__ float smem[10240];
  float* tile = smem;
  float* dt = smem + 64 * STR;
  float* mD = smem;
  int* mI = (int*)(smem + 5120);

  const int tid = threadIdx.x;
  const int pt = tid & 63;
  const int qt = tid >> 6;
  const int cloud = blockIdx.x >> 4;
  const int blk = blockIdx.x & 15;
  const int p = cloud * 1024 + blk * 64 + pt;
  const int cbase = cloud * 1024;

  float xp[DIM];
#pragma unroll
  for (int d = 0; d < DIM; d++) xp[d] = x[(size_t)p * DIM + d];
  const float d2p = d2[p];

  float bd[NK];
  int bi[NK];
#pragma unroll
  for (int s = 0; s < NK; s++) {
    bd[s] = FLT_MAX;
    bi[s] = 0x7fffffff;
  }
  float wd = FLT_MAX;
  int wi = 0x7fffffff;
  int wsl = 0;

  for (int t = 0; t < 16; t++) {
    __syncthreads();
    if (tid < 64) {
#pragma unroll
      for (int d = 0; d < DIM; d++) tile[tid * STR + d] = x[(size_t)(cbase + t * 64 + tid) * DIM + d];
      dt[tid] = d2[cbase + t * 64 + tid];
    }
    __syncthreads();
    for (int jj = 0; jj < 16; jj++) {
      const int j = jj * 4 + qt;
      float s = 0.f;
#pragma unroll
      for (int d = 0; d < DIM; d++) s = fmaf(xp[d], tile[j * STR + d], s);
      const float dist = fmaf(-2.f, s, d2p + dt[j]);
      const int qg = cbase + t * 64 + j;
      const bool ins = (dist < wd) || (dist == wd && qg < wi);
      if (ins) {
#pragma unroll
        for (int sl = 0; sl < NK; sl++)
          if (sl == wsl) {
            bd[sl] = dist;
            bi[sl] = qg;
          }
        wd = bd[0];
        wi = bi[0];
        wsl = 0;
#pragma unroll
        for (int sl = 1; sl < NK; sl++) {
          const bool worse = (bd[sl] > wd) || (bd[sl] == wd && bi[sl] > wi);
          if (worse) {
            wd = bd[sl];
            wi = bi[sl];
            wsl = sl;
          }
        }
      }
    }
  }
  __syncthreads();
#pragma unroll
  for (int s = 0; s < NK; s++) {
    mD[pt * 80 + qt * 20 + s] = bd[s];
    mI[pt * 80 + qt * 20 + s] = bi[s];
  }
  __syncthreads();
  if (tid < 128) {
    const int pt2 = tid >> 1, h = tid & 1;
    const int base = pt2 * 80 + h * 40;
    float cd[40];
    int ci[40];
#pragma unroll
    for (int a = 0; a < 40; a++) {
      cd[a] = mD[base + a];
      ci[a] = mI[base + a];
    }
    int rank[40];
#pragma unroll
    for (int a = 0; a < 40; a++) rank[a] = 0;
#pragma unroll
    for (int a = 0; a < 40; a++)
#pragma unroll
      for (int b = a + 1; b < 40; b++) {
        const bool abet = (cd[a] < cd[b]) || (cd[a] == cd[b] && ci[a] < ci[b]);
        if (abet)
          rank[b]++;
        else
          rank[a]++;
      }
#pragma unroll
    for (int a = 0; a < 40; a++)
      if (rank[a] < NK) {
        mD[base + rank[a]] = cd[a];
        mI[base + rank[a]] = ci[a];
      }
  }
  __syncthreads();
  if (tid < 64) {
    const int base = tid * 80;
    float cd[40];
    int ci[40];
#pragma unroll
    for (int a = 0; a < 20; a++) {
      cd[a] = mD[base + a];
      ci[a] = mI[base + a];
      cd[20 + a] = mD[base + 40 + a];
      ci[20 + a] = mI[base + 40 + a];
    }
    int rank[40];
#pragma unroll
    for (int a = 0; a < 40; a++) rank[a] = 0;
#pragma unroll
    for (int a = 0; a < 40; a++)
#pragma unroll
      for (int b = a + 1; b < 40; b++) {
        const bool abet = (cd[a] < cd[b]) || (cd[a] == cd[b] && ci[a] < ci[b]);
        if (abet)
          rank[b]++;
        else
          rank[a]++;
      }
    const int po = cloud * 1024 + blk * 64 + tid;
#pragma unroll
    for (int a = 0; a < 40; a++)
      if (rank[a] < NK) idxo[(size_t)po * NK + rank[a]] = ci[a];
  }
}

// ---------------------------------------------------------------------------
// Edge moments, atomic-free: wave butterfly -> LDS cross-wave -> per-block
// partial (double). kbn reduces the 128 partials.
// ---------------------------------------------------------------------------
__global__ __launch_bounds__(256) void kstats(const float* __restrict__ pos,
                                              const int* __restrict__ idx,
                                              double* __restrict__ Spart) {
  __shared__ float red[4][42];
  const int tid = threadIdx.x;
  const int w = tid >> 6;
  int p = blockIdx.x * 256 + tid;
  float xi0 = pos[p * 3], xi1 = pos[p * 3 + 1], xi2 = pos[p * 3 + 2];
  float s1[6];
  float s2[36];
#pragma unroll
  for (int a = 0; a < 6; a++) s1[a] = 0.f;
#pragma unroll
  for (int a = 0; a < 36; a++) s2[a] = 0.f;
  for (int k = 0; k < NK; k++) {
    int j = idx[p * NK + k];
    float e[6];
    e[0] = xi0;
    e[1] = xi1;
    e[2] = xi2;
    e[3] = pos[j * 3] - xi0;
    e[4] = pos[j * 3 + 1] - xi1;
    e[5] = pos[j * 3 + 2] - xi2;
#pragma unroll
    for (int a = 0; a < 6; a++) {
      s1[a] += e[a];
#pragma unroll
      for (int b = 0; b < 6; b++) s2[a * 6 + b] = fmaf(e[a], e[b], s2[a * 6 + b]);
    }
  }
#pragma unroll
  for (int a = 0; a < 6; a++) {
#pragma unroll
    for (int m = 1; m < 64; m <<= 1) s1[a] += __shfl_xor(s1[a], m, 64);
  }
#pragma unroll
  for (int a = 0; a < 36; a++) {
#pragma unroll
    for (int m = 1; m < 64; m <<= 1) s2[a] += __shfl_xor(s2[a], m, 64);
  }
  if ((tid & 63) == 0) {
#pragma unroll
    for (int a = 0; a < 6; a++) red[w][a] = s1[a];
#pragma unroll
    for (int a = 0; a < 36; a++) red[w][6 + a] = s2[a];
  }
  __syncthreads();
  if (tid < 42) {
    double t = (double)red[0][tid] + (double)red[1][tid] + (double)red[2][tid] +
               (double)red[3][tid];
    Spart[(size_t)blockIdx.x * 42 + tid] = t;
  }
}

// BN scale/shift from moments (reduce 128 partials, then exact in double)
__global__ void kbn(const double* __restrict__ Spart, const float* __restrict__ W1a,
                    const float* __restrict__ b1a, const float* __restrict__ g1,
                    const float* __restrict__ be1, float* __restrict__ ss) {
  __shared__ double S[42];
  int c = threadIdx.x;  // 64
  if (c < 42) {
    double t = 0.0;
    for (int b = 0; b < 128; b++) t += Spart[(size_t)b * 42 + c];
    S[c] = t;
  }
  __syncthreads();
  double w[6];
#pragma unroll
  for (int d = 0; d < 6; d++) w[d] = (double)W1a[d * 64 + c];
  double b = (double)b1a[c];
  const double invN = 1.0 / (double)((size_t)NPTS * NK);
  double m1 = 0.0;
#pragma unroll
  for (int d = 0; d < 6; d++) m1 += w[d] * S[d];
  m1 *= invN;
  double q = 0.0;
#pragma unroll
  for (int a = 0; a < 6; a++)
#pragma unroll
    for (int d = 0; d < 6; d++) q += w[a] * w[d] * S[6 + a * 6 + d];
  q *= invN;
  double mu = m1 + b;
  double eh2 = q + 2.0 * b * m1 + b * b;
  double var = eh2 - mu * mu;
  if (var < 0.0) var = 0.0;
  double inv = 1.0 / sqrt(var + 1e-5);
  double sc = (double)g1[c] * inv;
  ss[c] = (float)sc;
  ss[64 + c] = (float)((double)be1[c] - mu * sc);
}

// ---------------------------------------------------------------------------
// EdgeConv1 fused v3. Block = 8 points = 160 edges (32768 = 8*4096, no tail).
// Phase 1: Z[160][64] -> LDS (wave = 2 pts, lane = chan; nbr pre-gathered).
// Phase 2: Y = Z @ W1b, 5x8 register tile; W1b read DIRECTLY FROM GLOBAL
//          (16 KB, L1-resident) -> B traffic moves off the CU-shared LDS pipe
//          (which R6 counters showed is the bottleneck; the LDS-staged BW
//          reads were also the source of the 1.31M bank-conflict cycles).
// Phase 3: x1[p][c] = max_k Y[p*20+k][c] + b1b[c].
// Same FMA order as R6 -> bit-identical x1.
// ---------------------------------------------------------------------------
#define EC1P 8
__global__ __launch_bounds__(256, 3) void kec1(const float* __restrict__ pos,
                                               const int* __restrict__ idx,
                                               const float* __restrict__ ss,
                                               const float* __restrict__ W1a,
                                               const float* __restrict__ b1a,
                                               const float* __restrict__ W1b,
                                               const float* __restrict__ b1b,
                                               float* __restrict__ x1) {
  __shared__ float Z[160 * 68];   // 43520 B (Y overwrites)
  __shared__ float nbr[160 * 4];  // 2560 B
  const int tid = threadIdx.x;
  const int lane = tid & 63;
  const int w = tid >> 6;
  const int p0 = blockIdx.x * EC1P;

  // phase 0: parallel neighbor-coordinate gather (160 edges)
  if (tid < 160) {
    const int j = idx[(size_t)p0 * NK + tid];
    nbr[tid * 4 + 0] = pos[j * 3 + 0];
    nbr[tid * 4 + 1] = pos[j * 3 + 1];
    nbr[tid * 4 + 2] = pos[j * 3 + 2];
  }

  float wdf[3], wbt[3];
#pragma unroll
  for (int d = 0; d < 3; d++) {
    const float top = W1a[d * 64 + lane];
    const float bot = W1a[(3 + d) * 64 + lane];
    wdf[d] = top - bot;
    wbt[d] = bot;
  }
  const float b1 = b1a[lane];
  const float sc = ss[lane];
  const float sh = ss[64 + lane];
  __syncthreads();

  // phase 1: Z rows (wave w -> points w, w+4)
#pragma unroll
  for (int pp = 0; pp < 2; pp++) {
    const int pl = w + 4 * pp;
    const int p = p0 + pl;
    const float xi0 = pos[p * 3], xi1 = pos[p * 3 + 1], xi2 = pos[p * 3 + 2];
    const float pu = fmaf(xi2, wdf[2], fmaf(xi1, wdf[1], fmaf(xi0, wdf[0], b1)));
    for (int k = 0; k < NK; k++) {
      const float4 nb = *(const float4*)&nbr[(pl * NK + k) * 4];  // broadcast
      const float pv = fmaf(nb.z, wbt[2], fmaf(nb.y, wbt[1], nb.x * wbt[0]));
      Z[(pl * NK + k) * 68 + lane] = fmaxf(fmaf(pu + pv, sc, sh), 0.f);
    }
  }
  __syncthreads();

  // phase 2: Y(160x64) = Z(160x64) @ W1b(64x64); 5 rows x 8 ch per thread.
  // B from GLOBAL (L1), A from LDS.
  const int tc = tid & 7;
  const int tm = tid >> 3;  // 0..31; rows tm + 32*i, i<5 -> 0..159 exact
  float acc[5][8];
#pragma unroll
  for (int i = 0; i < 5; i++)
#pragma unroll
    for (int n = 0; n < 8; n++) acc[i][n] = 0.f;

#pragma unroll
  for (int d4 = 0; d4 < 16; d4++) {
    float b[4][8];
#pragma unroll
    for (int r = 0; r < 4; r++) {
      *(float4*)&b[r][0] = *(const float4*)&W1b[(d4 * 4 + r) * 64 + tc * 8];
      *(float4*)&b[r][4] = *(const float4*)&W1b[(d4 * 4 + r) * 64 + tc * 8 + 4];
    }
#pragma unroll
    for (int i = 0; i < 5; i++) {
      const int row = tm + 32 * i;
      float a[4];
      *(float4*)&a[0] = *(const float4*)&Z[row * 68 + d4 * 4];
#pragma unroll
      for (int r = 0; r < 4; r++)
#pragma unroll
        for (int n = 0; n < 8; n++) acc[i][n] = fmaf(a[r], b[r][n], acc[i][n]);
    }
  }
  __syncthreads();  // all Z reads done; overwrite with Y

#pragma unroll
  for (int i = 0; i < 5; i++) {
    const int row = tm + 32 * i;
    *(float4*)&Z[row * 68 + tc * 8] = *(const float4*)&acc[i][0];
    *(float4*)&Z[row * 68 + tc * 8 + 4] = *(const float4*)&acc[i][4];
  }
  __syncthreads();

  // phase 3: per (point, channel) max over 20 edge rows, + b1b
#pragma unroll
  for (int h = 0; h < 2; h++) {
    const int pc = h * 256 + tid;  // 512 (pl, c) pairs
    const int pl = pc >> 6, c = pc & 63;
    float m = -FLT_MAX;
#pragma unroll
    for (int k = 0; k < NK; k++) m = fmaxf(m, Z[(pl * NK + k) * 68 + c]);
    x1[(size_t)(p0 + pl) * 64 + c] = m + b1b[c];
  }
}

// v[j,c] = x1_j . W2[64+d][c]
__global__ __launch_bounds__(256) void kv(const float* __restrict__ x1,
                                          const float* __restrict__ W2,
                                          float* __restrict__ v) {
  const int c = threadIdx.x & 127;
  const int sub = threadIdx.x >> 7;
  float wv[64];
#pragma unroll
  for (int d = 0; d < 64; d++) wv[d] = W2[(64 + d) * 128 + c];
  const int pbase = blockIdx.x * 64 + sub * 32;
  for (int i = 0; i < 32; i++) {
    const int p = pbase + i;
    const float4* xr = (const float4*)(x1 + (size_t)p * 64);
    float a0 = 0.f, a1 = 0.f;
#pragma unroll
    for (int dq = 0; dq < 16; dq++) {
      float4 xv = xr[dq];
      a0 = fmaf(xv.x, wv[dq * 4 + 0], a0);
      a1 = fmaf(xv.y, wv[dq * 4 + 1], a1);
      a0 = fmaf(xv.z, wv[dq * 4 + 2], a0);
      a1 = fmaf(xv.w, wv[dq * 4 + 3], a1);
    }
    v[(size_t)p * 128 + c] = a0 + a1;
  }
}

// Bc (192x128) and const bias cb (128)
__global__ __launch_bounds__(256) void kprep(const float* __restrict__ W2,
                                             const float* __restrict__ Wl,
                                             const float* __restrict__ b2,
                                             const float* __restrict__ bl,
                                             float* __restrict__ Bc,
                                             float* __restrict__ cb) {
  const int t = blockIdx.x * 256 + threadIdx.x;  // 8192
  const int d = t >> 7, c = t & 127;
  float s = Wl[d * 128 + c];
  for (int e = 0; e < 128; e++)
    s = fmaf(W2[d * 128 + e] - W2[(64 + d) * 128 + e], Wl[(64 + e) * 128 + c], s);
  Bc[d * 128 + c] = s;
  Bc[(64 + 2 * d) * 128 + c] = Wl[(64 + 2 * d) * 128 + c];
  Bc[(64 + 2 * d + 1) * 128 + c] = Wl[(64 + 2 * d + 1) * 128 + c];
  if (d == 0) {
    float sb = bl[c];
    for (int e = 0; e < 128; e++) sb = fmaf(b2[e], Wl[(64 + e) * 128 + c], sb);
    cb[c] = sb;
  }
}

// Final fused: AT = [x1^T ; maxgather(v)^T], GEMM with Bc, per-tile max.
#define ATS 72
#define BSS 132
__global__ __launch_bounds__(256) void kgemm(const float* __restrict__ x1,
                                             const float* __restrict__ v,
                                             const int* __restrict__ idx,
                                             const float* __restrict__ Bc,
                                             float* __restrict__ partial) {
  __shared__ float AT[192 * ATS];
  __shared__ float BS[16 * BSS];
  int* idxs = (int*)BS;
  const int tid = threadIdx.x;
  const int cloud = blockIdx.x >> 4;
  const int mb = blockIdx.x & 15;
  const int pbase = cloud * 1024 + mb * 64;

#pragma unroll
  for (int r = 0; r < 5; r++) {
    int id = r * 256 + tid;
    idxs[id] = idx[(size_t)pbase * NK + id];
  }
#pragma unroll
  for (int r = 0; r < 16; r++) {
    int id = r * 256 + tid;
    int m = id >> 6, k = id & 63;
    AT[k * ATS + m] = x1[(size_t)(pbase + m) * 64 + k];
  }
  __syncthreads();
#pragma unroll
  for (int r = 0; r < 32; r++) {
    int id = r * 256 + tid;
    int m = id >> 7, kk = id & 127;
    const int* ip = &idxs[m * NK];
    float mx = -FLT_MAX;
#pragma unroll
    for (int k = 0; k < NK; k++) mx = fmaxf(mx, v[(size_t)ip[k] * 128 + kk]);
    AT[(64 + kk) * ATS + m] = mx;
  }
  __syncthreads();

  const int tr = tid >> 4, tc = tid & 15;
  float acc[4][8];
#pragma unroll
  for (int i = 0; i < 4; i++)
#pragma unroll
    for (int n = 0; n < 8; n++) acc[i][n] = 0.f;
  for (int kc = 0; kc < 12; kc++) {
#pragma unroll
    for (int r = 0; r < 8; r++) {
      int id = r * 256 + tid;
      int row = id >> 7, col = id & 127;
      BS[row * BSS + col] = Bc[(size_t)(kc * 16 + row) * 128 + col];
    }
    __syncthreads();
#pragma unroll
    for (int k = 0; k < 16; k++) {
      int kg = kc * 16 + k;
      float4 a = *(const float4*)&AT[kg * ATS + tr * 4];
      float4 b0 = *(const float4*)&BS[k * BSS + tc * 8];
      float4 b1 = *(const float4*)&BS[k * BSS + tc * 8 + 4];
      float av[4] = {a.x, a.y, a.z, a.w};
      float bv[8] = {b0.x, b0.y, b0.z, b0.w, b1.x, b1.y, b1.z, b1.w};
#pragma unroll
      for (int i = 0; i < 4; i++)
#pragma unroll
        for (int n = 0; n < 8; n++) acc[i][n] = fmaf(av[i], bv[n], acc[i][n]);
    }
    __syncthreads();
  }
#pragma unroll
  for (int n = 0; n < 8; n++) {
    float m4 = fmaxf(fmaxf(acc[0][n], acc[1][n]), fmaxf(acc[2][n], acc[3][n]));
    BS[tr * BSS + tc * 8 + n] = m4;
  }
  __syncthreads();
  if (tid < 128) {
    float m = -FLT_MAX;
#pragma unroll
    for (int rr = 0; rr < 16; rr++) m = fmaxf(m, BS[rr * BSS + tid]);
    partial[(size_t)blockIdx.x * 128 + tid] = m;
  }
}

__global__ __launch_bounds__(256) void kred(const float* __restrict__ partial,
                                            const float* __restrict__ cb,
                                            float* __restrict__ out) {
  int t = blockIdx.x * 256 + threadIdx.x;  // 4096
  int b = t >> 7, c = t & 127;
  float m = -FLT_MAX;
#pragma unroll
  for (int mb = 0; mb < 16; mb++) m = fmaxf(m, partial[(size_t)(b * 16 + mb) * 128 + c]);
  out[t] = m + cb[c];
}

// ---------------------------------------------------------------------------
extern "C" void kernel_launch(void* const* d_in, const int* in_sizes, int n_in,
                              void* d_out, int out_size, void* d_ws, size_t ws_size,
                              hipStream_t stream) {
  const float* pos = (const float*)d_in[0];
  const float* W1a = (const float*)d_in[1];
  const float* b1a = (const float*)d_in[2];
  const float* g1 = (const float*)d_in[3];
  const float* be1 = (const float*)d_in[4];
  const float* W1b = (const float*)d_in[5];
  const float* b1b = (const float*)d_in[6];
  const float* W2 = (const float*)d_in[7];
  const float* b2 = (const float*)d_in[8];
  const float* Wl = (const float*)d_in[9];
  const float* bl = (const float*)d_in[10];
  float* out = (float*)d_out;

  // Base workspace (floats). D-matrix chunk after it.
  float* ws = (float*)d_ws;
  float* x1 = ws;                           // 2,097,152
  float* v = ws + 2097152;                  // 4,194,304
  int* idx = (int*)(ws + 6291456);          // 655,360
  float* d2b = ws + 6946816;                // 32,768
  double* Spart = (double*)(ws + 6979584);  // 128*42 doubles = 10,752 slots
  float* Bc = ws + 6990336;                 // 24,576
  float* cb = ws + 7014912;                 // 128
  float* ss = ws + 7015040;                 // 128
  float* partial = ws + 7015168;            // 65,536 -> end 7,080,704
  const size_t base = 7080704;
  float* D = ws + base;

  if (ws_size < base * sizeof(float)) return;  // fail soft

  // D chunk: prefer the largest power-of-2 cloud count that fits (<= 32);
  // nc=32 -> single kdist+kselect pair per layer (fewest dispatches).
  size_t avail = ws_size / sizeof(float) - base;
  int nc = 0;
  for (int c = 32; c >= 1; c >>= 1)
    if ((size_t)c * 1024 * 1024 <= avail) {
      nc = c;
      break;
    }

  // --- layer 1: kNN on pos (3D) ---
  kd2<<<128, 256, 0, stream>>>(pos, 3, d2b);
  if (nc > 0) {
    for (int c0 = 0; c0 < NB; c0 += nc) {
      kdist<3><<<nc * 64, 256, 0, stream>>>(pos, d2b, c0, D);
      kselect<<<nc * 256, 256, 0, stream>>>(D, c0, idx);
    }
  } else {
    kknn<3><<<512, 256, 0, stream>>>(pos, d2b, idx);
  }

  // --- EdgeConv1 (analytic BN via exact 6-dim moments, atomic-free) ---
  kstats<<<128, 256, 0, stream>>>(pos, idx, Spart);
  kbn<<<1, 64, 0, stream>>>(Spart, W1a, b1a, g1, be1, ss);
  kec1<<<NPTS / EC1P, 256, 0, stream>>>(pos, idx, ss, W1a, b1a, W1b, b1b, x1);

  // --- layer 2: kNN on x1 (64D) ---
  kd2<<<128, 256, 0, stream>>>(x1, 64, d2b);
  if (nc > 0) {
    for (int c0 = 0; c0 < NB; c0 += nc) {
      kdist<64><<<nc * 64, 256, 0, stream>>>(x1, d2b, c0, D);
      kselect<<<nc * 256, 256, 0, stream>>>(D, c0, idx);
    }
  } else {
    kknn<64><<<512, 256, 0, stream>>>(x1, d2b, idx);
  }

  // --- EdgeConv2 factored + fused final linear + pool ---
  kv<<<512, 256, 0, stream>>>(x1, W2, v);
  kprep<<<32, 256, 0, stream>>>(W2, Wl, b2, bl, Bc, cb);
  kgemm<<<512, 256, 0, stream>>>(x1, v, idx, Bc, partial);
  kred<<<16, 256, 0, stream>>>(partial, cb, out);
}

// Round 9
// 451.264 us; speedup vs baseline: 1.1154x; 1.1154x over previous
//
#include <hip/hip_runtime.h>
#include <cfloat>
#include <cstdint>

#define NB 32
#define NP 1024
#define NK 20
#define NPTS 32768  // NB*NP

// ---------------------------------------------------------------------------
// d2[p] = sum x^2, SINGLE sequential FMA chain (order-matched with kdist's
// per-acc chain so diagonal dist = fmaf(-2,d2p,2*d2p) = exact 0).
// ---------------------------------------------------------------------------
__global__ __launch_bounds__(256) void kd2(const float* __restrict__ x, int dim,
                                           float* __restrict__ d2) {
  int p = blockIdx.x * 256 + threadIdx.x;
  if (p >= NPTS) return;
  if (dim == 64) {
    const float4* xr = (const float4*)(x + (size_t)p * 64);
    float s = 0.f;
#pragma unroll
    for (int dq = 0; dq < 16; dq++) {
      float4 v = xr[dq];
      s = fmaf(v.x, v.x, s);
      s = fmaf(v.y, v.y, s);
      s = fmaf(v.z, v.z, s);
      s = fmaf(v.w, v.w, s);
    }
    d2[p] = s;
  } else {
    float s = 0.f;
#pragma unroll
    for (int d = 0; d < 3; d++) {
      float v = x[p * 3 + d];
      s = fmaf(v, v, s);
    }
    d2[p] = s;
  }
}

// ---------------------------------------------------------------------------
// kdist: full per-cloud distance matrix, 128x128 tile per block.
// ---------------------------------------------------------------------------
template <int DIM>
__global__ __launch_bounds__(256) void kdist(const float* __restrict__ x,
                                             const float* __restrict__ d2,
                                             int c0, float* __restrict__ D) {
  constexpr int KC = (DIM == 64) ? 32 : 3;
  __shared__ float As[KC][132];
  __shared__ float Bs[KC][132];
  const int tid = threadIdx.x;
  const int cloud = blockIdx.x >> 6;  // within chunk
  const int t = blockIdx.x & 63;
  const int tr0 = (t >> 3) * 128, tc0 = (t & 7) * 128;
  const int cb = (c0 + cloud) * 1024;
  const int tr = tid >> 4, tc = tid & 15;

  float acc[8][8];
#pragma unroll
  for (int i = 0; i < 8; i++)
#pragma unroll
    for (int j = 0; j < 8; j++) acc[i][j] = 0.f;

  for (int kc = 0; kc < DIM; kc += KC) {
    __syncthreads();
    if constexpr (DIM == 64) {
      const int row = tid >> 1, seg = tid & 1;
      const float4* sa = (const float4*)(x + (size_t)(cb + tr0 + row) * 64 + kc + seg * 16);
      const float4* sb = (const float4*)(x + (size_t)(cb + tc0 + row) * 64 + kc + seg * 16);
#pragma unroll
      for (int i = 0; i < 4; i++) {
        float4 va = sa[i];
        float4 vb = sb[i];
        const int k0 = seg * 16 + i * 4;
        As[k0 + 0][row] = va.x;
        As[k0 + 1][row] = va.y;
        As[k0 + 2][row] = va.z;
        As[k0 + 3][row] = va.w;
        Bs[k0 + 0][row] = vb.x;
        Bs[k0 + 1][row] = vb.y;
        Bs[k0 + 2][row] = vb.z;
        Bs[k0 + 3][row] = vb.w;
      }
    } else {
      if (tid < 128) {
#pragma unroll
        for (int d = 0; d < 3; d++) {
          As[d][tid] = x[(size_t)(cb + tr0 + tid) * 3 + d];
          Bs[d][tid] = x[(size_t)(cb + tc0 + tid) * 3 + d];
        }
      }
    }
    __syncthreads();
#pragma unroll
    for (int k = 0; k < KC; k++) {
      float a[8], b[8];
      *(float4*)&a[0] = *(const float4*)&As[k][tr * 8];
      *(float4*)&a[4] = *(const float4*)&As[k][tr * 8 + 4];
      *(float4*)&b[0] = *(const float4*)&Bs[k][tc * 8];
      *(float4*)&b[4] = *(const float4*)&Bs[k][tc * 8 + 4];
#pragma unroll
      for (int i = 0; i < 8; i++)
#pragma unroll
        for (int j = 0; j < 8; j++) acc[i][j] = fmaf(a[i], b[j], acc[i][j]);
    }
  }
  float d2r[8], d2c[8];
#pragma unroll
  for (int i = 0; i < 8; i++) d2r[i] = d2[cb + tr0 + tr * 8 + i];
#pragma unroll
  for (int j = 0; j < 8; j++) d2c[j] = d2[cb + tc0 + tc * 8 + j];
#pragma unroll
  for (int i = 0; i < 8; i++) {
    float o[8];
#pragma unroll
    for (int j = 0; j < 8; j++) o[j] = fmaf(-2.f, acc[i][j], d2r[i] + d2c[j]);
    float* dst = &D[(size_t)(cloud * 1024 + tr0 + tr * 8 + i) * 1024 + tc0 + tc * 8];
    *(float4*)&dst[0] = *(const float4*)&o[0];
    *(float4*)&dst[4] = *(const float4*)&o[4];
  }
}

// ---------------------------------------------------------------------------
// kselect: exact top-20 via pivot selection (keys distinct by construction).
// ---------------------------------------------------------------------------
__global__ __launch_bounds__(256) void kselect(const float* __restrict__ D,
                                               int c0, int* __restrict__ idxo) {
  __shared__ unsigned long long lw[4][64];
  const int lane = threadIdx.x & 63;
  const int sub = threadIdx.x >> 6;
  const int pchunk = blockIdx.x * 4 + sub;  // point within chunk
  const int pg = c0 * 1024 + pchunk;        // global point
  const int gbase = (pg >> 10) << 10;       // cloud base (global)

  unsigned long long key[16];
  const float4* dr = (const float4*)(D + (size_t)pchunk * 1024 + lane * 4);
#pragma unroll
  for (int i = 0; i < 4; i++) {
    float4 d4 = dr[i * 64];  // q = i*256 + lane*4 ..+3
    float dv[4] = {d4.x, d4.y, d4.z, d4.w};
#pragma unroll
    for (int j = 0; j < 4; j++) {
      unsigned int u = __float_as_uint(dv[j]);
      u ^= (((int)u >> 31) | 0x80000000u);  // sortable transform
      key[i * 4 + j] = ((unsigned long long)u << 10) | (unsigned)(i * 256 + lane * 4 + j);
    }
  }

  unsigned long long mn = key[0], mx = key[0];
#pragma unroll
  for (int i = 1; i < 16; i++) {
    mn = key[i] < mn ? key[i] : mn;
    mx = key[i] > mx ? key[i] : mx;
  }
#pragma unroll
  for (int s = 1; s < 64; s <<= 1) {
    unsigned long long a = __shfl_xor(mn, s, 64);
    unsigned long long b = __shfl_xor(mx, s, 64);
    mn = a < mn ? a : mn;
    mx = b > mx ? b : mx;
  }
  unsigned long long lo = mn, hi = mx + 1, mid = hi;
  bool found = false;
  for (int it = 0; it < 48 && !found; ++it) {
    unsigned long long m2 = lo + ((hi - lo) >> 1);
    int cnt = 0;
#pragma unroll
    for (int i = 0; i < 16; i++) cnt += (key[i] < m2) ? 1 : 0;
#pragma unroll
    for (int s = 1; s < 64; s <<= 1) cnt += __shfl_xor(cnt, s, 64);
    if (cnt < 20)
      lo = m2;
    else if (cnt > 63)
      hi = m2;
    else {
      mid = m2;
      found = true;
    }
  }

  unsigned int mask = 0;
#pragma unroll
  for (int i = 0; i < 16; i++) mask |= (key[i] < mid) ? (1u << i) : 0u;
  const int lc = __popc(mask);
  int x = lc;
#pragma unroll
  for (int s = 1; s < 64; s <<= 1) {
    int y = __shfl_up(x, s, 64);
    if (lane >= s) x += y;
  }
  int off = x - lc;                    // exclusive prefix
  const int ctot = __shfl(x, 63, 64);  // total candidates
  const int c = ctot < 64 ? ctot : 64;
  unsigned long long* w = lw[sub];
#pragma unroll
  for (int i = 0; i < 16; i++) {
    if ((mask & (1u << i)) && off < 64) {
      w[off] = key[i];
      off++;
    }
  }
  __builtin_amdgcn_wave_barrier();

  const unsigned long long K = w[lane < c ? lane : 0];
  int rank = 0;
  for (int m = 0; m < c; m++) {
    const unsigned long long Km = w[m];  // broadcast read
    rank += (K > Km) ? 1 : 0;
  }
  if (lane < c && rank < NK)
    idxo[(size_t)pg * NK + rank] = gbase + (int)(K & 1023u);
}

// ---------------------------------------------------------------------------
// FALLBACK kNN (used only if ws_size can't fit a 1-cloud distance matrix).
// ---------------------------------------------------------------------------
template <int DIM>
__global__ __launch_bounds__(256) void kknn(const float* __restrict__ x,
                                            const float* __restrict__ d2,
                                            int* __restrict__ idxo) {
  constexpr int STR = (DIM == 64) ? 68 : 4;
  __shared__ float smem[10240];
  float* tile = smem;
  float* dt = smem + 64 * STR;
  float* mD = smem;
  int* mI = (int*)(smem + 5120);

  const int tid = threadIdx.x;
  const int pt = tid & 63;
  const int qt = tid >> 6;
  const int cloud = blockIdx.x >> 4;
  const int blk = blockIdx.x & 15;
  const int p = cloud * 1024 + blk * 64 + pt;
  const int cbase = cloud * 1024;

  float xp[DIM];
#pragma unroll
  for (int d = 0; d < DIM; d++) xp[d] = x[(size_t)p * DIM + d];
  const float d2p = d2[p];

  float bd[NK];
  int bi[NK];
#pragma unroll
  for (int s = 0; s < NK; s++) {
    bd[s] = FLT_MAX;
    bi[s] = 0x7fffffff;
  }
  float wd = FLT_MAX;
  int wi = 0x7fffffff;
  int wsl = 0;

  for (int t = 0; t < 16; t++) {
    __syncthreads();
    if (tid < 64) {
#pragma unroll
      for (int d = 0; d < DIM; d++) tile[tid * STR + d] = x[(size_t)(cbase + t * 64 + tid) * DIM + d];
      dt[tid] = d2[cbase + t * 64 + tid];
    }
    __syncthreads();
    for (int jj = 0; jj < 16; jj++) {
      const int j = jj * 4 + qt;
      float s = 0.f;
#pragma unroll
      for (int d = 0; d < DIM; d++) s = fmaf(xp[d], tile[j * STR + d], s);
      const float dist = fmaf(-2.f, s, d2p + dt[j]);
      const int qg = cbase + t * 64 + j;
      const bool ins = (dist < wd) || (dist == wd && qg < wi);
      if (ins) {
#pragma unroll
        for (int sl = 0; sl < NK; sl++)
          if (sl == wsl) {
            bd[sl] = dist;
            bi[sl] = qg;
          }
        wd = bd[0];
        wi = bi[0];
        wsl = 0;
#pragma unroll
        for (int sl = 1; sl < NK; sl++) {
          const bool worse = (bd[sl] > wd) || (bd[sl] == wd && bi[sl] > wi);
          if (worse) {
            wd = bd[sl];
            wi = bi[sl];
            wsl = sl;
          }
        }
      }
    }
  }
  __syncthreads();
#pragma unroll
  for (int s = 0; s < NK; s++) {
    mD[pt * 80 + qt * 20 + s] = bd[s];
    mI[pt * 80 + qt * 20 + s] = bi[s];
  }
  __syncthreads();
  if (tid < 128) {
    const int pt2 = tid >> 1, h = tid & 1;
    const int base = pt2 * 80 + h * 40;
    float cd[40];
    int ci[40];
#pragma unroll
    for (int a = 0; a < 40; a++) {
      cd[a] = mD[base + a];
      ci[a] = mI[base + a];
    }
    int rank[40];
#pragma unroll
    for (int a = 0; a < 40; a++) rank[a] = 0;
#pragma unroll
    for (int a = 0; a < 40; a++)
#pragma unroll
      for (int b = a + 1; b < 40; b++) {
        const bool abet = (cd[a] < cd[b]) || (cd[a] == cd[b] && ci[a] < ci[b]);
        if (abet)
          rank[b]++;
        else
          rank[a]++;
      }
#pragma unroll
    for (int a = 0; a < 40; a++)
      if (rank[a] < NK) {
        mD[base + rank[a]] = cd[a];
        mI[base + rank[a]] = ci[a];
      }
  }
  __syncthreads();
  if (tid < 64) {
    const int base = tid * 80;
    float cd[40];
    int ci[40];
#pragma unroll
    for (int a = 0; a < 20; a++) {
      cd[a] = mD[base + a];
      ci[a] = mI[base + a];
      cd[20 + a] = mD[base + 40 + a];
      ci[20 + a] = mI[base + 40 + a];
    }
    int rank[40];
#pragma unroll
    for (int a = 0; a < 40; a++) rank[a] = 0;
#pragma unroll
    for (int a = 0; a < 40; a++)
#pragma unroll
      for (int b = a + 1; b < 40; b++) {
        const bool abet = (cd[a] < cd[b]) || (cd[a] == cd[b] && ci[a] < ci[b]);
        if (abet)
          rank[b]++;
        else
          rank[a]++;
      }
    const int po = cloud * 1024 + blk * 64 + tid;
#pragma unroll
    for (int a = 0; a < 40; a++)
      if (rank[a] < NK) idxo[(size_t)po * NK + rank[a]] = ci[a];
  }
}

// ---------------------------------------------------------------------------
// Edge moments, atomic-free: wave butterfly -> LDS cross-wave -> per-block
// partial (double). kbn reduces the 128 partials.
// ---------------------------------------------------------------------------
__global__ __launch_bounds__(256) void kstats(const float* __restrict__ pos,
                                              const int* __restrict__ idx,
                                              double* __restrict__ Spart) {
  __shared__ float red[4][42];
  const int tid = threadIdx.x;
  const int w = tid >> 6;
  int p = blockIdx.x * 256 + tid;
  float xi0 = pos[p * 3], xi1 = pos[p * 3 + 1], xi2 = pos[p * 3 + 2];
  float s1[6];
  float s2[36];
#pragma unroll
  for (int a = 0; a < 6; a++) s1[a] = 0.f;
#pragma unroll
  for (int a = 0; a < 36; a++) s2[a] = 0.f;
  for (int k = 0; k < NK; k++) {
    int j = idx[p * NK + k];
    float e[6];
    e[0] = xi0;
    e[1] = xi1;
    e[2] = xi2;
    e[3] = pos[j * 3] - xi0;
    e[4] = pos[j * 3 + 1] - xi1;
    e[5] = pos[j * 3 + 2] - xi2;
#pragma unroll
    for (int a = 0; a < 6; a++) {
      s1[a] += e[a];
#pragma unroll
      for (int b = 0; b < 6; b++) s2[a * 6 + b] = fmaf(e[a], e[b], s2[a * 6 + b]);
    }
  }
#pragma unroll
  for (int a = 0; a < 6; a++) {
#pragma unroll
    for (int m = 1; m < 64; m <<= 1) s1[a] += __shfl_xor(s1[a], m, 64);
  }
#pragma unroll
  for (int a = 0; a < 36; a++) {
#pragma unroll
    for (int m = 1; m < 64; m <<= 1) s2[a] += __shfl_xor(s2[a], m, 64);
  }
  if ((tid & 63) == 0) {
#pragma unroll
    for (int a = 0; a < 6; a++) red[w][a] = s1[a];
#pragma unroll
    for (int a = 0; a < 36; a++) red[w][6 + a] = s2[a];
  }
  __syncthreads();
  if (tid < 42) {
    double t = (double)red[0][tid] + (double)red[1][tid] + (double)red[2][tid] +
               (double)red[3][tid];
    Spart[(size_t)blockIdx.x * 42 + tid] = t;
  }
}

// BN scale/shift from moments (reduce 128 partials, then exact in double)
__global__ void kbn(const double* __restrict__ Spart, const float* __restrict__ W1a,
                    const float* __restrict__ b1a, const float* __restrict__ g1,
                    const float* __restrict__ be1, float* __restrict__ ss) {
  __shared__ double S[42];
  int c = threadIdx.x;  // 64
  if (c < 42) {
    double t = 0.0;
    for (int b = 0; b < 128; b++) t += Spart[(size_t)b * 42 + c];
    S[c] = t;
  }
  __syncthreads();
  double w[6];
#pragma unroll
  for (int d = 0; d < 6; d++) w[d] = (double)W1a[d * 64 + c];
  double b = (double)b1a[c];
  const double invN = 1.0 / (double)((size_t)NPTS * NK);
  double m1 = 0.0;
#pragma unroll
  for (int d = 0; d < 6; d++) m1 += w[d] * S[d];
  m1 *= invN;
  double q = 0.0;
#pragma unroll
  for (int a = 0; a < 6; a++)
#pragma unroll
    for (int d = 0; d < 6; d++) q += w[a] * w[d] * S[6 + a * 6 + d];
  q *= invN;
  double mu = m1 + b;
  double eh2 = q + 2.0 * b * m1 + b * b;
  double var = eh2 - mu * mu;
  if (var < 0.0) var = 0.0;
  double inv = 1.0 / sqrt(var + 1e-5);
  double sc = (double)g1[c] * inv;
  ss[c] = (float)sc;
  ss[64 + c] = (float)((double)be1[c] - mu * sc);
}

// ---------------------------------------------------------------------------
// EdgeConv1 fused v4. Block = 8 points = 160 edges (32768 = 8*4096, no tail).
// Phase 1: Z[160][64] -> LDS (wave = 2 pts, lane = chan; nbr pre-gathered).
// Phase 2: Y = Z @ W1b, 5x8 register tile; W1b from GLOBAL (L1-resident),
//          but row-at-a-time with IMMEDIATE FMA -> live set ~68 floats
//          (acc 40 + a4 20 + b 8), no scratch spill (R8's all-at-once b[4][8]
//          spilled: WRITE_SIZE 8 MB -> 127 MB, the regression source).
// Phase 3: x1[p][c] = max_k Y[p*20+k][c] + b1b[c].
// Per-acc-element FMA chain is k-ascending, same as R5-R8 -> bit-identical x1.
// ---------------------------------------------------------------------------
#define EC1P 8
__global__ __launch_bounds__(256) void kec1(const float* __restrict__ pos,
                                            const int* __restrict__ idx,
                                            const float* __restrict__ ss,
                                            const float* __restrict__ W1a,
                                            const float* __restrict__ b1a,
                                            const float* __restrict__ W1b,
                                            const float* __restrict__ b1b,
                                            float* __restrict__ x1) {
  __shared__ float Z[160 * 68];   // 43520 B (Y overwrites)
  __shared__ float nbr[160 * 4];  // 2560 B
  const int tid = threadIdx.x;
  const int lane = tid & 63;
  const int w = tid >> 6;
  const int p0 = blockIdx.x * EC1P;

  // phase 0: parallel neighbor-coordinate gather (160 edges)
  if (tid < 160) {
    const int j = idx[(size_t)p0 * NK + tid];
    nbr[tid * 4 + 0] = pos[j * 3 + 0];
    nbr[tid * 4 + 1] = pos[j * 3 + 1];
    nbr[tid * 4 + 2] = pos[j * 3 + 2];
  }

  float wdf[3], wbt[3];
#pragma unroll
  for (int d = 0; d < 3; d++) {
    const float top = W1a[d * 64 + lane];
    const float bot = W1a[(3 + d) * 64 + lane];
    wdf[d] = top - bot;
    wbt[d] = bot;
  }
  const float b1 = b1a[lane];
  const float sc = ss[lane];
  const float sh = ss[64 + lane];
  __syncthreads();

  // phase 1: Z rows (wave w -> points w, w+4)
#pragma unroll
  for (int pp = 0; pp < 2; pp++) {
    const int pl = w + 4 * pp;
    const int p = p0 + pl;
    const float xi0 = pos[p * 3], xi1 = pos[p * 3 + 1], xi2 = pos[p * 3 + 2];
    const float pu = fmaf(xi2, wdf[2], fmaf(xi1, wdf[1], fmaf(xi0, wdf[0], b1)));
    for (int k = 0; k < NK; k++) {
      const float4 nb = *(const float4*)&nbr[(pl * NK + k) * 4];  // broadcast
      const float pv = fmaf(nb.z, wbt[2], fmaf(nb.y, wbt[1], nb.x * wbt[0]));
      Z[(pl * NK + k) * 68 + lane] = fmaxf(fmaf(pu + pv, sc, sh), 0.f);
    }
  }
  __syncthreads();

  // phase 2: Y(160x64) = Z(160x64) @ W1b(64x64); 5 rows x 8 ch per thread.
  // B rows streamed from global (L1) one at a time, FMA'd immediately.
  const int tc = tid & 7;
  const int tm = tid >> 3;  // 0..31; rows tm + 32*i, i<5 -> 0..159 exact
  float acc[5][8];
#pragma unroll
  for (int i = 0; i < 5; i++)
#pragma unroll
    for (int n = 0; n < 8; n++) acc[i][n] = 0.f;

#pragma unroll
  for (int d4 = 0; d4 < 16; d4++) {
    float4 a4[5];
#pragma unroll
    for (int i = 0; i < 5; i++)
      a4[i] = *(const float4*)&Z[(tm + 32 * i) * 68 + d4 * 4];
#pragma unroll
    for (int r = 0; r < 4; r++) {
      float b[8];
      *(float4*)&b[0] = *(const float4*)&W1b[(d4 * 4 + r) * 64 + tc * 8];
      *(float4*)&b[4] = *(const float4*)&W1b[(d4 * 4 + r) * 64 + tc * 8 + 4];
#pragma unroll
      for (int i = 0; i < 5; i++) {
        const float ar = (r == 0) ? a4[i].x : (r == 1) ? a4[i].y : (r == 2) ? a4[i].z : a4[i].w;
#pragma unroll
        for (int n = 0; n < 8; n++) acc[i][n] = fmaf(ar, b[n], acc[i][n]);
      }
    }
  }
  __syncthreads();  // all Z reads done; overwrite with Y

#pragma unroll
  for (int i = 0; i < 5; i++) {
    const int row = tm + 32 * i;
    *(float4*)&Z[row * 68 + tc * 8] = *(const float4*)&acc[i][0];
    *(float4*)&Z[row * 68 + tc * 8 + 4] = *(const float4*)&acc[i][4];
  }
  __syncthreads();

  // phase 3: per (point, channel) max over 20 edge rows, + b1b
#pragma unroll
  for (int h = 0; h < 2; h++) {
    const int pc = h * 256 + tid;  // 512 (pl, c) pairs
    const int pl = pc >> 6, c = pc & 63;
    float m = -FLT_MAX;
#pragma unroll
    for (int k = 0; k < NK; k++) m = fmaxf(m, Z[(pl * NK + k) * 68 + c]);
    x1[(size_t)(p0 + pl) * 64 + c] = m + b1b[c];
  }
}

// v[j,c] = x1_j . W2[64+d][c]
__global__ __launch_bounds__(256) void kv(const float* __restrict__ x1,
                                          const float* __restrict__ W2,
                                          float* __restrict__ v) {
  const int c = threadIdx.x & 127;
  const int sub = threadIdx.x >> 7;
  float wv[64];
#pragma unroll
  for (int d = 0; d < 64; d++) wv[d] = W2[(64 + d) * 128 + c];
  const int pbase = blockIdx.x * 64 + sub * 32;
  for (int i = 0; i < 32; i++) {
    const int p = pbase + i;
    const float4* xr = (const float4*)(x1 + (size_t)p * 64);
    float a0 = 0.f, a1 = 0.f;
#pragma unroll
    for (int dq = 0; dq < 16; dq++) {
      float4 xv = xr[dq];
      a0 = fmaf(xv.x, wv[dq * 4 + 0], a0);
      a1 = fmaf(xv.y, wv[dq * 4 + 1], a1);
      a0 = fmaf(xv.z, wv[dq * 4 + 2], a0);
      a1 = fmaf(xv.w, wv[dq * 4 + 3], a1);
    }
    v[(size_t)p * 128 + c] = a0 + a1;
  }
}

// Bc (192x128) and const bias cb (128)
__global__ __launch_bounds__(256) void kprep(const float* __restrict__ W2,
                                             const float* __restrict__ Wl,
                                             const float* __restrict__ b2,
                                             const float* __restrict__ bl,
                                             float* __restrict__ Bc,
                                             float* __restrict__ cb) {
  const int t = blockIdx.x * 256 + threadIdx.x;  // 8192
  const int d = t >> 7, c = t & 127;
  float s = Wl[d * 128 + c];
  for (int e = 0; e < 128; e++)
    s = fmaf(W2[d * 128 + e] - W2[(64 + d) * 128 + e], Wl[(64 + e) * 128 + c], s);
  Bc[d * 128 + c] = s;
  Bc[(64 + 2 * d) * 128 + c] = Wl[(64 + 2 * d) * 128 + c];
  Bc[(64 + 2 * d + 1) * 128 + c] = Wl[(64 + 2 * d + 1) * 128 + c];
  if (d == 0) {
    float sb = bl[c];
    for (int e = 0; e < 128; e++) sb = fmaf(b2[e], Wl[(64 + e) * 128 + c], sb);
    cb[c] = sb;
  }
}

// Final fused: AT = [x1^T ; maxgather(v)^T], GEMM with Bc, per-tile max.
#define ATS 72
#define BSS 132
__global__ __launch_bounds__(256) void kgemm(const float* __restrict__ x1,
                                             const float* __restrict__ v,
                                             const int* __restrict__ idx,
                                             const float* __restrict__ Bc,
                                             float* __restrict__ partial) {
  __shared__ float AT[192 * ATS];
  __shared__ float BS[16 * BSS];
  int* idxs = (int*)BS;
  const int tid = threadIdx.x;
  const int cloud = blockIdx.x >> 4;
  const int mb = blockIdx.x & 15;
  const int pbase = cloud * 1024 + mb * 64;

#pragma unroll
  for (int r = 0; r < 5; r++) {
    int id = r * 256 + tid;
    idxs[id] = idx[(size_t)pbase * NK + id];
  }
#pragma unroll
  for (int r = 0; r < 16; r++) {
    int id = r * 256 + tid;
    int m = id >> 6, k = id & 63;
    AT[k * ATS + m] = x1[(size_t)(pbase + m) * 64 + k];
  }
  __syncthreads();
#pragma unroll
  for (int r = 0; r < 32; r++) {
    int id = r * 256 + tid;
    int m = id >> 7, kk = id & 127;
    const int* ip = &idxs[m * NK];
    float mx = -FLT_MAX;
#pragma unroll
    for (int k = 0; k < NK; k++) mx = fmaxf(mx, v[(size_t)ip[k] * 128 + kk]);
    AT[(64 + kk) * ATS + m] = mx;
  }
  __syncthreads();

  const int tr = tid >> 4, tc = tid & 15;
  float acc[4][8];
#pragma unroll
  for (int i = 0; i < 4; i++)
#pragma unroll
    for (int n = 0; n < 8; n++) acc[i][n] = 0.f;
  for (int kc = 0; kc < 12; kc++) {
#pragma unroll
    for (int r = 0; r < 8; r++) {
      int id = r * 256 + tid;
      int row = id >> 7, col = id & 127;
      BS[row * BSS + col] = Bc[(size_t)(kc * 16 + row) * 128 + col];
    }
    __syncthreads();
#pragma unroll
    for (int k = 0; k < 16; k++) {
      int kg = kc * 16 + k;
      float4 a = *(const float4*)&AT[kg * ATS + tr * 4];
      float4 b0 = *(const float4*)&BS[k * BSS + tc * 8];
      float4 b1 = *(const float4*)&BS[k * BSS + tc * 8 + 4];
      float av[4] = {a.x, a.y, a.z, a.w};
      float bv[8] = {b0.x, b0.y, b0.z, b0.w, b1.x, b1.y, b1.z, b1.w};
#pragma unroll
      for (int i = 0; i < 4; i++)
#pragma unroll
        for (int n = 0; n < 8; n++) acc[i][n] = fmaf(av[i], bv[n], acc[i][n]);
    }
    __syncthreads();
  }
#pragma unroll
  for (int n = 0; n < 8; n++) {
    float m4 = fmaxf(fmaxf(acc[0][n], acc[1][n]), fmaxf(acc[2][n], acc[3][n]));
    BS[tr * BSS + tc * 8 + n] = m4;
  }
  __syncthreads();
  if (tid < 128) {
    float m = -FLT_MAX;
#pragma unroll
    for (int rr = 0; rr < 16; rr++) m = fmaxf(m, BS[rr * BSS + tid]);
    partial[(size_t)blockIdx.x * 128 + tid] = m;
  }
}

__global__ __launch_bounds__(256) void kred(const float* __restrict__ partial,
                                            const float* __restrict__ cb,
                                            float* __restrict__ out) {
  int t = blockIdx.x * 256 + threadIdx.x;  // 4096
  int b = t >> 7, c = t & 127;
  float m = -FLT_MAX;
#pragma unroll
  for (int mb = 0; mb < 16; mb++) m = fmaxf(m, partial[(size_t)(b * 16 + mb) * 128 + c]);
  out[t] = m + cb[c];
}

// ---------------------------------------------------------------------------
extern "C" void kernel_launch(void* const* d_in, const int* in_sizes, int n_in,
                              void* d_out, int out_size, void* d_ws, size_t ws_size,
                              hipStream_t stream) {
  const float* pos = (const float*)d_in[0];
  const float* W1a = (const float*)d_in[1];
  const float* b1a = (const float*)d_in[2];
  const float* g1 = (const float*)d_in[3];
  const float* be1 = (const float*)d_in[4];
  const float* W1b = (const float*)d_in[5];
  const float* b1b = (const float*)d_in[6];
  const float* W2 = (const float*)d_in[7];
  const float* b2 = (const float*)d_in[8];
  const float* Wl = (const float*)d_in[9];
  const float* bl = (const float*)d_in[10];
  float* out = (float*)d_out;

  // Base workspace (floats). D-matrix chunk after it.
  float* ws = (float*)d_ws;
  float* x1 = ws;                           // 2,097,152
  float* v = ws + 2097152;                  // 4,194,304
  int* idx = (int*)(ws + 6291456);          // 655,360
  float* d2b = ws + 6946816;                // 32,768
  double* Spart = (double*)(ws + 6979584);  // 128*42 doubles = 10,752 slots
  float* Bc = ws + 6990336;                 // 24,576
  float* cb = ws + 7014912;                 // 128
  float* ss = ws + 7015040;                 // 128
  float* partial = ws + 7015168;            // 65,536 -> end 7,080,704
  const size_t base = 7080704;
  float* D = ws + base;

  if (ws_size < base * sizeof(float)) return;  // fail soft

  // D chunk: prefer the largest power-of-2 cloud count that fits (<= 32);
  // nc=32 -> single kdist+kselect pair per layer (fewest dispatches).
  size_t avail = ws_size / sizeof(float) - base;
  int nc = 0;
  for (int c = 32; c >= 1; c >>= 1)
    if ((size_t)c * 1024 * 1024 <= avail) {
      nc = c;
      break;
    }

  // --- layer 1: kNN on pos (3D) ---
  kd2<<<128, 256, 0, stream>>>(pos, 3, d2b);
  if (nc > 0) {
    for (int c0 = 0; c0 < NB; c0 += nc) {
      kdist<3><<<nc * 64, 256, 0, stream>>>(pos, d2b, c0, D);
      kselect<<<nc * 256, 256, 0, stream>>>(D, c0, idx);
    }
  } else {
    kknn<3><<<512, 256, 0, stream>>>(pos, d2b, idx);
  }

  // --- EdgeConv1 (analytic BN via exact 6-dim moments, atomic-free) ---
  kstats<<<128, 256, 0, stream>>>(pos, idx, Spart);
  kbn<<<1, 64, 0, stream>>>(Spart, W1a, b1a, g1, be1, ss);
  kec1<<<NPTS / EC1P, 256, 0, stream>>>(pos, idx, ss, W1a, b1a, W1b, b1b, x1);

  // --- layer 2: kNN on x1 (64D) ---
  kd2<<<128, 256, 0, stream>>>(x1, 64, d2b);
  if (nc > 0) {
    for (int c0 = 0; c0 < NB; c0 += nc) {
      kdist<64><<<nc * 64, 256, 0, stream>>>(x1, d2b, c0, D);
      kselect<<<nc * 256, 256, 0, stream>>>(D, c0, idx);
    }
  } else {
    kknn<64><<<512, 256, 0, stream>>>(x1, d2b, idx);
  }

  // --- EdgeConv2 factored + fused final linear + pool ---
  kv<<<512, 256, 0, stream>>>(x1, W2, v);
  kprep<<<32, 256, 0, stream>>>(W2, Wl, b2, bl, Bc, cb);
  kgemm<<<512, 256, 0, stream>>>(x1, v, idx, Bc, partial);
  kred<<<16, 256, 0, stream>>>(partial, cb, out);
}

// Round 10
// 450.264 us; speedup vs baseline: 1.1179x; 1.0022x over previous
//
#include <hip/hip_runtime.h>
#include <cfloat>
#include <cstdint>

#define NB 32
#define NP 1024
#define NK 20
#define NPTS 32768  // NB*NP

// ---------------------------------------------------------------------------
// d2[p] = sum x^2, SINGLE sequential FMA chain (order-matched with kdist's
// per-acc chain so diagonal dist = fmaf(-2,d2p,2*d2p) = exact 0).
// ---------------------------------------------------------------------------
__global__ __launch_bounds__(256) void kd2(const float* __restrict__ x, int dim,
                                           float* __restrict__ d2) {
  int p = blockIdx.x * 256 + threadIdx.x;
  if (p >= NPTS) return;
  if (dim == 64) {
    const float4* xr = (const float4*)(x + (size_t)p * 64);
    float s = 0.f;
#pragma unroll
    for (int dq = 0; dq < 16; dq++) {
      float4 v = xr[dq];
      s = fmaf(v.x, v.x, s);
      s = fmaf(v.y, v.y, s);
      s = fmaf(v.z, v.z, s);
      s = fmaf(v.w, v.w, s);
    }
    d2[p] = s;
  } else {
    float s = 0.f;
#pragma unroll
    for (int d = 0; d < 3; d++) {
      float v = x[p * 3 + d];
      s = fmaf(v, v, s);
    }
    d2[p] = s;
  }
}

// ---------------------------------------------------------------------------
// kdist: full per-cloud distance matrix, 128x128 tile per block.
// ---------------------------------------------------------------------------
template <int DIM>
__global__ __launch_bounds__(256) void kdist(const float* __restrict__ x,
                                             const float* __restrict__ d2,
                                             int c0, float* __restrict__ D) {
  constexpr int KC = (DIM == 64) ? 32 : 3;
  __shared__ float As[KC][132];
  __shared__ float Bs[KC][132];
  const int tid = threadIdx.x;
  const int cloud = blockIdx.x >> 6;  // within chunk
  const int t = blockIdx.x & 63;
  const int tr0 = (t >> 3) * 128, tc0 = (t & 7) * 128;
  const int cb = (c0 + cloud) * 1024;
  const int tr = tid >> 4, tc = tid & 15;

  float acc[8][8];
#pragma unroll
  for (int i = 0; i < 8; i++)
#pragma unroll
    for (int j = 0; j < 8; j++) acc[i][j] = 0.f;

  for (int kc = 0; kc < DIM; kc += KC) {
    __syncthreads();
    if constexpr (DIM == 64) {
      const int row = tid >> 1, seg = tid & 1;
      const float4* sa = (const float4*)(x + (size_t)(cb + tr0 + row) * 64 + kc + seg * 16);
      const float4* sb = (const float4*)(x + (size_t)(cb + tc0 + row) * 64 + kc + seg * 16);
#pragma unroll
      for (int i = 0; i < 4; i++) {
        float4 va = sa[i];
        float4 vb = sb[i];
        const int k0 = seg * 16 + i * 4;
        As[k0 + 0][row] = va.x;
        As[k0 + 1][row] = va.y;
        As[k0 + 2][row] = va.z;
        As[k0 + 3][row] = va.w;
        Bs[k0 + 0][row] = vb.x;
        Bs[k0 + 1][row] = vb.y;
        Bs[k0 + 2][row] = vb.z;
        Bs[k0 + 3][row] = vb.w;
      }
    } else {
      if (tid < 128) {
#pragma unroll
        for (int d = 0; d < 3; d++) {
          As[d][tid] = x[(size_t)(cb + tr0 + tid) * 3 + d];
          Bs[d][tid] = x[(size_t)(cb + tc0 + tid) * 3 + d];
        }
      }
    }
    __syncthreads();
#pragma unroll
    for (int k = 0; k < KC; k++) {
      float a[8], b[8];
      *(float4*)&a[0] = *(const float4*)&As[k][tr * 8];
      *(float4*)&a[4] = *(const float4*)&As[k][tr * 8 + 4];
      *(float4*)&b[0] = *(const float4*)&Bs[k][tc * 8];
      *(float4*)&b[4] = *(const float4*)&Bs[k][tc * 8 + 4];
#pragma unroll
      for (int i = 0; i < 8; i++)
#pragma unroll
        for (int j = 0; j < 8; j++) acc[i][j] = fmaf(a[i], b[j], acc[i][j]);
    }
  }
  float d2r[8], d2c[8];
#pragma unroll
  for (int i = 0; i < 8; i++) d2r[i] = d2[cb + tr0 + tr * 8 + i];
#pragma unroll
  for (int j = 0; j < 8; j++) d2c[j] = d2[cb + tc0 + tc * 8 + j];
#pragma unroll
  for (int i = 0; i < 8; i++) {
    float o[8];
#pragma unroll
    for (int j = 0; j < 8; j++) o[j] = fmaf(-2.f, acc[i][j], d2r[i] + d2c[j]);
    float* dst = &D[(size_t)(cloud * 1024 + tr0 + tr * 8 + i) * 1024 + tc0 + tc * 8];
    *(float4*)&dst[0] = *(const float4*)&o[0];
    *(float4*)&dst[4] = *(const float4*)&o[4];
  }
}

// ---------------------------------------------------------------------------
// kselect: exact top-20 via pivot selection (keys distinct by construction).
// ---------------------------------------------------------------------------
__global__ __launch_bounds__(256) void kselect(const float* __restrict__ D,
                                               int c0, int* __restrict__ idxo) {
  __shared__ unsigned long long lw[4][64];
  const int lane = threadIdx.x & 63;
  const int sub = threadIdx.x >> 6;
  const int pchunk = blockIdx.x * 4 + sub;  // point within chunk
  const int pg = c0 * 1024 + pchunk;        // global point
  const int gbase = (pg >> 10) << 10;       // cloud base (global)

  unsigned long long key[16];
  const float4* dr = (const float4*)(D + (size_t)pchunk * 1024 + lane * 4);
#pragma unroll
  for (int i = 0; i < 4; i++) {
    float4 d4 = dr[i * 64];  // q = i*256 + lane*4 ..+3
    float dv[4] = {d4.x, d4.y, d4.z, d4.w};
#pragma unroll
    for (int j = 0; j < 4; j++) {
      unsigned int u = __float_as_uint(dv[j]);
      u ^= (((int)u >> 31) | 0x80000000u);  // sortable transform
      key[i * 4 + j] = ((unsigned long long)u << 10) | (unsigned)(i * 256 + lane * 4 + j);
    }
  }

  unsigned long long mn = key[0], mx = key[0];
#pragma unroll
  for (int i = 1; i < 16; i++) {
    mn = key[i] < mn ? key[i] : mn;
    mx = key[i] > mx ? key[i] : mx;
  }
#pragma unroll
  for (int s = 1; s < 64; s <<= 1) {
    unsigned long long a = __shfl_xor(mn, s, 64);
    unsigned long long b = __shfl_xor(mx, s, 64);
    mn = a < mn ? a : mn;
    mx = b > mx ? b : mx;
  }
  unsigned long long lo = mn, hi = mx + 1, mid = hi;
  bool found = false;
  for (int it = 0; it < 48 && !found; ++it) {
    unsigned long long m2 = lo + ((hi - lo) >> 1);
    int cnt = 0;
#pragma unroll
    for (int i = 0; i < 16; i++) cnt += (key[i] < m2) ? 1 : 0;
#pragma unroll
    for (int s = 1; s < 64; s <<= 1) cnt += __shfl_xor(cnt, s, 64);
    if (cnt < 20)
      lo = m2;
    else if (cnt > 63)
      hi = m2;
    else {
      mid = m2;
      found = true;
    }
  }

  unsigned int mask = 0;
#pragma unroll
  for (int i = 0; i < 16; i++) mask |= (key[i] < mid) ? (1u << i) : 0u;
  const int lc = __popc(mask);
  int x = lc;
#pragma unroll
  for (int s = 1; s < 64; s <<= 1) {
    int y = __shfl_up(x, s, 64);
    if (lane >= s) x += y;
  }
  int off = x - lc;                    // exclusive prefix
  const int ctot = __shfl(x, 63, 64);  // total candidates
  const int c = ctot < 64 ? ctot : 64;
  unsigned long long* w = lw[sub];
#pragma unroll
  for (int i = 0; i < 16; i++) {
    if ((mask & (1u << i)) && off < 64) {
      w[off] = key[i];
      off++;
    }
  }
  __builtin_amdgcn_wave_barrier();

  const unsigned long long K = w[lane < c ? lane : 0];
  int rank = 0;
  for (int m = 0; m < c; m++) {
    const unsigned long long Km = w[m];  // broadcast read
    rank += (K > Km) ? 1 : 0;
  }
  if (lane < c && rank < NK)
    idxo[(size_t)pg * NK + rank] = gbase + (int)(K & 1023u);
}

// ---------------------------------------------------------------------------
// FALLBACK kNN (used only if ws_size can't fit a 1-cloud distance matrix).
// ---------------------------------------------------------------------------
template <int DIM>
__global__ __launch_bounds__(256) void kknn(const float* __restrict__ x,
                                            const float* __restrict__ d2,
                                            int* __restrict__ idxo) {
  constexpr int STR = (DIM == 64) ? 68 : 4;
  __shared__ float smem[10240];
  float* tile = smem;
  float* dt = smem + 64 * STR;
  float* mD = smem;
  int* mI = (int*)(smem + 5120);

  const int tid = threadIdx.x;
  const int pt = tid & 63;
  const int qt = tid >> 6;
  const int cloud = blockIdx.x >> 4;
  const int blk = blockIdx.x & 15;
  const int p = cloud * 1024 + blk * 64 + pt;
  const int cbase = cloud * 1024;

  float xp[DIM];
#pragma unroll
  for (int d = 0; d < DIM; d++) xp[d] = x[(size_t)p * DIM + d];
  const float d2p = d2[p];

  float bd[NK];
  int bi[NK];
#pragma unroll
  for (int s = 0; s < NK; s++) {
    bd[s] = FLT_MAX;
    bi[s] = 0x7fffffff;
  }
  float wd = FLT_MAX;
  int wi = 0x7fffffff;
  int wsl = 0;

  for (int t = 0; t < 16; t++) {
    __syncthreads();
    if (tid < 64) {
#pragma unroll
      for (int d = 0; d < DIM; d++) tile[tid * STR + d] = x[(size_t)(cbase + t * 64 + tid) * DIM + d];
      dt[tid] = d2[cbase + t * 64 + tid];
    }
    __syncthreads();
    for (int jj = 0; jj < 16; jj++) {
      const int j = jj * 4 + qt;
      float s = 0.f;
#pragma unroll
      for (int d = 0; d < DIM; d++) s = fmaf(xp[d], tile[j * STR + d], s);
      const float dist = fmaf(-2.f, s, d2p + dt[j]);
      const int qg = cbase + t * 64 + j;
      const bool ins = (dist < wd) || (dist == wd && qg < wi);
      if (ins) {
#pragma unroll
        for (int sl = 0; sl < NK; sl++)
          if (sl == wsl) {
            bd[sl] = dist;
            bi[sl] = qg;
          }
        wd = bd[0];
        wi = bi[0];
        wsl = 0;
#pragma unroll
        for (int sl = 1; sl < NK; sl++) {
          const bool worse = (bd[sl] > wd) || (bd[sl] == wd && bi[sl] > wi);
          if (worse) {
            wd = bd[sl];
            wi = bi[sl];
            wsl = sl;
          }
        }
      }
    }
  }
  __syncthreads();
#pragma unroll
  for (int s = 0; s < NK; s++) {
    mD[pt * 80 + qt * 20 + s] = bd[s];
    mI[pt * 80 + qt * 20 + s] = bi[s];
  }
  __syncthreads();
  if (tid < 128) {
    const int pt2 = tid >> 1, h = tid & 1;
    const int base = pt2 * 80 + h * 40;
    float cd[40];
    int ci[40];
#pragma unroll
    for (int a = 0; a < 40; a++) {
      cd[a] = mD[base + a];
      ci[a] = mI[base + a];
    }
    int rank[40];
#pragma unroll
    for (int a = 0; a < 40; a++) rank[a] = 0;
#pragma unroll
    for (int a = 0; a < 40; a++)
#pragma unroll
      for (int b = a + 1; b < 40; b++) {
        const bool abet = (cd[a] < cd[b]) || (cd[a] == cd[b] && ci[a] < ci[b]);
        if (abet)
          rank[b]++;
        else
          rank[a]++;
      }
#pragma unroll
    for (int a = 0; a < 40; a++)
      if (rank[a] < NK) {
        mD[base + rank[a]] = cd[a];
        mI[base + rank[a]] = ci[a];
      }
  }
  __syncthreads();
  if (tid < 64) {
    const int base = tid * 80;
    float cd[40];
    int ci[40];
#pragma unroll
    for (int a = 0; a < 20; a++) {
      cd[a] = mD[base + a];
      ci[a] = mI[base + a];
      cd[20 + a] = mD[base + 40 + a];
      ci[20 + a] = mI[base + 40 + a];
    }
    int rank[40];
#pragma unroll
    for (int a = 0; a < 40; a++) rank[a] = 0;
#pragma unroll
    for (int a = 0; a < 40; a++)
#pragma unroll
      for (int b = a + 1; b < 40; b++) {
        const bool abet = (cd[a] < cd[b]) || (cd[a] == cd[b] && ci[a] < ci[b]);
        if (abet)
          rank[b]++;
        else
          rank[a]++;
      }
    const int po = cloud * 1024 + blk * 64 + tid;
#pragma unroll
    for (int a = 0; a < 40; a++)
      if (rank[a] < NK) idxo[(size_t)po * NK + rank[a]] = ci[a];
  }
}

// ---------------------------------------------------------------------------
// Edge moments, atomic-free: wave butterfly -> LDS cross-wave -> per-block
// partial (double). kbn reduces the 128 partials.
// ---------------------------------------------------------------------------
__global__ __launch_bounds__(256) void kstats(const float* __restrict__ pos,
                                              const int* __restrict__ idx,
                                              double* __restrict__ Spart) {
  __shared__ float red[4][42];
  const int tid = threadIdx.x;
  const int w = tid >> 6;
  int p = blockIdx.x * 256 + tid;
  float xi0 = pos[p * 3], xi1 = pos[p * 3 + 1], xi2 = pos[p * 3 + 2];
  float s1[6];
  float s2[36];
#pragma unroll
  for (int a = 0; a < 6; a++) s1[a] = 0.f;
#pragma unroll
  for (int a = 0; a < 36; a++) s2[a] = 0.f;
  for (int k = 0; k < NK; k++) {
    int j = idx[p * NK + k];
    float e[6];
    e[0] = xi0;
    e[1] = xi1;
    e[2] = xi2;
    e[3] = pos[j * 3] - xi0;
    e[4] = pos[j * 3 + 1] - xi1;
    e[5] = pos[j * 3 + 2] - xi2;
#pragma unroll
    for (int a = 0; a < 6; a++) {
      s1[a] += e[a];
#pragma unroll
      for (int b = 0; b < 6; b++) s2[a * 6 + b] = fmaf(e[a], e[b], s2[a * 6 + b]);
    }
  }
#pragma unroll
  for (int a = 0; a < 6; a++) {
#pragma unroll
    for (int m = 1; m < 64; m <<= 1) s1[a] += __shfl_xor(s1[a], m, 64);
  }
#pragma unroll
  for (int a = 0; a < 36; a++) {
#pragma unroll
    for (int m = 1; m < 64; m <<= 1) s2[a] += __shfl_xor(s2[a], m, 64);
  }
  if ((tid & 63) == 0) {
#pragma unroll
    for (int a = 0; a < 6; a++) red[w][a] = s1[a];
#pragma unroll
    for (int a = 0; a < 36; a++) red[w][6 + a] = s2[a];
  }
  __syncthreads();
  if (tid < 42) {
    double t = (double)red[0][tid] + (double)red[1][tid] + (double)red[2][tid] +
               (double)red[3][tid];
    Spart[(size_t)blockIdx.x * 42 + tid] = t;
  }
}

// BN scale/shift from moments (reduce 128 partials, then exact in double)
__global__ void kbn(const double* __restrict__ Spart, const float* __restrict__ W1a,
                    const float* __restrict__ b1a, const float* __restrict__ g1,
                    const float* __restrict__ be1, float* __restrict__ ss) {
  __shared__ double S[42];
  int c = threadIdx.x;  // 64
  if (c < 42) {
    double t = 0.0;
    for (int b = 0; b < 128; b++) t += Spart[(size_t)b * 42 + c];
    S[c] = t;
  }
  __syncthreads();
  double w[6];
#pragma unroll
  for (int d = 0; d < 6; d++) w[d] = (double)W1a[d * 64 + c];
  double b = (double)b1a[c];
  const double invN = 1.0 / (double)((size_t)NPTS * NK);
  double m1 = 0.0;
#pragma unroll
  for (int d = 0; d < 6; d++) m1 += w[d] * S[d];
  m1 *= invN;
  double q = 0.0;
#pragma unroll
  for (int a = 0; a < 6; a++)
#pragma unroll
    for (int d = 0; d < 6; d++) q += w[a] * w[d] * S[6 + a * 6 + d];
  q *= invN;
  double mu = m1 + b;
  double eh2 = q + 2.0 * b * m1 + b * b;
  double var = eh2 - mu * mu;
  if (var < 0.0) var = 0.0;
  double inv = 1.0 / sqrt(var + 1e-5);
  double sc = (double)g1[c] * inv;
  ss[c] = (float)sc;
  ss[64 + c] = (float)((double)be1[c] - mu * sc);
}

// ---------------------------------------------------------------------------
// EdgeConv1 fused v5 — BARRIER-FREE. Block = 8 points, but each WAVE owns 2
// points (40 edges) end-to-end with a private LDS slice: gather -> z -> GEMM
// -> in-register max -> store. No __syncthreads; the 4 waves de-phase so
// phase-1 LDS writes, phase-2 VALU+VMEM, and stores overlap across waves
// (R6-R9 showed the 3-barrier phase-locked version pins VALUBusy at ~52%).
// Phase 3 is register-only: per-lane partial max over its 5 acc rows, then a
// 3-stage shfl_xor butterfly across the row-octet. fmaxf is exact/order-free
// and per-output FMA chains are unchanged -> bit-identical x1.
// ---------------------------------------------------------------------------
#define EC1P 8
__global__ __launch_bounds__(256) void kec1(const float* __restrict__ pos,
                                            const int* __restrict__ idx,
                                            const float* __restrict__ ss,
                                            const float* __restrict__ W1a,
                                            const float* __restrict__ b1a,
                                            const float* __restrict__ W1b,
                                            const float* __restrict__ b1b,
                                            float* __restrict__ x1) {
  __shared__ float Z[4][40 * 68];   // 43520 B, per-wave private slices
  __shared__ float nbr[4][40 * 4];  // 2560 B
  const int tid = threadIdx.x;
  const int lane = tid & 63;
  const int w = tid >> 6;
  const int p0 = blockIdx.x * EC1P + w * 2;  // this wave's 2 points

  float* Zw = Z[w];
  float* nb = nbr[w];

  // gather this wave's 40 neighbor coords (lanes 0..39)
  if (lane < 40) {
    const int j = idx[(size_t)p0 * NK + lane];
    nb[lane * 4 + 0] = pos[j * 3 + 0];
    nb[lane * 4 + 1] = pos[j * 3 + 1];
    nb[lane * 4 + 2] = pos[j * 3 + 2];
  }

  float wdf[3], wbt[3];
#pragma unroll
  for (int d = 0; d < 3; d++) {
    const float top = W1a[d * 64 + lane];
    const float bot = W1a[(3 + d) * 64 + lane];
    wdf[d] = top - bot;
    wbt[d] = bot;
  }
  const float b1 = b1a[lane];
  const float sc = ss[lane];
  const float sh = ss[64 + lane];
  __builtin_amdgcn_wave_barrier();  // order nbr writes before reads (free)

  // phase 1: 40 z rows into this wave's slice (lane = channel)
#pragma unroll
  for (int pp = 0; pp < 2; pp++) {
    const int p = p0 + pp;
    const float xi0 = pos[p * 3], xi1 = pos[p * 3 + 1], xi2 = pos[p * 3 + 2];
    const float pu = fmaf(xi2, wdf[2], fmaf(xi1, wdf[1], fmaf(xi0, wdf[0], b1)));
    for (int k = 0; k < NK; k++) {
      const float4 nbv = *(const float4*)&nb[(pp * NK + k) * 4];  // broadcast
      const float pv = fmaf(nbv.z, wbt[2], fmaf(nbv.y, wbt[1], nbv.x * wbt[0]));
      Zw[(pp * NK + k) * 68 + lane] = fmaxf(fmaf(pu + pv, sc, sh), 0.f);
    }
  }

  // phase 2: Y(40x64) = Zw(40x64) @ W1b(64x64); lane = (r,c) in 8x8 grid,
  // rows r+8i (i<5), cols c*8..c*8+7. B streamed from global (L1), row at a
  // time with immediate FMA (no spill — R8 lesson).
  const int r = lane >> 3, c = lane & 7;
  float acc[5][8];
#pragma unroll
  for (int i = 0; i < 5; i++)
#pragma unroll
    for (int n = 0; n < 8; n++) acc[i][n] = 0.f;

#pragma unroll
  for (int d4 = 0; d4 < 16; d4++) {
    float4 a4[5];
#pragma unroll
    for (int i = 0; i < 5; i++)
      a4[i] = *(const float4*)&Zw[(r + 8 * i) * 68 + d4 * 4];
#pragma unroll
    for (int rr = 0; rr < 4; rr++) {
      float b[8];
      *(float4*)&b[0] = *(const float4*)&W1b[(d4 * 4 + rr) * 64 + c * 8];
      *(float4*)&b[4] = *(const float4*)&W1b[(d4 * 4 + rr) * 64 + c * 8 + 4];
#pragma unroll
      for (int i = 0; i < 5; i++) {
        const float ar = (rr == 0) ? a4[i].x : (rr == 1) ? a4[i].y : (rr == 2) ? a4[i].z : a4[i].w;
#pragma unroll
        for (int n = 0; n < 8; n++) acc[i][n] = fmaf(ar, b[n], acc[i][n]);
      }
    }
  }

  // phase 3 (register-only): rows r+8i — point A rows {i=0,1} ∪ {i=2 if r<4};
  // point B rows {i=2 if r>=4} ∪ {i=3,4}. Partial max per lane, then butterfly
  // max across the 8 r-lanes (xor 8,16,32) so all lanes hold the 20-row max.
  float mA[8], mB[8];
#pragma unroll
  for (int n = 0; n < 8; n++) {
    float a = fmaxf(acc[0][n], acc[1][n]);
    float bmax = fmaxf(acc[3][n], acc[4][n]);
    if (r < 4)
      a = fmaxf(a, acc[2][n]);
    else
      bmax = fmaxf(bmax, acc[2][n]);
    mA[n] = a;
    mB[n] = bmax;
  }
#pragma unroll
  for (int s = 8; s < 64; s <<= 1) {
#pragma unroll
    for (int n = 0; n < 8; n++) {
      mA[n] = fmaxf(mA[n], __shfl_xor(mA[n], s, 64));
      mB[n] = fmaxf(mB[n], __shfl_xor(mB[n], s, 64));
    }
  }
  if (r == 0) {
    float bb[8];
    *(float4*)&bb[0] = *(const float4*)&b1b[c * 8];
    *(float4*)&bb[4] = *(const float4*)&b1b[c * 8 + 4];
    float oA[8], oB[8];
#pragma unroll
    for (int n = 0; n < 8; n++) {
      oA[n] = mA[n] + bb[n];
      oB[n] = mB[n] + bb[n];
    }
    float* dA = &x1[(size_t)p0 * 64 + c * 8];
    float* dB = &x1[(size_t)(p0 + 1) * 64 + c * 8];
    *(float4*)&dA[0] = *(const float4*)&oA[0];
    *(float4*)&dA[4] = *(const float4*)&oA[4];
    *(float4*)&dB[0] = *(const float4*)&oB[0];
    *(float4*)&dB[4] = *(const float4*)&oB[4];
  }
}

// v[j,c] = x1_j . W2[64+d][c]
__global__ __launch_bounds__(256) void kv(const float* __restrict__ x1,
                                          const float* __restrict__ W2,
                                          float* __restrict__ v) {
  const int c = threadIdx.x & 127;
  const int sub = threadIdx.x >> 7;
  float wv[64];
#pragma unroll
  for (int d = 0; d < 64; d++) wv[d] = W2[(64 + d) * 128 + c];
  const int pbase = blockIdx.x * 64 + sub * 32;
  for (int i = 0; i < 32; i++) {
    const int p = pbase + i;
    const float4* xr = (const float4*)(x1 + (size_t)p * 64);
    float a0 = 0.f, a1 = 0.f;
#pragma unroll
    for (int dq = 0; dq < 16; dq++) {
      float4 xv = xr[dq];
      a0 = fmaf(xv.x, wv[dq * 4 + 0], a0);
      a1 = fmaf(xv.y, wv[dq * 4 + 1], a1);
      a0 = fmaf(xv.z, wv[dq * 4 + 2], a0);
      a1 = fmaf(xv.w, wv[dq * 4 + 3], a1);
    }
    v[(size_t)p * 128 + c] = a0 + a1;
  }
}

// Bc (192x128) and const bias cb (128)
__global__ __launch_bounds__(256) void kprep(const float* __restrict__ W2,
                                             const float* __restrict__ Wl,
                                             const float* __restrict__ b2,
                                             const float* __restrict__ bl,
                                             float* __restrict__ Bc,
                                             float* __restrict__ cb) {
  const int t = blockIdx.x * 256 + threadIdx.x;  // 8192
  const int d = t >> 7, c = t & 127;
  float s = Wl[d * 128 + c];
  for (int e = 0; e < 128; e++)
    s = fmaf(W2[d * 128 + e] - W2[(64 + d) * 128 + e], Wl[(64 + e) * 128 + c], s);
  Bc[d * 128 + c] = s;
  Bc[(64 + 2 * d) * 128 + c] = Wl[(64 + 2 * d) * 128 + c];
  Bc[(64 + 2 * d + 1) * 128 + c] = Wl[(64 + 2 * d + 1) * 128 + c];
  if (d == 0) {
    float sb = bl[c];
    for (int e = 0; e < 128; e++) sb = fmaf(b2[e], Wl[(64 + e) * 128 + c], sb);
    cb[c] = sb;
  }
}

// Final fused: AT = [x1^T ; maxgather(v)^T], GEMM with Bc, per-tile max.
#define ATS 72
#define BSS 132
__global__ __launch_bounds__(256) void kgemm(const float* __restrict__ x1,
                                             const float* __restrict__ v,
                                             const int* __restrict__ idx,
                                             const float* __restrict__ Bc,
                                             float* __restrict__ partial) {
  __shared__ float AT[192 * ATS];
  __shared__ float BS[16 * BSS];
  int* idxs = (int*)BS;
  const int tid = threadIdx.x;
  const int cloud = blockIdx.x >> 4;
  const int mb = blockIdx.x & 15;
  const int pbase = cloud * 1024 + mb * 64;

#pragma unroll
  for (int r = 0; r < 5; r++) {
    int id = r * 256 + tid;
    idxs[id] = idx[(size_t)pbase * NK + id];
  }
#pragma unroll
  for (int r = 0; r < 16; r++) {
    int id = r * 256 + tid;
    int m = id >> 6, k = id & 63;
    AT[k * ATS + m] = x1[(size_t)(pbase + m) * 64 + k];
  }
  __syncthreads();
#pragma unroll
  for (int r = 0; r < 32; r++) {
    int id = r * 256 + tid;
    int m = id >> 7, kk = id & 127;
    const int* ip = &idxs[m * NK];
    float mx = -FLT_MAX;
#pragma unroll
    for (int k = 0; k < NK; k++) mx = fmaxf(mx, v[(size_t)ip[k] * 128 + kk]);
    AT[(64 + kk) * ATS + m] = mx;
  }
  __syncthreads();

  const int tr = tid >> 4, tc = tid & 15;
  float acc[4][8];
#pragma unroll
  for (int i = 0; i < 4; i++)
#pragma unroll
    for (int n = 0; n < 8; n++) acc[i][n] = 0.f;
  for (int kc = 0; kc < 12; kc++) {
#pragma unroll
    for (int r = 0; r < 8; r++) {
      int id = r * 256 + tid;
      int row = id >> 7, col = id & 127;
      BS[row * BSS + col] = Bc[(size_t)(kc * 16 + row) * 128 + col];
    }
    __syncthreads();
#pragma unroll
    for (int k = 0; k < 16; k++) {
      int kg = kc * 16 + k;
      float4 a = *(const float4*)&AT[kg * ATS + tr * 4];
      float4 b0 = *(const float4*)&BS[k * BSS + tc * 8];
      float4 b1 = *(const float4*)&BS[k * BSS + tc * 8 + 4];
      float av[4] = {a.x, a.y, a.z, a.w};
      float bv[8] = {b0.x, b0.y, b0.z, b0.w, b1.x, b1.y, b1.z, b1.w};
#pragma unroll
      for (int i = 0; i < 4; i++)
#pragma unroll
        for (int n = 0; n < 8; n++) acc[i][n] = fmaf(av[i], bv[n], acc[i][n]);
    }
    __syncthreads();
  }
#pragma unroll
  for (int n = 0; n < 8; n++) {
    float m4 = fmaxf(fmaxf(acc[0][n], acc[1][n]), fmaxf(acc[2][n], acc[3][n]));
    BS[tr * BSS + tc * 8 + n] = m4;
  }
  __syncthreads();
  if (tid < 128) {
    float m = -FLT_MAX;
#pragma unroll
    for (int rr = 0; rr < 16; rr++) m = fmaxf(m, BS[rr * BSS + tid]);
    partial[(size_t)blockIdx.x * 128 + tid] = m;
  }
}

__global__ __launch_bounds__(256) void kred(const float* __restrict__ partial,
                                            const float* __restrict__ cb,
                                            float* __restrict__ out) {
  int t = blockIdx.x * 256 + threadIdx.x;  // 4096
  int b = t >> 7, c = t & 127;
  float m = -FLT_MAX;
#pragma unroll
  for (int mb = 0; mb < 16; mb++) m = fmaxf(m, partial[(size_t)(b * 16 + mb) * 128 + c]);
  out[t] = m + cb[c];
}

// ---------------------------------------------------------------------------
extern "C" void kernel_launch(void* const* d_in, const int* in_sizes, int n_in,
                              void* d_out, int out_size, void* d_ws, size_t ws_size,
                              hipStream_t stream) {
  const float* pos = (const float*)d_in[0];
  const float* W1a = (const float*)d_in[1];
  const float* b1a = (const float*)d_in[2];
  const float* g1 = (const float*)d_in[3];
  const float* be1 = (const float*)d_in[4];
  const float* W1b = (const float*)d_in[5];
  const float* b1b = (const float*)d_in[6];
  const float* W2 = (const float*)d_in[7];
  const float* b2 = (const float*)d_in[8];
  const float* Wl = (const float*)d_in[9];
  const float* bl = (const float*)d_in[10];
  float* out = (float*)d_out;

  // Base workspace (floats). D-matrix chunk after it.
  float* ws = (float*)d_ws;
  float* x1 = ws;                           // 2,097,152
  float* v = ws + 2097152;                  // 4,194,304
  int* idx = (int*)(ws + 6291456);          // 655,360
  float* d2b = ws + 6946816;                // 32,768
  double* Spart = (double*)(ws + 6979584);  // 128*42 doubles = 10,752 slots
  float* Bc = ws + 6990336;                 // 24,576
  float* cb = ws + 7014912;                 // 128
  float* ss = ws + 7015040;                 // 128
  float* partial = ws + 7015168;            // 65,536 -> end 7,080,704
  const size_t base = 7080704;
  float* D = ws + base;

  if (ws_size < base * sizeof(float)) return;  // fail soft

  // D chunk: prefer the largest power-of-2 cloud count that fits (<= 32);
  // nc=32 -> single kdist+kselect pair per layer (fewest dispatches).
  size_t avail = ws_size / sizeof(float) - base;
  int nc = 0;
  for (int c = 32; c >= 1; c >>= 1)
    if ((size_t)c * 1024 * 1024 <= avail) {
      nc = c;
      break;
    }

  // --- layer 1: kNN on pos (3D) ---
  kd2<<<128, 256, 0, stream>>>(pos, 3, d2b);
  if (nc > 0) {
    for (int c0 = 0; c0 < NB; c0 += nc) {
      kdist<3><<<nc * 64, 256, 0, stream>>>(pos, d2b, c0, D);
      kselect<<<nc * 256, 256, 0, stream>>>(D, c0, idx);
    }
  } else {
    kknn<3><<<512, 256, 0, stream>>>(pos, d2b, idx);
  }

  // --- EdgeConv1 (analytic BN via exact 6-dim moments, atomic-free) ---
  kstats<<<128, 256, 0, stream>>>(pos, idx, Spart);
  kbn<<<1, 64, 0, stream>>>(Spart, W1a, b1a, g1, be1, ss);
  kec1<<<NPTS / EC1P, 256, 0, stream>>>(pos, idx, ss, W1a, b1a, W1b, b1b, x1);

  // --- layer 2: kNN on x1 (64D) ---
  kd2<<<128, 256, 0, stream>>>(x1, 64, d2b);
  if (nc > 0) {
    for (int c0 = 0; c0 < NB; c0 += nc) {
      kdist<64><<<nc * 64, 256, 0, stream>>>(x1, d2b, c0, D);
      kselect<<<nc * 256, 256, 0, stream>>>(D, c0, idx);
    }
  } else {
    kknn<64><<<512, 256, 0, stream>>>(x1, d2b, idx);
  }

  // --- EdgeConv2 factored + fused final linear + pool ---
  kv<<<512, 256, 0, stream>>>(x1, W2, v);
  kprep<<<32, 256, 0, stream>>>(W2, Wl, b2, bl, Bc, cb);
  kgemm<<<512, 256, 0, stream>>>(x1, v, idx, Bc, partial);
  kred<<<16, 256, 0, stream>>>(partial, cb, out);
}

// Round 12
// 427.314 us; speedup vs baseline: 1.1779x; 1.0537x over previous
//
#include <hip/hip_runtime.h>
#include <cfloat>
#include <cstdint>

#define NB 32
#define NP 1024
#define NK 20
#define NPTS 32768  // NB*NP

typedef __attribute__((ext_vector_type(8))) short bf16x8;
typedef __attribute__((ext_vector_type(4))) float f32x4;

// ---------------------------------------------------------------------------
// d2[p] = sum x^2, SINGLE sequential FMA chain (order-matched with kdist's
// per-acc chain so diagonal dist = fmaf(-2,d2p,2*d2p) = exact 0).
// ---------------------------------------------------------------------------
__global__ __launch_bounds__(256) void kd2(const float* __restrict__ x, int dim,
                                           float* __restrict__ d2) {
  int p = blockIdx.x * 256 + threadIdx.x;
  if (p >= NPTS) return;
  if (dim == 64) {
    const float4* xr = (const float4*)(x + (size_t)p * 64);
    float s = 0.f;
#pragma unroll
    for (int dq = 0; dq < 16; dq++) {
      float4 v = xr[dq];
      s = fmaf(v.x, v.x, s);
      s = fmaf(v.y, v.y, s);
      s = fmaf(v.z, v.z, s);
      s = fmaf(v.w, v.w, s);
    }
    d2[p] = s;
  } else {
    float s = 0.f;
#pragma unroll
    for (int d = 0; d < 3; d++) {
      float v = x[p * 3 + d];
      s = fmaf(v, v, s);
    }
    d2[p] = s;
  }
}

// ---------------------------------------------------------------------------
// kdist: full per-cloud distance matrix, 128x128 tile per block.
// ---------------------------------------------------------------------------
template <int DIM>
__global__ __launch_bounds__(256) void kdist(const float* __restrict__ x,
                                             const float* __restrict__ d2,
                                             int c0, float* __restrict__ D) {
  constexpr int KC = (DIM == 64) ? 32 : 3;
  __shared__ float As[KC][132];
  __shared__ float Bs[KC][132];
  const int tid = threadIdx.x;
  const int cloud = blockIdx.x >> 6;  // within chunk
  const int t = blockIdx.x & 63;
  const int tr0 = (t >> 3) * 128, tc0 = (t & 7) * 128;
  const int cb = (c0 + cloud) * 1024;
  const int tr = tid >> 4, tc = tid & 15;

  float acc[8][8];
#pragma unroll
  for (int i = 0; i < 8; i++)
#pragma unroll
    for (int j = 0; j < 8; j++) acc[i][j] = 0.f;

  for (int kc = 0; kc < DIM; kc += KC) {
    __syncthreads();
    if constexpr (DIM == 64) {
      const int row = tid >> 1, seg = tid & 1;
      const float4* sa = (const float4*)(x + (size_t)(cb + tr0 + row) * 64 + kc + seg * 16);
      const float4* sb = (const float4*)(x + (size_t)(cb + tc0 + row) * 64 + kc + seg * 16);
#pragma unroll
      for (int i = 0; i < 4; i++) {
        float4 va = sa[i];
        float4 vb = sb[i];
        const int k0 = seg * 16 + i * 4;
        As[k0 + 0][row] = va.x;
        As[k0 + 1][row] = va.y;
        As[k0 + 2][row] = va.z;
        As[k0 + 3][row] = va.w;
        Bs[k0 + 0][row] = vb.x;
        Bs[k0 + 1][row] = vb.y;
        Bs[k0 + 2][row] = vb.z;
        Bs[k0 + 3][row] = vb.w;
      }
    } else {
      if (tid < 128) {
#pragma unroll
        for (int d = 0; d < 3; d++) {
          As[d][tid] = x[(size_t)(cb + tr0 + tid) * 3 + d];
          Bs[d][tid] = x[(size_t)(cb + tc0 + tid) * 3 + d];
        }
      }
    }
    __syncthreads();
#pragma unroll
    for (int k = 0; k < KC; k++) {
      float a[8], b[8];
      *(float4*)&a[0] = *(const float4*)&As[k][tr * 8];
      *(float4*)&a[4] = *(const float4*)&As[k][tr * 8 + 4];
      *(float4*)&b[0] = *(const float4*)&Bs[k][tc * 8];
      *(float4*)&b[4] = *(const float4*)&Bs[k][tc * 8 + 4];
#pragma unroll
      for (int i = 0; i < 8; i++)
#pragma unroll
        for (int j = 0; j < 8; j++) acc[i][j] = fmaf(a[i], b[j], acc[i][j]);
    }
  }
  float d2r[8], d2c[8];
#pragma unroll
  for (int i = 0; i < 8; i++) d2r[i] = d2[cb + tr0 + tr * 8 + i];
#pragma unroll
  for (int j = 0; j < 8; j++) d2c[j] = d2[cb + tc0 + tc * 8 + j];
#pragma unroll
  for (int i = 0; i < 8; i++) {
    float o[8];
#pragma unroll
    for (int j = 0; j < 8; j++) o[j] = fmaf(-2.f, acc[i][j], d2r[i] + d2c[j]);
    float* dst = &D[(size_t)(cloud * 1024 + tr0 + tr * 8 + i) * 1024 + tc0 + tc * 8];
    *(float4*)&dst[0] = *(const float4*)&o[0];
    *(float4*)&dst[4] = *(const float4*)&o[4];
  }
}

// ---------------------------------------------------------------------------
// kselect: exact top-20 via pivot selection (keys distinct by construction).
// ---------------------------------------------------------------------------
__global__ __launch_bounds__(256) void kselect(const float* __restrict__ D,
                                               int c0, int* __restrict__ idxo) {
  __shared__ unsigned long long lw[4][64];
  const int lane = threadIdx.x & 63;
  const int sub = threadIdx.x >> 6;
  const int pchunk = blockIdx.x * 4 + sub;  // point within chunk
  const int pg = c0 * 1024 + pchunk;        // global point
  const int gbase = (pg >> 10) << 10;       // cloud base (global)

  unsigned long long key[16];
  const float4* dr = (const float4*)(D + (size_t)pchunk * 1024 + lane * 4);
#pragma unroll
  for (int i = 0; i < 4; i++) {
    float4 d4 = dr[i * 64];  // q = i*256 + lane*4 ..+3
    float dv[4] = {d4.x, d4.y, d4.z, d4.w};
#pragma unroll
    for (int j = 0; j < 4; j++) {
      unsigned int u = __float_as_uint(dv[j]);
      u ^= (((int)u >> 31) | 0x80000000u);  // sortable transform
      key[i * 4 + j] = ((unsigned long long)u << 10) | (unsigned)(i * 256 + lane * 4 + j);
    }
  }

  unsigned long long mn = key[0], mx = key[0];
#pragma unroll
  for (int i = 1; i < 16; i++) {
    mn = key[i] < mn ? key[i] : mn;
    mx = key[i] > mx ? key[i] : mx;
  }
#pragma unroll
  for (int s = 1; s < 64; s <<= 1) {
    unsigned long long a = __shfl_xor(mn, s, 64);
    unsigned long long b = __shfl_xor(mx, s, 64);
    mn = a < mn ? a : mn;
    mx = b > mx ? b : mx;
  }
  unsigned long long lo = mn, hi = mx + 1, mid = hi;
  bool found = false;
  for (int it = 0; it < 48 && !found; ++it) {
    unsigned long long m2 = lo + ((hi - lo) >> 1);
    int cnt = 0;
#pragma unroll
    for (int i = 0; i < 16; i++) cnt += (key[i] < m2) ? 1 : 0;
#pragma unroll
    for (int s = 1; s < 64; s <<= 1) cnt += __shfl_xor(cnt, s, 64);
    if (cnt < 20)
      lo = m2;
    else if (cnt > 63)
      hi = m2;
    else {
      mid = m2;
      found = true;
    }
  }

  unsigned int mask = 0;
#pragma unroll
  for (int i = 0; i < 16; i++) mask |= (key[i] < mid) ? (1u << i) : 0u;
  const int lc = __popc(mask);
  int x = lc;
#pragma unroll
  for (int s = 1; s < 64; s <<= 1) {
    int y = __shfl_up(x, s, 64);
    if (lane >= s) x += y;
  }
  int off = x - lc;                    // exclusive prefix
  const int ctot = __shfl(x, 63, 64);  // total candidates
  const int c = ctot < 64 ? ctot : 64;
  unsigned long long* w = lw[sub];
#pragma unroll
  for (int i = 0; i < 16; i++) {
    if ((mask & (1u << i)) && off < 64) {
      w[off] = key[i];
      off++;
    }
  }
  __builtin_amdgcn_wave_barrier();

  const unsigned long long K = w[lane < c ? lane : 0];
  int rank = 0;
  for (int m = 0; m < c; m++) {
    const unsigned long long Km = w[m];  // broadcast read
    rank += (K > Km) ? 1 : 0;
  }
  if (lane < c && rank < NK)
    idxo[(size_t)pg * NK + rank] = gbase + (int)(K & 1023u);
}

// ---------------------------------------------------------------------------
// FALLBACK kNN (used only if ws_size can't fit a 1-cloud distance matrix).
// ---------------------------------------------------------------------------
template <int DIM>
__global__ __launch_bounds__(256) void kknn(const float* __restrict__ x,
                                            const float* __restrict__ d2,
                                            int* __restrict__ idxo) {
  constexpr int STR = (DIM == 64) ? 68 : 4;
  __shared__ float smem[10240];
  float* tile = smem;
  float* dt = smem + 64 * STR;
  float* mD = smem;
  int* mI = (int*)(smem + 5120);

  const int tid = threadIdx.x;
  const int pt = tid & 63;
  const int qt = tid >> 6;
  const int cloud = blockIdx.x >> 4;
  const int blk = blockIdx.x & 15;
  const int p = cloud * 1024 + blk * 64 + pt;
  const int cbase = cloud * 1024;

  float xp[DIM];
#pragma unroll
  for (int d = 0; d < DIM; d++) xp[d] = x[(size_t)p * DIM + d];
  const float d2p = d2[p];

  float bd[NK];
  int bi[NK];
#pragma unroll
  for (int s = 0; s < NK; s++) {
    bd[s] = FLT_MAX;
    bi[s] = 0x7fffffff;
  }
  float wd = FLT_MAX;
  int wi = 0x7fffffff;
  int wsl = 0;

  for (int t = 0; t < 16; t++) {
    __syncthreads();
    if (tid < 64) {
#pragma unroll
      for (int d = 0; d < DIM; d++) tile[tid * STR + d] = x[(size_t)(cbase + t * 64 + tid) * DIM + d];
      dt[tid] = d2[cbase + t * 64 + tid];
    }
    __syncthreads();
    for (int jj = 0; jj < 16; jj++) {
      const int j = jj * 4 + qt;
      float s = 0.f;
#pragma unroll
      for (int d = 0; d < DIM; d++) s = fmaf(xp[d], tile[j * STR + d], s);
      const float dist = fmaf(-2.f, s, d2p + dt[j]);
      const int qg = cbase + t * 64 + j;
      const bool ins = (dist < wd) || (dist == wd && qg < wi);
      if (ins) {
#pragma unroll
        for (int sl = 0; sl < NK; sl++)
          if (sl == wsl) {
            bd[sl] = dist;
            bi[sl] = qg;
          }
        wd = bd[0];
        wi = bi[0];
        wsl = 0;
#pragma unroll
        for (int sl = 1; sl < NK; sl++) {
          const bool worse = (bd[sl] > wd) || (bd[sl] == wd && bi[sl] > wi);
          if (worse) {
            wd = bd[sl];
            wi = bi[sl];
            wsl = sl;
          }
        }
      }
    }
  }
  __syncthreads();
#pragma unroll
  for (int s = 0; s < NK; s++) {
    mD[pt * 80 + qt * 20 + s] = bd[s];
    mI[pt * 80 + qt * 20 + s] = bi[s];
  }
  __syncthreads();
  if (tid < 128) {
    const int pt2 = tid >> 1, h = tid & 1;
    const int base = pt2 * 80 + h * 40;
    float cd[40];
    int ci[40];
#pragma unroll
    for (int a = 0; a < 40; a++) {
      cd[a] = mD[base + a];
      ci[a] = mI[base + a];
    }
    int rank[40];
#pragma unroll
    for (int a = 0; a < 40; a++) rank[a] = 0;
#pragma unroll
    for (int a = 0; a < 40; a++)
#pragma unroll
      for (int b = a + 1; b < 40; b++) {
        const bool abet = (cd[a] < cd[b]) || (cd[a] == cd[b] && ci[a] < ci[b]);
        if (abet)
          rank[b]++;
        else
          rank[a]++;
      }
#pragma unroll
    for (int a = 0; a < 40; a++)
      if (rank[a] < NK) {
        mD[base + rank[a]] = cd[a];
        mI[base + rank[a]] = ci[a];
      }
  }
  __syncthreads();
  if (tid < 64) {
    const int base = tid * 80;
    float cd[40];
    int ci[40];
#pragma unroll
    for (int a = 0; a < 20; a++) {
      cd[a] = mD[base + a];
      ci[a] = mI[base + a];
      cd[20 + a] = mD[base + 40 + a];
      ci[20 + a] = mI[base + 40 + a];
    }
    int rank[40];
#pragma unroll
    for (int a = 0; a < 40; a++) rank[a] = 0;
#pragma unroll
    for (int a = 0; a < 40; a++)
#pragma unroll
      for (int b = a + 1; b < 40; b++) {
        const bool abet = (cd[a] < cd[b]) || (cd[a] == cd[b] && ci[a] < ci[b]);
        if (abet)
          rank[b]++;
        else
          rank[a]++;
      }
    const int po = cloud * 1024 + blk * 64 + tid;
#pragma unroll
    for (int a = 0; a < 40; a++)
      if (rank[a] < NK) idxo[(size_t)po * NK + rank[a]] = ci[a];
  }
}

// ---------------------------------------------------------------------------
// Edge moments, atomic-free: wave butterfly -> LDS cross-wave -> per-block
// partial (double). kbn reduces the 128 partials.
// ---------------------------------------------------------------------------
__global__ __launch_bounds__(256) void kstats(const float* __restrict__ pos,
                                              const int* __restrict__ idx,
                                              double* __restrict__ Spart) {
  __shared__ float red[4][42];
  const int tid = threadIdx.x;
  const int w = tid >> 6;
  int p = blockIdx.x * 256 + tid;
  float xi0 = pos[p * 3], xi1 = pos[p * 3 + 1], xi2 = pos[p * 3 + 2];
  float s1[6];
  float s2[36];
#pragma unroll
  for (int a = 0; a < 6; a++) s1[a] = 0.f;
#pragma unroll
  for (int a = 0; a < 36; a++) s2[a] = 0.f;
  for (int k = 0; k < NK; k++) {
    int j = idx[p * NK + k];
    float e[6];
    e[0] = xi0;
    e[1] = xi1;
    e[2] = xi2;
    e[3] = pos[j * 3] - xi0;
    e[4] = pos[j * 3 + 1] - xi1;
    e[5] = pos[j * 3 + 2] - xi2;
#pragma unroll
    for (int a = 0; a < 6; a++) {
      s1[a] += e[a];
#pragma unroll
      for (int b = 0; b < 6; b++) s2[a * 6 + b] = fmaf(e[a], e[b], s2[a * 6 + b]);
    }
  }
#pragma unroll
  for (int a = 0; a < 6; a++) {
#pragma unroll
    for (int m = 1; m < 64; m <<= 1) s1[a] += __shfl_xor(s1[a], m, 64);
  }
#pragma unroll
  for (int a = 0; a < 36; a++) {
#pragma unroll
    for (int m = 1; m < 64; m <<= 1) s2[a] += __shfl_xor(s2[a], m, 64);
  }
  if ((tid & 63) == 0) {
#pragma unroll
    for (int a = 0; a < 6; a++) red[w][a] = s1[a];
#pragma unroll
    for (int a = 0; a < 36; a++) red[w][6 + a] = s2[a];
  }
  __syncthreads();
  if (tid < 42) {
    double t = (double)red[0][tid] + (double)red[1][tid] + (double)red[2][tid] +
               (double)red[3][tid];
    Spart[(size_t)blockIdx.x * 42 + tid] = t;
  }
}

// ---------------------------------------------------------------------------
// kbn: (a) reduce 128 stat partials -> BN scale/shift (exact in double);
//      (b) pre-swizzle W1b into MFMA B-fragment order as bf16 hi/lo pair
//          (B[k][n]: lane L holds n=L&15, k=ks*32+(L>>4)*8+j; stored so each
//          lane reads ushort8 = 16 B contiguous).
// ---------------------------------------------------------------------------
__global__ void kbn(const double* __restrict__ Spart, const float* __restrict__ W1a,
                    const float* __restrict__ b1a, const float* __restrict__ g1,
                    const float* __restrict__ be1, const float* __restrict__ W1b,
                    float* __restrict__ ss, unsigned short* __restrict__ Bh,
                    unsigned short* __restrict__ Bl) {
  __shared__ double S[42];
  const int c = threadIdx.x;  // 256 threads
  if (c < 42) {
    double t = 0.0;
    for (int b = 0; b < 128; b++) t += Spart[(size_t)b * 42 + c];
    S[c] = t;
  }
  // W1b swizzle (all 256 threads)
  for (int t = c; t < 4096; t += 256) {
    const int j = t & 7, L = (t >> 3) & 63, f = t >> 9;  // f = nt*2+ks
    const int nt = f >> 1, ks = f & 1;
    const int k = ks * 32 + (L >> 4) * 8 + j;
    const int n = nt * 16 + (L & 15);
    const float wv = W1b[k * 64 + n];
    const unsigned u = __float_as_uint(wv);
    const unsigned hb = (u + 0x7fffu + ((u >> 16) & 1u)) & 0xffff0000u;  // RNE bf16
    const float hif = __uint_as_float(hb);
    const float lo = wv - hif;
    const unsigned ul = __float_as_uint(lo);
    const unsigned lb = (ul + 0x7fffu + ((ul >> 16) & 1u)) >> 16;
    Bh[t] = (unsigned short)(hb >> 16);
    Bl[t] = (unsigned short)lb;
  }
  __syncthreads();
  if (c < 64) {
    double w[6];
#pragma unroll
    for (int d = 0; d < 6; d++) w[d] = (double)W1a[d * 64 + c];
    double b = (double)b1a[c];
    const double invN = 1.0 / (double)((size_t)NPTS * NK);
    double m1 = 0.0;
#pragma unroll
    for (int d = 0; d < 6; d++) m1 += w[d] * S[d];
    m1 *= invN;
    double q = 0.0;
#pragma unroll
    for (int a = 0; a < 6; a++)
#pragma unroll
      for (int d = 0; d < 6; d++) q += w[a] * w[d] * S[6 + a * 6 + d];
    q *= invN;
    double mu = m1 + b;
    double eh2 = q + 2.0 * b * m1 + b * b;
    double var = eh2 - mu * mu;
    if (var < 0.0) var = 0.0;
    double inv = 1.0 / sqrt(var + 1e-5);
    double sc = (double)g1[c] * inv;
    ss[c] = (float)sc;
    ss[64 + c] = (float)((double)be1[c] - mu * sc);
  }
}

// ---------------------------------------------------------------------------
// EdgeConv1 fused v6 — MFMA. Wave owns 2 points = 40 edge rows (barrier-free,
// the R10 structure that hit 99.8% VALUBusy — now offloading the GEMM to the
// idle matrix pipe). Phase 1 writes Z as bf16 hi/lo DIRECTLY in A-fragment
// order (A[m=lane&15][k=quad*8+j], padded to 48 rows; pad rows excluded from
// max by row guard). Phase 2: Y = Z @ W1b as 3 mt x 4 nt tiles x 2 ksteps x
// 3 split-products (hi*hi + hi*lo + lo*hi, fp32 accum) = 72 MFMAs/wave.
// Phase 3 register-only: row-guarded per-reg max fold + butterfly over quads.
// bf16x3 split error ~3e-5 relative on x1 (vs 2.86e-2 test threshold).
// ---------------------------------------------------------------------------
#define EC1P 8
__global__ __launch_bounds__(256) void kec1(const float* __restrict__ pos,
                                            const int* __restrict__ idx,
                                            const float* __restrict__ ss,
                                            const float* __restrict__ W1a,
                                            const float* __restrict__ b1a,
                                            const unsigned short* __restrict__ Bh,
                                            const unsigned short* __restrict__ Bl,
                                            const float* __restrict__ b1b,
                                            float* __restrict__ x1) {
  // per-wave private: A-frags hi/lo [3 mt][2 ks][64 lanes][8 bf16] = 3072 each
  __shared__ __align__(16) unsigned short Ah[4][3072];
  __shared__ __align__(16) unsigned short Al[4][3072];
  __shared__ float nbr[4][160];
  const int tid = threadIdx.x;
  const int lane = tid & 63;
  const int w = tid >> 6;
  const int p0 = blockIdx.x * EC1P + w * 2;  // this wave's 2 points

  unsigned short* ah = Ah[w];
  unsigned short* al = Al[w];
  float* nb = nbr[w];

  // gather this wave's 40 neighbor coords (lanes 0..39)
  if (lane < 40) {
    const int j = idx[(size_t)p0 * NK + lane];
    nb[lane * 4 + 0] = pos[j * 3 + 0];
    nb[lane * 4 + 1] = pos[j * 3 + 1];
    nb[lane * 4 + 2] = pos[j * 3 + 2];
  }

  // per-lane (channel) parameters for phase 1
  float wdf[3], wbt[3];
#pragma unroll
  for (int d = 0; d < 3; d++) {
    const float top = W1a[d * 64 + lane];
    const float bot = W1a[(3 + d) * 64 + lane];
    wdf[d] = top - bot;
    wbt[d] = bot;
  }
  const float b1 = b1a[lane];
  const float sc = ss[lane];
  const float sh = ss[64 + lane];
  // lane's position inside the A-fragment for its channel (k = lane):
  // ks = lane>>5, quad q = (lane&31)>>3, j = lane&7
  const int lanepart = ((lane >> 5) * 512) + (((lane & 31) >> 3) * 128) + (lane & 7);
  __builtin_amdgcn_wave_barrier();

  // phase 1: z = relu(BN(edge)), split to bf16 hi/lo, store in A-frag order
#pragma unroll
  for (int pp = 0; pp < 2; pp++) {
    const int p = p0 + pp;
    const float xi0 = pos[p * 3], xi1 = pos[p * 3 + 1], xi2 = pos[p * 3 + 2];
    const float pu = fmaf(xi2, wdf[2], fmaf(xi1, wdf[1], fmaf(xi0, wdf[0], b1)));
    for (int k = 0; k < NK; k++) {
      const int row = pp * NK + k;
      const float4 nbv = *(const float4*)&nb[row * 4];  // broadcast
      const float pv = fmaf(nbv.z, wbt[2], fmaf(nbv.y, wbt[1], nbv.x * wbt[0]));
      const float z = fmaxf(fmaf(pu + pv, sc, sh), 0.f);
      const unsigned u = __float_as_uint(z);
      const unsigned hb = (u + 0x7fffu + ((u >> 16) & 1u)) & 0xffff0000u;
      const float hif = __uint_as_float(hb);
      const float lo = z - hif;
      const unsigned ul = __float_as_uint(lo);
      const unsigned lb = (ul + 0x7fffu + ((ul >> 16) & 1u)) >> 16;
      const int off = (row >> 4) * 1024 + (row & 15) * 8 + lanepart;
      ah[off] = (unsigned short)(hb >> 16);
      al[off] = (unsigned short)lb;
    }
  }
  __builtin_amdgcn_wave_barrier();  // in-wave DS ordering guarantees visibility

  // load all B fragments (global, L1-hot): [nt][ks] hi/lo
  bf16x8 bh[4][2], bl[4][2];
#pragma unroll
  for (int nt = 0; nt < 4; nt++)
#pragma unroll
    for (int ks = 0; ks < 2; ks++) {
      const int base = ((nt * 2 + ks) * 64 + lane) * 8;
      bh[nt][ks] = *(const bf16x8*)&Bh[base];
      bl[nt][ks] = *(const bf16x8*)&Bl[base];
    }

  // phase 2+3: MFMA tiles with register-resident row-guarded max
  float pA[4], pB[4];
#pragma unroll
  for (int nt = 0; nt < 4; nt++) {
    pA[nt] = -FLT_MAX;
    pB[nt] = -FLT_MAX;
  }
  const int q4 = (lane >> 4) * 4;  // row offset within m-tile for C regs

#pragma unroll
  for (int mt = 0; mt < 3; mt++) {
    const bf16x8 a_h0 = *(const bf16x8*)&ah[mt * 1024 + lane * 8];
    const bf16x8 a_l0 = *(const bf16x8*)&al[mt * 1024 + lane * 8];
    const bf16x8 a_h1 = *(const bf16x8*)&ah[mt * 1024 + 512 + lane * 8];
    const bf16x8 a_l1 = *(const bf16x8*)&al[mt * 1024 + 512 + lane * 8];
#pragma unroll
    for (int nt = 0; nt < 4; nt++) {
      f32x4 C = {0.f, 0.f, 0.f, 0.f};
      C = __builtin_amdgcn_mfma_f32_16x16x32_bf16(a_h0, bh[nt][0], C, 0, 0, 0);
      C = __builtin_amdgcn_mfma_f32_16x16x32_bf16(a_h0, bl[nt][0], C, 0, 0, 0);
      C = __builtin_amdgcn_mfma_f32_16x16x32_bf16(a_l0, bh[nt][0], C, 0, 0, 0);
      C = __builtin_amdgcn_mfma_f32_16x16x32_bf16(a_h1, bh[nt][1], C, 0, 0, 0);
      C = __builtin_amdgcn_mfma_f32_16x16x32_bf16(a_h1, bl[nt][1], C, 0, 0, 0);
      C = __builtin_amdgcn_mfma_f32_16x16x32_bf16(a_l1, bh[nt][1], C, 0, 0, 0);
#pragma unroll
      for (int r = 0; r < 4; r++) {
        const int row = mt * 16 + q4 + r;
        const float vv = C[r];
        if (row < NK) pA[nt] = fmaxf(pA[nt], vv);
        if (row >= NK && row < 2 * NK) pB[nt] = fmaxf(pB[nt], vv);
      }
    }
  }
  // butterfly over the 4 quads (xor 16, 32)
#pragma unroll
  for (int s = 16; s < 64; s <<= 1) {
#pragma unroll
    for (int nt = 0; nt < 4; nt++) {
      pA[nt] = fmaxf(pA[nt], __shfl_xor(pA[nt], s, 64));
      pB[nt] = fmaxf(pB[nt], __shfl_xor(pB[nt], s, 64));
    }
  }
  if (lane < 16) {
#pragma unroll
    for (int nt = 0; nt < 4; nt++) {
      const float bb = b1b[nt * 16 + lane];
      x1[(size_t)p0 * 64 + nt * 16 + lane] = pA[nt] + bb;
      x1[(size_t)(p0 + 1) * 64 + nt * 16 + lane] = pB[nt] + bb;
    }
  }
}

// v[j,c] = x1_j . W2[64+d][c]
__global__ __launch_bounds__(256) void kv(const float* __restrict__ x1,
                                          const float* __restrict__ W2,
                                          float* __restrict__ v) {
  const int c = threadIdx.x & 127;
  const int sub = threadIdx.x >> 7;
  float wv[64];
#pragma unroll
  for (int d = 0; d < 64; d++) wv[d] = W2[(64 + d) * 128 + c];
  const int pbase = blockIdx.x * 64 + sub * 32;
  for (int i = 0; i < 32; i++) {
    const int p = pbase + i;
    const float4* xr = (const float4*)(x1 + (size_t)p * 64);
    float a0 = 0.f, a1 = 0.f;
#pragma unroll
    for (int dq = 0; dq < 16; dq++) {
      float4 xv = xr[dq];
      a0 = fmaf(xv.x, wv[dq * 4 + 0], a0);
      a1 = fmaf(xv.y, wv[dq * 4 + 1], a1);
      a0 = fmaf(xv.z, wv[dq * 4 + 2], a0);
      a1 = fmaf(xv.w, wv[dq * 4 + 3], a1);
    }
    v[(size_t)p * 128 + c] = a0 + a1;
  }
}

// Bc (192x128) and const bias cb (128)
__global__ __launch_bounds__(256) void kprep(const float* __restrict__ W2,
                                             const float* __restrict__ Wl,
                                             const float* __restrict__ b2,
                                             const float* __restrict__ bl,
                                             float* __restrict__ Bc,
                                             float* __restrict__ cb) {
  const int t = blockIdx.x * 256 + threadIdx.x;  // 8192
  const int d = t >> 7, c = t & 127;
  float s = Wl[d * 128 + c];
  for (int e = 0; e < 128; e++)
    s = fmaf(W2[d * 128 + e] - W2[(64 + d) * 128 + e], Wl[(64 + e) * 128 + c], s);
  Bc[d * 128 + c] = s;
  Bc[(64 + 2 * d) * 128 + c] = Wl[(64 + 2 * d) * 128 + c];
  Bc[(64 + 2 * d + 1) * 128 + c] = Wl[(64 + 2 * d + 1) * 128 + c];
  if (d == 0) {
    float sb = bl[c];
    for (int e = 0; e < 128; e++) sb = fmaf(b2[e], Wl[(64 + e) * 128 + c], sb);
    cb[c] = sb;
  }
}

// Final fused: AT = [x1^T ; maxgather(v)^T], GEMM with Bc, per-tile max.
#define ATS 72
#define BSS 132
__global__ __launch_bounds__(256) void kgemm(const float* __restrict__ x1,
                                             const float* __restrict__ v,
                                             const int* __restrict__ idx,
                                             const float* __restrict__ Bc,
                                             float* __restrict__ partial) {
  __shared__ float AT[192 * ATS];
  __shared__ float BS[16 * BSS];
  int* idxs = (int*)BS;
  const int tid = threadIdx.x;
  const int cloud = blockIdx.x >> 4;
  const int mb = blockIdx.x & 15;
  const int pbase = cloud * 1024 + mb * 64;

#pragma unroll
  for (int r = 0; r < 5; r++) {
    int id = r * 256 + tid;
    idxs[id] = idx[(size_t)pbase * NK + id];
  }
#pragma unroll
  for (int r = 0; r < 16; r++) {
    int id = r * 256 + tid;
    int m = id >> 6, k = id & 63;
    AT[k * ATS + m] = x1[(size_t)(pbase + m) * 64 + k];
  }
  __syncthreads();
#pragma unroll
  for (int r = 0; r < 32; r++) {
    int id = r * 256 + tid;
    int m = id >> 7, kk = id & 127;
    const int* ip = &idxs[m * NK];
    float mx = -FLT_MAX;
#pragma unroll
    for (int k = 0; k < NK; k++) mx = fmaxf(mx, v[(size_t)ip[k] * 128 + kk]);
    AT[(64 + kk) * ATS + m] = mx;
  }
  __syncthreads();

  const int tr = tid >> 4, tc = tid & 15;
  float acc[4][8];
#pragma unroll
  for (int i = 0; i < 4; i++)
#pragma unroll
    for (int n = 0; n < 8; n++) acc[i][n] = 0.f;
  for (int kc = 0; kc < 12; kc++) {
#pragma unroll
    for (int r = 0; r < 8; r++) {
      int id = r * 256 + tid;
      int row = id >> 7, col = id & 127;
      BS[row * BSS + col] = Bc[(size_t)(kc * 16 + row) * 128 + col];
    }
    __syncthreads();
#pragma unroll
    for (int k = 0; k < 16; k++) {
      int kg = kc * 16 + k;
      float4 a = *(const float4*)&AT[kg * ATS + tr * 4];
      float4 b0 = *(const float4*)&BS[k * BSS + tc * 8];
      float4 b1 = *(const float4*)&BS[k * BSS + tc * 8 + 4];
      float av[4] = {a.x, a.y, a.z, a.w};
      float bv[8] = {b0.x, b0.y, b0.z, b0.w, b1.x, b1.y, b1.z, b1.w};
#pragma unroll
      for (int i = 0; i < 4; i++)
#pragma unroll
        for (int n = 0; n < 8; n++) acc[i][n] = fmaf(av[i], bv[n], acc[i][n]);
    }
    __syncthreads();
  }
#pragma unroll
  for (int n = 0; n < 8; n++) {
    float m4 = fmaxf(fmaxf(acc[0][n], acc[1][n]), fmaxf(acc[2][n], acc[3][n]));
    BS[tr * BSS + tc * 8 + n] = m4;
  }
  __syncthreads();
  if (tid < 128) {
    float m = -FLT_MAX;
#pragma unroll
    for (int rr = 0; rr < 16; rr++) m = fmaxf(m, BS[rr * BSS + tid]);
    partial[(size_t)blockIdx.x * 128 + tid] = m;
  }
}

__global__ __launch_bounds__(256) void kred(const float* __restrict__ partial,
                                            const float* __restrict__ cb,
                                            float* __restrict__ out) {
  int t = blockIdx.x * 256 + threadIdx.x;  // 4096
  int b = t >> 7, c = t & 127;
  float m = -FLT_MAX;
#pragma unroll
  for (int mb = 0; mb < 16; mb++) m = fmaxf(m, partial[(size_t)(b * 16 + mb) * 128 + c]);
  out[t] = m + cb[c];
}

// ---------------------------------------------------------------------------
extern "C" void kernel_launch(void* const* d_in, const int* in_sizes, int n_in,
                              void* d_out, int out_size, void* d_ws, size_t ws_size,
                              hipStream_t stream) {
  const float* pos = (const float*)d_in[0];
  const float* W1a = (const float*)d_in[1];
  const float* b1a = (const float*)d_in[2];
  const float* g1 = (const float*)d_in[3];
  const float* be1 = (const float*)d_in[4];
  const float* W1b = (const float*)d_in[5];
  const float* b1b = (const float*)d_in[6];
  const float* W2 = (const float*)d_in[7];
  const float* b2 = (const float*)d_in[8];
  const float* Wl = (const float*)d_in[9];
  const float* bl = (const float*)d_in[10];
  float* out = (float*)d_out;

  // Base workspace (floats). D-matrix chunk after it.
  float* ws = (float*)d_ws;
  float* x1 = ws;                                     // 2,097,152
  float* v = ws + 2097152;                            // 4,194,304
  int* idx = (int*)(ws + 6291456);                    // 655,360
  float* d2b = ws + 6946816;                          // 32,768
  double* Spart = (double*)(ws + 6979584);            // 128*42 doubles = 10,752 slots
  float* Bc = ws + 6990336;                           // 24,576
  float* cb = ws + 7014912;                           // 128
  float* ss = ws + 7015040;                           // 128
  unsigned short* Bh = (unsigned short*)(ws + 7015168);  // 4096 ushort = 2048 fl
  unsigned short* Bl = (unsigned short*)(ws + 7017216);  // 4096 ushort = 2048 fl
  float* partial = ws + 7019264;                      // 65,536 -> end 7,084,800
  const size_t base = 7084800;
  float* D = ws + base;

  if (ws_size < base * sizeof(float)) return;  // fail soft

  // D chunk: prefer the largest power-of-2 cloud count that fits (<= 32);
  // nc=32 -> single kdist+kselect pair per layer (fewest dispatches).
  size_t avail = ws_size / sizeof(float) - base;
  int nc = 0;
  for (int c = 32; c >= 1; c >>= 1)
    if ((size_t)c * 1024 * 1024 <= avail) {
      nc = c;
      break;
    }

  // --- layer 1: kNN on pos (3D) ---
  kd2<<<128, 256, 0, stream>>>(pos, 3, d2b);
  if (nc > 0) {
    for (int c0 = 0; c0 < NB; c0 += nc) {
      kdist<3><<<nc * 64, 256, 0, stream>>>(pos, d2b, c0, D);
      kselect<<<nc * 256, 256, 0, stream>>>(D, c0, idx);
    }
  } else {
    kknn<3><<<512, 256, 0, stream>>>(pos, d2b, idx);
  }

  // --- EdgeConv1 (analytic BN + MFMA edge-GEMM) ---
  kstats<<<128, 256, 0, stream>>>(pos, idx, Spart);
  kbn<<<1, 256, 0, stream>>>(Spart, W1a, b1a, g1, be1, W1b, ss, Bh, Bl);
  kec1<<<NPTS / EC1P, 256, 0, stream>>>(pos, idx, ss, W1a, b1a, Bh, Bl, b1b, x1);

  // --- layer 2: kNN on x1 (64D) ---
  kd2<<<128, 256, 0, stream>>>(x1, 64, d2b);
  if (nc > 0) {
    for (int c0 = 0; c0 < NB; c0 += nc) {
      kdist<64><<<nc * 64, 256, 0, stream>>>(x1, d2b, c0, D);
      kselect<<<nc * 256, 256, 0, stream>>>(D, c0, idx);
    }
  } else {
    kknn<64><<<512, 256, 0, stream>>>(x1, d2b, idx);
  }

  // --- EdgeConv2 factored + fused final linear + pool ---
  kv<<<512, 256, 0, stream>>>(x1, W2, v);
  kprep<<<32, 256, 0, stream>>>(W2, Wl, b2, bl, Bc, cb);
  kgemm<<<512, 256, 0, stream>>>(x1, v, idx, Bc, partial);
  kred<<<16, 256, 0, stream>>>(partial, cb, out);
}

// Round 13
// 393.183 us; speedup vs baseline: 1.2802x; 1.0868x over previous
//
#include <hip/hip_runtime.h>
#include <cfloat>
#include <cstdint>

#define NB 32
#define NP 1024
#define NK 20
#define NPTS 32768  // NB*NP

typedef __attribute__((ext_vector_type(8))) short bf16x8;
typedef __attribute__((ext_vector_type(4))) float f32x4;

// ---------------------------------------------------------------------------
// d2[p] = sum x^2, SINGLE sequential FMA chain (order-matched with kdist's
// per-acc chain so diagonal dist = fmaf(-2,d2p,2*d2p) = exact 0).
// ---------------------------------------------------------------------------
__global__ __launch_bounds__(256) void kd2(const float* __restrict__ x, int dim,
                                           float* __restrict__ d2) {
  int p = blockIdx.x * 256 + threadIdx.x;
  if (p >= NPTS) return;
  if (dim == 64) {
    const float4* xr = (const float4*)(x + (size_t)p * 64);
    float s = 0.f;
#pragma unroll
    for (int dq = 0; dq < 16; dq++) {
      float4 v = xr[dq];
      s = fmaf(v.x, v.x, s);
      s = fmaf(v.y, v.y, s);
      s = fmaf(v.z, v.z, s);
      s = fmaf(v.w, v.w, s);
    }
    d2[p] = s;
  } else {
    float s = 0.f;
#pragma unroll
    for (int d = 0; d < 3; d++) {
      float v = x[p * 3 + d];
      s = fmaf(v, v, s);
    }
    d2[p] = s;
  }
}

// ---------------------------------------------------------------------------
// kdist: full per-cloud distance matrix, 128x128 tile per block.
// XCD swizzle (R13): cloud = blockIdx % nc so all of one cloud's tiles land
// on one XCD (blockIdx%8 heuristic) -> x1 slabs L2-resident, no cross-XCD
// re-fetch (R12: FETCH 33 MB for an 8 MB input).
// ---------------------------------------------------------------------------
template <int DIM>
__global__ __launch_bounds__(256) void kdist(const float* __restrict__ x,
                                             const float* __restrict__ d2,
                                             int c0, int nc, float* __restrict__ D) {
  constexpr int KC = (DIM == 64) ? 32 : 3;
  __shared__ float As[KC][132];
  __shared__ float Bs[KC][132];
  const int tid = threadIdx.x;
  const int cloud = blockIdx.x % nc;  // within chunk (XCD-local)
  const int t = blockIdx.x / nc;
  const int tr0 = (t >> 3) * 128, tc0 = (t & 7) * 128;
  const int cb = (c0 + cloud) * 1024;
  const int tr = tid >> 4, tc = tid & 15;

  float acc[8][8];
#pragma unroll
  for (int i = 0; i < 8; i++)
#pragma unroll
    for (int j = 0; j < 8; j++) acc[i][j] = 0.f;

  for (int kc = 0; kc < DIM; kc += KC) {
    __syncthreads();
    if constexpr (DIM == 64) {
      const int row = tid >> 1, seg = tid & 1;
      const float4* sa = (const float4*)(x + (size_t)(cb + tr0 + row) * 64 + kc + seg * 16);
      const float4* sb = (const float4*)(x + (size_t)(cb + tc0 + row) * 64 + kc + seg * 16);
#pragma unroll
      for (int i = 0; i < 4; i++) {
        float4 va = sa[i];
        float4 vb = sb[i];
        const int k0 = seg * 16 + i * 4;
        As[k0 + 0][row] = va.x;
        As[k0 + 1][row] = va.y;
        As[k0 + 2][row] = va.z;
        As[k0 + 3][row] = va.w;
        Bs[k0 + 0][row] = vb.x;
        Bs[k0 + 1][row] = vb.y;
        Bs[k0 + 2][row] = vb.z;
        Bs[k0 + 3][row] = vb.w;
      }
    } else {
      if (tid < 128) {
#pragma unroll
        for (int d = 0; d < 3; d++) {
          As[d][tid] = x[(size_t)(cb + tr0 + tid) * 3 + d];
          Bs[d][tid] = x[(size_t)(cb + tc0 + tid) * 3 + d];
        }
      }
    }
    __syncthreads();
#pragma unroll
    for (int k = 0; k < KC; k++) {
      float a[8], b[8];
      *(float4*)&a[0] = *(const float4*)&As[k][tr * 8];
      *(float4*)&a[4] = *(const float4*)&As[k][tr * 8 + 4];
      *(float4*)&b[0] = *(const float4*)&Bs[k][tc * 8];
      *(float4*)&b[4] = *(const float4*)&Bs[k][tc * 8 + 4];
#pragma unroll
      for (int i = 0; i < 8; i++)
#pragma unroll
        for (int j = 0; j < 8; j++) acc[i][j] = fmaf(a[i], b[j], acc[i][j]);
    }
  }
  float d2r[8], d2c[8];
#pragma unroll
  for (int i = 0; i < 8; i++) d2r[i] = d2[cb + tr0 + tr * 8 + i];
#pragma unroll
  for (int j = 0; j < 8; j++) d2c[j] = d2[cb + tc0 + tc * 8 + j];
#pragma unroll
  for (int i = 0; i < 8; i++) {
    float o[8];
#pragma unroll
    for (int j = 0; j < 8; j++) o[j] = fmaf(-2.f, acc[i][j], d2r[i] + d2c[j]);
    float* dst = &D[(size_t)(cloud * 1024 + tr0 + tr * 8 + i) * 1024 + tc0 + tc * 8];
    *(float4*)&dst[0] = *(const float4*)&o[0];
    *(float4*)&dst[4] = *(const float4*)&o[4];
  }
}

// ---------------------------------------------------------------------------
// kselect: exact top-20 via pivot selection (keys distinct by construction).
// ---------------------------------------------------------------------------
__global__ __launch_bounds__(256) void kselect(const float* __restrict__ D,
                                               int c0, int* __restrict__ idxo) {
  __shared__ unsigned long long lw[4][64];
  const int lane = threadIdx.x & 63;
  const int sub = threadIdx.x >> 6;
  const int pchunk = blockIdx.x * 4 + sub;  // point within chunk
  const int pg = c0 * 1024 + pchunk;        // global point
  const int gbase = (pg >> 10) << 10;       // cloud base (global)

  unsigned long long key[16];
  const float4* dr = (const float4*)(D + (size_t)pchunk * 1024 + lane * 4);
#pragma unroll
  for (int i = 0; i < 4; i++) {
    float4 d4 = dr[i * 64];  // q = i*256 + lane*4 ..+3
    float dv[4] = {d4.x, d4.y, d4.z, d4.w};
#pragma unroll
    for (int j = 0; j < 4; j++) {
      unsigned int u = __float_as_uint(dv[j]);
      u ^= (((int)u >> 31) | 0x80000000u);  // sortable transform
      key[i * 4 + j] = ((unsigned long long)u << 10) | (unsigned)(i * 256 + lane * 4 + j);
    }
  }

  unsigned long long mn = key[0], mx = key[0];
#pragma unroll
  for (int i = 1; i < 16; i++) {
    mn = key[i] < mn ? key[i] : mn;
    mx = key[i] > mx ? key[i] : mx;
  }
#pragma unroll
  for (int s = 1; s < 64; s <<= 1) {
    unsigned long long a = __shfl_xor(mn, s, 64);
    unsigned long long b = __shfl_xor(mx, s, 64);
    mn = a < mn ? a : mn;
    mx = b > mx ? b : mx;
  }
  unsigned long long lo = mn, hi = mx + 1, mid = hi;
  bool found = false;
  for (int it = 0; it < 48 && !found; ++it) {
    unsigned long long m2 = lo + ((hi - lo) >> 1);
    int cnt = 0;
#pragma unroll
    for (int i = 0; i < 16; i++) cnt += (key[i] < m2) ? 1 : 0;
#pragma unroll
    for (int s = 1; s < 64; s <<= 1) cnt += __shfl_xor(cnt, s, 64);
    if (cnt < 20)
      lo = m2;
    else if (cnt > 63)
      hi = m2;
    else {
      mid = m2;
      found = true;
    }
  }

  unsigned int mask = 0;
#pragma unroll
  for (int i = 0; i < 16; i++) mask |= (key[i] < mid) ? (1u << i) : 0u;
  const int lc = __popc(mask);
  int x = lc;
#pragma unroll
  for (int s = 1; s < 64; s <<= 1) {
    int y = __shfl_up(x, s, 64);
    if (lane >= s) x += y;
  }
  int off = x - lc;                    // exclusive prefix
  const int ctot = __shfl(x, 63, 64);  // total candidates
  const int c = ctot < 64 ? ctot : 64;
  unsigned long long* w = lw[sub];
#pragma unroll
  for (int i = 0; i < 16; i++) {
    if ((mask & (1u << i)) && off < 64) {
      w[off] = key[i];
      off++;
    }
  }
  __builtin_amdgcn_wave_barrier();

  const unsigned long long K = w[lane < c ? lane : 0];
  int rank = 0;
  for (int m = 0; m < c; m++) {
    const unsigned long long Km = w[m];  // broadcast read
    rank += (K > Km) ? 1 : 0;
  }
  if (lane < c && rank < NK)
    idxo[(size_t)pg * NK + rank] = gbase + (int)(K & 1023u);
}

// ---------------------------------------------------------------------------
// FALLBACK kNN (used only if ws_size can't fit a 1-cloud distance matrix).
// ---------------------------------------------------------------------------
template <int DIM>
__global__ __launch_bounds__(256) void kknn(const float* __restrict__ x,
                                            const float* __restrict__ d2,
                                            int* __restrict__ idxo) {
  constexpr int STR = (DIM == 64) ? 68 : 4;
  __shared__ float smem[10240];
  float* tile = smem;
  float* dt = smem + 64 * STR;
  float* mD = smem;
  int* mI = (int*)(smem + 5120);

  const int tid = threadIdx.x;
  const int pt = tid & 63;
  const int qt = tid >> 6;
  const int cloud = blockIdx.x >> 4;
  const int blk = blockIdx.x & 15;
  const int p = cloud * 1024 + blk * 64 + pt;
  const int cbase = cloud * 1024;

  float xp[DIM];
#pragma unroll
  for (int d = 0; d < DIM; d++) xp[d] = x[(size_t)p * DIM + d];
  const float d2p = d2[p];

  float bd[NK];
  int bi[NK];
#pragma unroll
  for (int s = 0; s < NK; s++) {
    bd[s] = FLT_MAX;
    bi[s] = 0x7fffffff;
  }
  float wd = FLT_MAX;
  int wi = 0x7fffffff;
  int wsl = 0;

  for (int t = 0; t < 16; t++) {
    __syncthreads();
    if (tid < 64) {
#pragma unroll
      for (int d = 0; d < DIM; d++) tile[tid * STR + d] = x[(size_t)(cbase + t * 64 + tid) * DIM + d];
      dt[tid] = d2[cbase + t * 64 + tid];
    }
    __syncthreads();
    for (int jj = 0; jj < 16; jj++) {
      const int j = jj * 4 + qt;
      float s = 0.f;
#pragma unroll
      for (int d = 0; d < DIM; d++) s = fmaf(xp[d], tile[j * STR + d], s);
      const float dist = fmaf(-2.f, s, d2p + dt[j]);
      const int qg = cbase + t * 64 + j;
      const bool ins = (dist < wd) || (dist == wd && qg < wi);
      if (ins) {
#pragma unroll
        for (int sl = 0; sl < NK; sl++)
          if (sl == wsl) {
            bd[sl] = dist;
            bi[sl] = qg;
          }
        wd = bd[0];
        wi = bi[0];
        wsl = 0;
#pragma unroll
        for (int sl = 1; sl < NK; sl++) {
          const bool worse = (bd[sl] > wd) || (bd[sl] == wd && bi[sl] > wi);
          if (worse) {
            wd = bd[sl];
            wi = bi[sl];
            wsl = sl;
          }
        }
      }
    }
  }
  __syncthreads();
#pragma unroll
  for (int s = 0; s < NK; s++) {
    mD[pt * 80 + qt * 20 + s] = bd[s];
    mI[pt * 80 + qt * 20 + s] = bi[s];
  }
  __syncthreads();
  if (tid < 128) {
    const int pt2 = tid >> 1, h = tid & 1;
    const int base = pt2 * 80 + h * 40;
    float cd[40];
    int ci[40];
#pragma unroll
    for (int a = 0; a < 40; a++) {
      cd[a] = mD[base + a];
      ci[a] = mI[base + a];
    }
    int rank[40];
#pragma unroll
    for (int a = 0; a < 40; a++) rank[a] = 0;
#pragma unroll
    for (int a = 0; a < 40; a++)
#pragma unroll
      for (int b = a + 1; b < 40; b++) {
        const bool abet = (cd[a] < cd[b]) || (cd[a] == cd[b] && ci[a] < ci[b]);
        if (abet)
          rank[b]++;
        else
          rank[a]++;
      }
#pragma unroll
    for (int a = 0; a < 40; a++)
      if (rank[a] < NK) {
        mD[base + rank[a]] = cd[a];
        mI[base + rank[a]] = ci[a];
      }
  }
  __syncthreads();
  if (tid < 64) {
    const int base = tid * 80;
    float cd[40];
    int ci[40];
#pragma unroll
    for (int a = 0; a < 20; a++) {
      cd[a] = mD[base + a];
      ci[a] = mI[base + a];
      cd[20 + a] = mD[base + 40 + a];
      ci[20 + a] = mI[base + 40 + a];
    }
    int rank[40];
#pragma unroll
    for (int a = 0; a < 40; a++) rank[a] = 0;
#pragma unroll
    for (int a = 0; a < 40; a++)
#pragma unroll
      for (int b = a + 1; b < 40; b++) {
        const bool abet = (cd[a] < cd[b]) || (cd[a] == cd[b] && ci[a] < ci[b]);
        if (abet)
          rank[b]++;
        else
          rank[a]++;
      }
    const int po = cloud * 1024 + blk * 64 + tid;
#pragma unroll
    for (int a = 0; a < 40; a++)
      if (rank[a] < NK) idxo[(size_t)po * NK + rank[a]] = ci[a];
  }
}

// ---------------------------------------------------------------------------
// Edge moments, atomic-free: wave butterfly -> LDS cross-wave -> per-block
// partial (double). kbn reduces the 128 partials.
// ---------------------------------------------------------------------------
__global__ __launch_bounds__(256) void kstats(const float* __restrict__ pos,
                                              const int* __restrict__ idx,
                                              double* __restrict__ Spart) {
  __shared__ float red[4][42];
  const int tid = threadIdx.x;
  const int w = tid >> 6;
  int p = blockIdx.x * 256 + tid;
  float xi0 = pos[p * 3], xi1 = pos[p * 3 + 1], xi2 = pos[p * 3 + 2];
  float s1[6];
  float s2[36];
#pragma unroll
  for (int a = 0; a < 6; a++) s1[a] = 0.f;
#pragma unroll
  for (int a = 0; a < 36; a++) s2[a] = 0.f;
  for (int k = 0; k < NK; k++) {
    int j = idx[p * NK + k];
    float e[6];
    e[0] = xi0;
    e[1] = xi1;
    e[2] = xi2;
    e[3] = pos[j * 3] - xi0;
    e[4] = pos[j * 3 + 1] - xi1;
    e[5] = pos[j * 3 + 2] - xi2;
#pragma unroll
    for (int a = 0; a < 6; a++) {
      s1[a] += e[a];
#pragma unroll
      for (int b = 0; b < 6; b++) s2[a * 6 + b] = fmaf(e[a], e[b], s2[a * 6 + b]);
    }
  }
#pragma unroll
  for (int a = 0; a < 6; a++) {
#pragma unroll
    for (int m = 1; m < 64; m <<= 1) s1[a] += __shfl_xor(s1[a], m, 64);
  }
#pragma unroll
  for (int a = 0; a < 36; a++) {
#pragma unroll
    for (int m = 1; m < 64; m <<= 1) s2[a] += __shfl_xor(s2[a], m, 64);
  }
  if ((tid & 63) == 0) {
#pragma unroll
    for (int a = 0; a < 6; a++) red[w][a] = s1[a];
#pragma unroll
    for (int a = 0; a < 36; a++) red[w][6 + a] = s2[a];
  }
  __syncthreads();
  if (tid < 42) {
    double t = (double)red[0][tid] + (double)red[1][tid] + (double)red[2][tid] +
               (double)red[3][tid];
    Spart[(size_t)blockIdx.x * 42 + tid] = t;
  }
}

// ---------------------------------------------------------------------------
// kbn: (a) reduce 128 stat partials -> BN scale/shift (exact in double);
//      (b) pre-swizzle W1b into MFMA B-fragment order as bf16 hi/lo pair.
// ---------------------------------------------------------------------------
__global__ void kbn(const double* __restrict__ Spart, const float* __restrict__ W1a,
                    const float* __restrict__ b1a, const float* __restrict__ g1,
                    const float* __restrict__ be1, const float* __restrict__ W1b,
                    float* __restrict__ ss, unsigned short* __restrict__ Bh,
                    unsigned short* __restrict__ Bl) {
  __shared__ double S[42];
  const int c = threadIdx.x;  // 256 threads
  if (c < 42) {
    double t = 0.0;
    for (int b = 0; b < 128; b++) t += Spart[(size_t)b * 42 + c];
    S[c] = t;
  }
  // W1b swizzle (all 256 threads)
  for (int t = c; t < 4096; t += 256) {
    const int j = t & 7, L = (t >> 3) & 63, f = t >> 9;  // f = nt*2+ks
    const int nt = f >> 1, ks = f & 1;
    const int k = ks * 32 + (L >> 4) * 8 + j;
    const int n = nt * 16 + (L & 15);
    const float wv = W1b[k * 64 + n];
    const unsigned u = __float_as_uint(wv);
    const unsigned hb = (u + 0x7fffu + ((u >> 16) & 1u)) & 0xffff0000u;  // RNE bf16
    const float hif = __uint_as_float(hb);
    const float lo = wv - hif;
    const unsigned ul = __float_as_uint(lo);
    const unsigned lb = (ul + 0x7fffu + ((ul >> 16) & 1u)) >> 16;
    Bh[t] = (unsigned short)(hb >> 16);
    Bl[t] = (unsigned short)lb;
  }
  __syncthreads();
  if (c < 64) {
    double w[6];
#pragma unroll
    for (int d = 0; d < 6; d++) w[d] = (double)W1a[d * 64 + c];
    double b = (double)b1a[c];
    const double invN = 1.0 / (double)((size_t)NPTS * NK);
    double m1 = 0.0;
#pragma unroll
    for (int d = 0; d < 6; d++) m1 += w[d] * S[d];
    m1 *= invN;
    double q = 0.0;
#pragma unroll
    for (int a = 0; a < 6; a++)
#pragma unroll
      for (int d = 0; d < 6; d++) q += w[a] * w[d] * S[6 + a * 6 + d];
    q *= invN;
    double mu = m1 + b;
    double eh2 = q + 2.0 * b * m1 + b * b;
    double var = eh2 - mu * mu;
    if (var < 0.0) var = 0.0;
    double inv = 1.0 / sqrt(var + 1e-5);
    double sc = (double)g1[c] * inv;
    ss[c] = (float)sc;
    ss[64 + c] = (float)((double)be1[c] - mu * sc);
  }
}

// ---------------------------------------------------------------------------
// EdgeConv1 fused v6 — MFMA (verified R12: kec1 left top-5, absmax 1.95e-3).
// ---------------------------------------------------------------------------
#define EC1P 8
__global__ __launch_bounds__(256) void kec1(const float* __restrict__ pos,
                                            const int* __restrict__ idx,
                                            const float* __restrict__ ss,
                                            const float* __restrict__ W1a,
                                            const float* __restrict__ b1a,
                                            const unsigned short* __restrict__ Bh,
                                            const unsigned short* __restrict__ Bl,
                                            const float* __restrict__ b1b,
                                            float* __restrict__ x1) {
  __shared__ __align__(16) unsigned short Ah[4][3072];
  __shared__ __align__(16) unsigned short Al[4][3072];
  __shared__ float nbr[4][160];
  const int tid = threadIdx.x;
  const int lane = tid & 63;
  const int w = tid >> 6;
  const int p0 = blockIdx.x * EC1P + w * 2;  // this wave's 2 points

  unsigned short* ah = Ah[w];
  unsigned short* al = Al[w];
  float* nb = nbr[w];

  if (lane < 40) {
    const int j = idx[(size_t)p0 * NK + lane];
    nb[lane * 4 + 0] = pos[j * 3 + 0];
    nb[lane * 4 + 1] = pos[j * 3 + 1];
    nb[lane * 4 + 2] = pos[j * 3 + 2];
  }

  float wdf[3], wbt[3];
#pragma unroll
  for (int d = 0; d < 3; d++) {
    const float top = W1a[d * 64 + lane];
    const float bot = W1a[(3 + d) * 64 + lane];
    wdf[d] = top - bot;
    wbt[d] = bot;
  }
  const float b1 = b1a[lane];
  const float sc = ss[lane];
  const float sh = ss[64 + lane];
  const int lanepart = ((lane >> 5) * 512) + (((lane & 31) >> 3) * 128) + (lane & 7);
  __builtin_amdgcn_wave_barrier();

#pragma unroll
  for (int pp = 0; pp < 2; pp++) {
    const int p = p0 + pp;
    const float xi0 = pos[p * 3], xi1 = pos[p * 3 + 1], xi2 = pos[p * 3 + 2];
    const float pu = fmaf(xi2, wdf[2], fmaf(xi1, wdf[1], fmaf(xi0, wdf[0], b1)));
    for (int k = 0; k < NK; k++) {
      const int row = pp * NK + k;
      const float4 nbv = *(const float4*)&nb[row * 4];  // broadcast
      const float pv = fmaf(nbv.z, wbt[2], fmaf(nbv.y, wbt[1], nbv.x * wbt[0]));
      const float z = fmaxf(fmaf(pu + pv, sc, sh), 0.f);
      const unsigned u = __float_as_uint(z);
      const unsigned hb = (u + 0x7fffu + ((u >> 16) & 1u)) & 0xffff0000u;
      const float hif = __uint_as_float(hb);
      const float lo = z - hif;
      const unsigned ul = __float_as_uint(lo);
      const unsigned lb = (ul + 0x7fffu + ((ul >> 16) & 1u)) >> 16;
      const int off = (row >> 4) * 1024 + (row & 15) * 8 + lanepart;
      ah[off] = (unsigned short)(hb >> 16);
      al[off] = (unsigned short)lb;
    }
  }
  __builtin_amdgcn_wave_barrier();

  bf16x8 bh[4][2], bl[4][2];
#pragma unroll
  for (int nt = 0; nt < 4; nt++)
#pragma unroll
    for (int ks = 0; ks < 2; ks++) {
      const int base = ((nt * 2 + ks) * 64 + lane) * 8;
      bh[nt][ks] = *(const bf16x8*)&Bh[base];
      bl[nt][ks] = *(const bf16x8*)&Bl[base];
    }

  float pA[4], pB[4];
#pragma unroll
  for (int nt = 0; nt < 4; nt++) {
    pA[nt] = -FLT_MAX;
    pB[nt] = -FLT_MAX;
  }
  const int q4 = (lane >> 4) * 4;

#pragma unroll
  for (int mt = 0; mt < 3; mt++) {
    const bf16x8 a_h0 = *(const bf16x8*)&ah[mt * 1024 + lane * 8];
    const bf16x8 a_l0 = *(const bf16x8*)&al[mt * 1024 + lane * 8];
    const bf16x8 a_h1 = *(const bf16x8*)&ah[mt * 1024 + 512 + lane * 8];
    const bf16x8 a_l1 = *(const bf16x8*)&al[mt * 1024 + 512 + lane * 8];
#pragma unroll
    for (int nt = 0; nt < 4; nt++) {
      f32x4 C = {0.f, 0.f, 0.f, 0.f};
      C = __builtin_amdgcn_mfma_f32_16x16x32_bf16(a_h0, bh[nt][0], C, 0, 0, 0);
      C = __builtin_amdgcn_mfma_f32_16x16x32_bf16(a_h0, bl[nt][0], C, 0, 0, 0);
      C = __builtin_amdgcn_mfma_f32_16x16x32_bf16(a_l0, bh[nt][0], C, 0, 0, 0);
      C = __builtin_amdgcn_mfma_f32_16x16x32_bf16(a_h1, bh[nt][1], C, 0, 0, 0);
      C = __builtin_amdgcn_mfma_f32_16x16x32_bf16(a_h1, bl[nt][1], C, 0, 0, 0);
      C = __builtin_amdgcn_mfma_f32_16x16x32_bf16(a_l1, bh[nt][1], C, 0, 0, 0);
#pragma unroll
      for (int r = 0; r < 4; r++) {
        const int row = mt * 16 + q4 + r;
        const float vv = C[r];
        if (row < NK) pA[nt] = fmaxf(pA[nt], vv);
        if (row >= NK && row < 2 * NK) pB[nt] = fmaxf(pB[nt], vv);
      }
    }
  }
#pragma unroll
  for (int s = 16; s < 64; s <<= 1) {
#pragma unroll
    for (int nt = 0; nt < 4; nt++) {
      pA[nt] = fmaxf(pA[nt], __shfl_xor(pA[nt], s, 64));
      pB[nt] = fmaxf(pB[nt], __shfl_xor(pB[nt], s, 64));
    }
  }
  if (lane < 16) {
#pragma unroll
    for (int nt = 0; nt < 4; nt++) {
      const float bb = b1b[nt * 16 + lane];
      x1[(size_t)p0 * 64 + nt * 16 + lane] = pA[nt] + bb;
      x1[(size_t)(p0 + 1) * 64 + nt * 16 + lane] = pB[nt] + bb;
    }
  }
}

// v[j,c] = x1_j . W2[64+d][c]
__global__ __launch_bounds__(256) void kv(const float* __restrict__ x1,
                                          const float* __restrict__ W2,
                                          float* __restrict__ v) {
  const int c = threadIdx.x & 127;
  const int sub = threadIdx.x >> 7;
  float wv[64];
#pragma unroll
  for (int d = 0; d < 64; d++) wv[d] = W2[(64 + d) * 128 + c];
  const int pbase = blockIdx.x * 64 + sub * 32;
  for (int i = 0; i < 32; i++) {
    const int p = pbase + i;
    const float4* xr = (const float4*)(x1 + (size_t)p * 64);
    float a0 = 0.f, a1 = 0.f;
#pragma unroll
    for (int dq = 0; dq < 16; dq++) {
      float4 xv = xr[dq];
      a0 = fmaf(xv.x, wv[dq * 4 + 0], a0);
      a1 = fmaf(xv.y, wv[dq * 4 + 1], a1);
      a0 = fmaf(xv.z, wv[dq * 4 + 2], a0);
      a1 = fmaf(xv.w, wv[dq * 4 + 3], a1);
    }
    v[(size_t)p * 128 + c] = a0 + a1;
  }
}

// Bc (192x128) and const bias cb (128)
__global__ __launch_bounds__(256) void kprep(const float* __restrict__ W2,
                                             const float* __restrict__ Wl,
                                             const float* __restrict__ b2,
                                             const float* __restrict__ bl,
                                             float* __restrict__ Bc,
                                             float* __restrict__ cb) {
  const int t = blockIdx.x * 256 + threadIdx.x;  // 8192
  const int d = t >> 7, c = t & 127;
  float s = Wl[d * 128 + c];
  for (int e = 0; e < 128; e++)
    s = fmaf(W2[d * 128 + e] - W2[(64 + d) * 128 + e], Wl[(64 + e) * 128 + c], s);
  Bc[d * 128 + c] = s;
  Bc[(64 + 2 * d) * 128 + c] = Wl[(64 + 2 * d) * 128 + c];
  Bc[(64 + 2 * d + 1) * 128 + c] = Wl[(64 + 2 * d + 1) * 128 + c];
  if (d == 0) {
    float sb = bl[c];
    for (int e = 0; e < 128; e++) sb = fmaf(b2[e], Wl[(64 + e) * 128 + c], sb);
    cb[c] = sb;
  }
}

// ---------------------------------------------------------------------------
// Final fused: AT = [x1^T ; maxgather(v)^T], GEMM with Bc, per-tile max.
// XCD swizzle (R13): cloud = blockIdx & 31 -> one cloud's 16 tiles share
// blockIdx mod 8 (one XCD) -> v gather hits that XCD's L2 (R12 showed 127 MB
// FETCH for a 27 MB input = 8-way cross-XCD re-fetch of v).
// ---------------------------------------------------------------------------
#define ATS 72
#define BSS 132
__global__ __launch_bounds__(256) void kgemm(const float* __restrict__ x1,
                                             const float* __restrict__ v,
                                             const int* __restrict__ idx,
                                             const float* __restrict__ Bc,
                                             float* __restrict__ partial) {
  __shared__ float AT[192 * ATS];
  __shared__ float BS[16 * BSS];
  int* idxs = (int*)BS;
  const int tid = threadIdx.x;
  const int cloud = blockIdx.x & 31;  // XCD-local cloud assignment
  const int mb = blockIdx.x >> 5;
  const int pbase = cloud * 1024 + mb * 64;

#pragma unroll
  for (int r = 0; r < 5; r++) {
    int id = r * 256 + tid;
    idxs[id] = idx[(size_t)pbase * NK + id];
  }
#pragma unroll
  for (int r = 0; r < 16; r++) {
    int id = r * 256 + tid;
    int m = id >> 6, k = id & 63;
    AT[k * ATS + m] = x1[(size_t)(pbase + m) * 64 + k];
  }
  __syncthreads();
#pragma unroll
  for (int r = 0; r < 32; r++) {
    int id = r * 256 + tid;
    int m = id >> 7, kk = id & 127;
    const int* ip = &idxs[m * NK];
    float mx = -FLT_MAX;
#pragma unroll
    for (int k = 0; k < NK; k++) mx = fmaxf(mx, v[(size_t)ip[k] * 128 + kk]);
    AT[(64 + kk) * ATS + m] = mx;
  }
  __syncthreads();

  const int tr = tid >> 4, tc = tid & 15;
  float acc[4][8];
#pragma unroll
  for (int i = 0; i < 4; i++)
#pragma unroll
    for (int n = 0; n < 8; n++) acc[i][n] = 0.f;
  for (int kc = 0; kc < 12; kc++) {
#pragma unroll
    for (int r = 0; r < 8; r++) {
      int id = r * 256 + tid;
      int row = id >> 7, col = id & 127;
      BS[row * BSS + col] = Bc[(size_t)(kc * 16 + row) * 128 + col];
    }
    __syncthreads();
#pragma unroll
    for (int k = 0; k < 16; k++) {
      int kg = kc * 16 + k;
      float4 a = *(const float4*)&AT[kg * ATS + tr * 4];
      float4 b0 = *(const float4*)&BS[k * BSS + tc * 8];
      float4 b1 = *(const float4*)&BS[k * BSS + tc * 8 + 4];
      float av[4] = {a.x, a.y, a.z, a.w};
      float bv[8] = {b0.x, b0.y, b0.z, b0.w, b1.x, b1.y, b1.z, b1.w};
#pragma unroll
      for (int i = 0; i < 4; i++)
#pragma unroll
        for (int n = 0; n < 8; n++) acc[i][n] = fmaf(av[i], bv[n], acc[i][n]);
    }
    __syncthreads();
  }
#pragma unroll
  for (int n = 0; n < 8; n++) {
    float m4 = fmaxf(fmaxf(acc[0][n], acc[1][n]), fmaxf(acc[2][n], acc[3][n]));
    BS[tr * BSS + tc * 8 + n] = m4;
  }
  __syncthreads();
  if (tid < 128) {
    float m = -FLT_MAX;
#pragma unroll
    for (int rr = 0; rr < 16; rr++) m = fmaxf(m, BS[rr * BSS + tid]);
    partial[(size_t)(cloud * 16 + mb) * 128 + tid] = m;
  }
}

__global__ __launch_bounds__(256) void kred(const float* __restrict__ partial,
                                            const float* __restrict__ cb,
                                            float* __restrict__ out) {
  int t = blockIdx.x * 256 + threadIdx.x;  // 4096
  int b = t >> 7, c = t & 127;
  float m = -FLT_MAX;
#pragma unroll
  for (int mb = 0; mb < 16; mb++) m = fmaxf(m, partial[(size_t)(b * 16 + mb) * 128 + c]);
  out[t] = m + cb[c];
}

// ---------------------------------------------------------------------------
extern "C" void kernel_launch(void* const* d_in, const int* in_sizes, int n_in,
                              void* d_out, int out_size, void* d_ws, size_t ws_size,
                              hipStream_t stream) {
  const float* pos = (const float*)d_in[0];
  const float* W1a = (const float*)d_in[1];
  const float* b1a = (const float*)d_in[2];
  const float* g1 = (const float*)d_in[3];
  const float* be1 = (const float*)d_in[4];
  const float* W1b = (const float*)d_in[5];
  const float* b1b = (const float*)d_in[6];
  const float* W2 = (const float*)d_in[7];
  const float* b2 = (const float*)d_in[8];
  const float* Wl = (const float*)d_in[9];
  const float* bl = (const float*)d_in[10];
  float* out = (float*)d_out;

  // Base workspace (floats). D-matrix chunk after it.
  float* ws = (float*)d_ws;
  float* x1 = ws;                                     // 2,097,152
  float* v = ws + 2097152;                            // 4,194,304
  int* idx = (int*)(ws + 6291456);                    // 655,360
  float* d2b = ws + 6946816;                          // 32,768
  double* Spart = (double*)(ws + 6979584);            // 128*42 doubles = 10,752 slots
  float* Bc = ws + 6990336;                           // 24,576
  float* cb = ws + 7014912;                           // 128
  float* ss = ws + 7015040;                           // 128
  unsigned short* Bh = (unsigned short*)(ws + 7015168);  // 4096 ushort = 2048 fl
  unsigned short* Bl = (unsigned short*)(ws + 7017216);  // 4096 ushort = 2048 fl
  float* partial = ws + 7019264;                      // 65,536 -> end 7,084,800
  const size_t base = 7084800;
  float* D = ws + base;

  if (ws_size < base * sizeof(float)) return;  // fail soft

  // D chunk: prefer the largest power-of-2 cloud count that fits (<= 32);
  // nc=32 -> single kdist+kselect pair per layer (fewest dispatches).
  size_t avail = ws_size / sizeof(float) - base;
  int nc = 0;
  for (int c = 32; c >= 1; c >>= 1)
    if ((size_t)c * 1024 * 1024 <= avail) {
      nc = c;
      break;
    }

  // --- layer 1: kNN on pos (3D) ---
  kd2<<<128, 256, 0, stream>>>(pos, 3, d2b);
  if (nc > 0) {
    for (int c0 = 0; c0 < NB; c0 += nc) {
      kdist<3><<<nc * 64, 256, 0, stream>>>(pos, d2b, c0, nc, D);
      kselect<<<nc * 256, 256, 0, stream>>>(D, c0, idx);
    }
  } else {
    kknn<3><<<512, 256, 0, stream>>>(pos, d2b, idx);
  }

  // --- EdgeConv1 (analytic BN + MFMA edge-GEMM) ---
  kstats<<<128, 256, 0, stream>>>(pos, idx, Spart);
  kbn<<<1, 256, 0, stream>>>(Spart, W1a, b1a, g1, be1, W1b, ss, Bh, Bl);
  kec1<<<NPTS / EC1P, 256, 0, stream>>>(pos, idx, ss, W1a, b1a, Bh, Bl, b1b, x1);

  // --- layer 2: kNN on x1 (64D) ---
  kd2<<<128, 256, 0, stream>>>(x1, 64, d2b);
  if (nc > 0) {
    for (int c0 = 0; c0 < NB; c0 += nc) {
      kdist<64><<<nc * 64, 256, 0, stream>>>(x1, d2b, c0, nc, D);
      kselect<<<nc * 256, 256, 0, stream>>>(D, c0, idx);
    }
  } else {
    kknn<64><<<512, 256, 0, stream>>>(x1, d2b, idx);
  }

  // --- EdgeConv2 factored + fused final linear + pool ---
  kv<<<512, 256, 0, stream>>>(x1, W2, v);
  kprep<<<32, 256, 0, stream>>>(W2, Wl, b2, bl, Bc, cb);
  kgemm<<<512, 256, 0, stream>>>(x1, v, idx, Bc, partial);
  kred<<<16, 256, 0, stream>>>(partial, cb, out);
}

// Round 14
// 371.996 us; speedup vs baseline: 1.3531x; 1.0570x over previous
//
#include <hip/hip_runtime.h>
#include <cfloat>
#include <cstdint>

#define NB 32
#define NP 1024
#define NK 20
#define NPTS 32768  // NB*NP

typedef __attribute__((ext_vector_type(8))) short bf16x8;
typedef __attribute__((ext_vector_type(4))) float f32x4;

__device__ __forceinline__ unsigned bf16rne(float v) {
  const unsigned u = __float_as_uint(v);
  return (u + 0x7fffu + ((u >> 16) & 1u)) >> 16;
}

// ---------------------------------------------------------------------------
// d2[p] = sum x^2 (fp32 exact).
// ---------------------------------------------------------------------------
__global__ __launch_bounds__(256) void kd2(const float* __restrict__ x, int dim,
                                           float* __restrict__ d2) {
  int p = blockIdx.x * 256 + threadIdx.x;
  if (p >= NPTS) return;
  if (dim == 64) {
    const float4* xr = (const float4*)(x + (size_t)p * 64);
    float s = 0.f;
#pragma unroll
    for (int dq = 0; dq < 16; dq++) {
      float4 v = xr[dq];
      s = fmaf(v.x, v.x, s);
      s = fmaf(v.y, v.y, s);
      s = fmaf(v.z, v.z, s);
      s = fmaf(v.w, v.w, s);
    }
    d2[p] = s;
  } else {
    float s = 0.f;
#pragma unroll
    for (int d = 0; d < 3; d++) {
      float v = x[p * 3 + d];
      s = fmaf(v, v, s);
    }
    d2[p] = s;
  }
}

// ---------------------------------------------------------------------------
// kxprep: convert x1 (32768x64 fp32) into MFMA fragment order, bf16 hi/lo.
// Fragment mapping (HW-validated by kec1 R12): element (point p, k) lives at
// frag tile tg=p>>4, kstep ks=k>>5, lane=((k&31)>>3)<<4 | (p&15), j=k&7:
//   off = ((tg*2+ks)*64 + lane)*8 + j.
// Same array serves A (rows) and B (cols) operands of S = X·X^T.
// Thread = one (p, k-octet): 32B coalesced read, 2x16B writes.
// ---------------------------------------------------------------------------
__global__ __launch_bounds__(256) void kxprep(const float* __restrict__ x,
                                              unsigned short* __restrict__ Xh,
                                              unsigned short* __restrict__ Xl) {
  const int t = blockIdx.x * 256 + threadIdx.x;  // 262144
  const int p = t >> 3, g = t & 7;               // k = g*8 + j
  const float4* xr = (const float4*)(x + (size_t)p * 64 + g * 8);
  const float4 v0 = xr[0];
  const float4 v1 = xr[1];
  const float vv[8] = {v0.x, v0.y, v0.z, v0.w, v1.x, v1.y, v1.z, v1.w};
  unsigned short h[8], l[8];
#pragma unroll
  for (int j = 0; j < 8; j++) {
    const float z = vv[j];
    const unsigned u = __float_as_uint(z);
    const unsigned hb = (u + 0x7fffu + ((u >> 16) & 1u)) & 0xffff0000u;
    h[j] = (unsigned short)(hb >> 16);
    l[j] = (unsigned short)bf16rne(z - __uint_as_float(hb));
  }
  const int off = (((p >> 4) * 2 + (g >> 2)) * 64 + ((g & 3) << 4) + (p & 15)) * 8;
  *(uint4*)&Xh[off] = *(const uint4*)&h[0];
  *(uint4*)&Xl[off] = *(const uint4*)&l[0];
}

// ---------------------------------------------------------------------------
// kdistm: MFMA distance matrix for dim=64 (bf16x3 split, fp32 accum).
// Block = 128x128 tile; wave = 32 rows x 128 cols = 2 mt x 8 nt C-tiles.
// Frags read straight from global (L2; XCD-local via cloud swizzle); no LDS.
// dist = fmaf(-2, S, d2r + d2c); added error ~4e-5 abs — an order below the
// x1 bf16 noise already flowing into these distances (R12 passed 1.95e-3).
// ---------------------------------------------------------------------------
__global__ __launch_bounds__(256) void kdistm(const unsigned short* __restrict__ Xh,
                                              const unsigned short* __restrict__ Xl,
                                              const float* __restrict__ d2,
                                              int c0, int nc, float* __restrict__ D) {
  const int lane = threadIdx.x & 63;
  const int w = threadIdx.x >> 6;
  const int cloud = blockIdx.x % nc;  // XCD-local
  const int t = blockIdx.x / nc;
  const int tr0 = (t >> 3) * 128, tc0 = (t & 7) * 128;
  const int cb = (c0 + cloud) * 1024;
  const int rw = tr0 + w * 32;  // this wave's row base (local)

  // A-frags for the wave's 2 row-tiles
  bf16x8 Ah[2][2], Al[2][2];
#pragma unroll
  for (int mt = 0; mt < 2; mt++)
#pragma unroll
    for (int ks = 0; ks < 2; ks++) {
      const int tg = (cb + rw + mt * 16) >> 4;
      const size_t base = ((size_t)(tg * 2 + ks) * 64 + lane) * 8;
      Ah[mt][ks] = *(const bf16x8*)&Xh[base];
      Al[mt][ks] = *(const bf16x8*)&Xl[base];
    }
  float d2r[2][4];
#pragma unroll
  for (int mt = 0; mt < 2; mt++)
#pragma unroll
    for (int r = 0; r < 4; r++)
      d2r[mt][r] = d2[cb + rw + mt * 16 + (lane >> 4) * 4 + r];

  for (int nt = 0; nt < 8; nt++) {
    const int cg = cb + tc0 + nt * 16;
    bf16x8 Bh2[2], Bl2[2];
#pragma unroll
    for (int ks = 0; ks < 2; ks++) {
      const int tg = cg >> 4;
      const size_t base = ((size_t)(tg * 2 + ks) * 64 + lane) * 8;
      Bh2[ks] = *(const bf16x8*)&Xh[base];
      Bl2[ks] = *(const bf16x8*)&Xl[base];
    }
    const float d2c = d2[cg + (lane & 15)];
#pragma unroll
    for (int mt = 0; mt < 2; mt++) {
      f32x4 C = {0.f, 0.f, 0.f, 0.f};
      C = __builtin_amdgcn_mfma_f32_16x16x32_bf16(Ah[mt][0], Bh2[0], C, 0, 0, 0);
      C = __builtin_amdgcn_mfma_f32_16x16x32_bf16(Ah[mt][0], Bl2[0], C, 0, 0, 0);
      C = __builtin_amdgcn_mfma_f32_16x16x32_bf16(Al[mt][0], Bh2[0], C, 0, 0, 0);
      C = __builtin_amdgcn_mfma_f32_16x16x32_bf16(Ah[mt][1], Bh2[1], C, 0, 0, 0);
      C = __builtin_amdgcn_mfma_f32_16x16x32_bf16(Ah[mt][1], Bl2[1], C, 0, 0, 0);
      C = __builtin_amdgcn_mfma_f32_16x16x32_bf16(Al[mt][1], Bh2[1], C, 0, 0, 0);
#pragma unroll
      for (int r = 0; r < 4; r++) {
        const int row = cloud * 1024 + rw + mt * 16 + (lane >> 4) * 4 + r;
        const int col = tc0 + nt * 16 + (lane & 15);
        D[(size_t)row * 1024 + col] = fmaf(-2.f, C[r], d2r[mt][r] + d2c);
      }
    }
  }
}

// ---------------------------------------------------------------------------
// kdist: fp32 distance matrix (used for dim=3; trivial compute, write-bound).
// ---------------------------------------------------------------------------
template <int DIM>
__global__ __launch_bounds__(256) void kdist(const float* __restrict__ x,
                                             const float* __restrict__ d2,
                                             int c0, int nc, float* __restrict__ D) {
  constexpr int KC = (DIM == 64) ? 32 : 3;
  __shared__ float As[KC][132];
  __shared__ float Bs[KC][132];
  const int tid = threadIdx.x;
  const int cloud = blockIdx.x % nc;  // XCD-local
  const int t = blockIdx.x / nc;
  const int tr0 = (t >> 3) * 128, tc0 = (t & 7) * 128;
  const int cb = (c0 + cloud) * 1024;
  const int tr = tid >> 4, tc = tid & 15;

  float acc[8][8];
#pragma unroll
  for (int i = 0; i < 8; i++)
#pragma unroll
    for (int j = 0; j < 8; j++) acc[i][j] = 0.f;

  for (int kc = 0; kc < DIM; kc += KC) {
    __syncthreads();
    if constexpr (DIM == 64) {
      const int row = tid >> 1, seg = tid & 1;
      const float4* sa = (const float4*)(x + (size_t)(cb + tr0 + row) * 64 + kc + seg * 16);
      const float4* sb = (const float4*)(x + (size_t)(cb + tc0 + row) * 64 + kc + seg * 16);
#pragma unroll
      for (int i = 0; i < 4; i++) {
        float4 va = sa[i];
        float4 vb = sb[i];
        const int k0 = seg * 16 + i * 4;
        As[k0 + 0][row] = va.x;
        As[k0 + 1][row] = va.y;
        As[k0 + 2][row] = va.z;
        As[k0 + 3][row] = va.w;
        Bs[k0 + 0][row] = vb.x;
        Bs[k0 + 1][row] = vb.y;
        Bs[k0 + 2][row] = vb.z;
        Bs[k0 + 3][row] = vb.w;
      }
    } else {
      if (tid < 128) {
#pragma unroll
        for (int d = 0; d < 3; d++) {
          As[d][tid] = x[(size_t)(cb + tr0 + tid) * 3 + d];
          Bs[d][tid] = x[(size_t)(cb + tc0 + tid) * 3 + d];
        }
      }
    }
    __syncthreads();
#pragma unroll
    for (int k = 0; k < KC; k++) {
      float a[8], b[8];
      *(float4*)&a[0] = *(const float4*)&As[k][tr * 8];
      *(float4*)&a[4] = *(const float4*)&As[k][tr * 8 + 4];
      *(float4*)&b[0] = *(const float4*)&Bs[k][tc * 8];
      *(float4*)&b[4] = *(const float4*)&Bs[k][tc * 8 + 4];
#pragma unroll
      for (int i = 0; i < 8; i++)
#pragma unroll
        for (int j = 0; j < 8; j++) acc[i][j] = fmaf(a[i], b[j], acc[i][j]);
    }
  }
  float d2r[8], d2c[8];
#pragma unroll
  for (int i = 0; i < 8; i++) d2r[i] = d2[cb + tr0 + tr * 8 + i];
#pragma unroll
  for (int j = 0; j < 8; j++) d2c[j] = d2[cb + tc0 + tc * 8 + j];
#pragma unroll
  for (int i = 0; i < 8; i++) {
    float o[8];
#pragma unroll
    for (int j = 0; j < 8; j++) o[j] = fmaf(-2.f, acc[i][j], d2r[i] + d2c[j]);
    float* dst = &D[(size_t)(cloud * 1024 + tr0 + tr * 8 + i) * 1024 + tc0 + tc * 8];
    *(float4*)&dst[0] = *(const float4*)&o[0];
    *(float4*)&dst[4] = *(const float4*)&o[4];
  }
}

// ---------------------------------------------------------------------------
// kselect: exact top-20 via pivot selection (keys distinct by construction).
// ---------------------------------------------------------------------------
__global__ __launch_bounds__(256) void kselect(const float* __restrict__ D,
                                               int c0, int* __restrict__ idxo) {
  __shared__ unsigned long long lw[4][64];
  const int lane = threadIdx.x & 63;
  const int sub = threadIdx.x >> 6;
  const int pchunk = blockIdx.x * 4 + sub;  // point within chunk
  const int pg = c0 * 1024 + pchunk;        // global point
  const int gbase = (pg >> 10) << 10;       // cloud base (global)

  unsigned long long key[16];
  const float4* dr = (const float4*)(D + (size_t)pchunk * 1024 + lane * 4);
#pragma unroll
  for (int i = 0; i < 4; i++) {
    float4 d4 = dr[i * 64];  // q = i*256 + lane*4 ..+3
    float dv[4] = {d4.x, d4.y, d4.z, d4.w};
#pragma unroll
    for (int j = 0; j < 4; j++) {
      unsigned int u = __float_as_uint(dv[j]);
      u ^= (((int)u >> 31) | 0x80000000u);  // sortable transform
      key[i * 4 + j] = ((unsigned long long)u << 10) | (unsigned)(i * 256 + lane * 4 + j);
    }
  }

  unsigned long long mn = key[0], mx = key[0];
#pragma unroll
  for (int i = 1; i < 16; i++) {
    mn = key[i] < mn ? key[i] : mn;
    mx = key[i] > mx ? key[i] : mx;
  }
#pragma unroll
  for (int s = 1; s < 64; s <<= 1) {
    unsigned long long a = __shfl_xor(mn, s, 64);
    unsigned long long b = __shfl_xor(mx, s, 64);
    mn = a < mn ? a : mn;
    mx = b > mx ? b : mx;
  }
  unsigned long long lo = mn, hi = mx + 1, mid = hi;
  bool found = false;
  for (int it = 0; it < 48 && !found; ++it) {
    unsigned long long m2 = lo + ((hi - lo) >> 1);
    int cnt = 0;
#pragma unroll
    for (int i = 0; i < 16; i++) cnt += (key[i] < m2) ? 1 : 0;
#pragma unroll
    for (int s = 1; s < 64; s <<= 1) cnt += __shfl_xor(cnt, s, 64);
    if (cnt < 20)
      lo = m2;
    else if (cnt > 63)
      hi = m2;
    else {
      mid = m2;
      found = true;
    }
  }

  unsigned int mask = 0;
#pragma unroll
  for (int i = 0; i < 16; i++) mask |= (key[i] < mid) ? (1u << i) : 0u;
  const int lc = __popc(mask);
  int x = lc;
#pragma unroll
  for (int s = 1; s < 64; s <<= 1) {
    int y = __shfl_up(x, s, 64);
    if (lane >= s) x += y;
  }
  int off = x - lc;                    // exclusive prefix
  const int ctot = __shfl(x, 63, 64);  // total candidates
  const int c = ctot < 64 ? ctot : 64;
  unsigned long long* w = lw[sub];
#pragma unroll
  for (int i = 0; i < 16; i++) {
    if ((mask & (1u << i)) && off < 64) {
      w[off] = key[i];
      off++;
    }
  }
  __builtin_amdgcn_wave_barrier();

  const unsigned long long K = w[lane < c ? lane : 0];
  int rank = 0;
  for (int m = 0; m < c; m++) {
    const unsigned long long Km = w[m];  // broadcast read
    rank += (K > Km) ? 1 : 0;
  }
  if (lane < c && rank < NK)
    idxo[(size_t)pg * NK + rank] = gbase + (int)(K & 1023u);
}

// ---------------------------------------------------------------------------
// FALLBACK kNN (used only if ws_size can't fit a 1-cloud distance matrix).
// ---------------------------------------------------------------------------
template <int DIM>
__global__ __launch_bounds__(256) void kknn(const float* __restrict__ x,
                                            const float* __restrict__ d2,
                                            int* __restrict__ idxo) {
  constexpr int STR = (DIM == 64) ? 68 : 4;
  __shared__ float smem[10240];
  float* tile = smem;
  float* dt = smem + 64 * STR;
  float* mD = smem;
  int* mI = (int*)(smem + 5120);

  const int tid = threadIdx.x;
  const int pt = tid & 63;
  const int qt = tid >> 6;
  const int cloud = blockIdx.x >> 4;
  const int blk = blockIdx.x & 15;
  const int p = cloud * 1024 + blk * 64 + pt;
  const int cbase = cloud * 1024;

  float xp[DIM];
#pragma unroll
  for (int d = 0; d < DIM; d++) xp[d] = x[(size_t)p * DIM + d];
  const float d2p = d2[p];

  float bd[NK];
  int bi[NK];
#pragma unroll
  for (int s = 0; s < NK; s++) {
    bd[s] = FLT_MAX;
    bi[s] = 0x7fffffff;
  }
  float wd = FLT_MAX;
  int wi = 0x7fffffff;
  int wsl = 0;

  for (int t = 0; t < 16; t++) {
    __syncthreads();
    if (tid < 64) {
#pragma unroll
      for (int d = 0; d < DIM; d++) tile[tid * STR + d] = x[(size_t)(cbase + t * 64 + tid) * DIM + d];
      dt[tid] = d2[cbase + t * 64 + tid];
    }
    __syncthreads();
    for (int jj = 0; jj < 16; jj++) {
      const int j = jj * 4 + qt;
      float s = 0.f;
#pragma unroll
      for (int d = 0; d < DIM; d++) s = fmaf(xp[d], tile[j * STR + d], s);
      const float dist = fmaf(-2.f, s, d2p + dt[j]);
      const int qg = cbase + t * 64 + j;
      const bool ins = (dist < wd) || (dist == wd && qg < wi);
      if (ins) {
#pragma unroll
        for (int sl = 0; sl < NK; sl++)
          if (sl == wsl) {
            bd[sl] = dist;
            bi[sl] = qg;
          }
        wd = bd[0];
        wi = bi[0];
        wsl = 0;
#pragma unroll
        for (int sl = 1; sl < NK; sl++) {
          const bool worse = (bd[sl] > wd) || (bd[sl] == wd && bi[sl] > wi);
          if (worse) {
            wd = bd[sl];
            wi = bi[sl];
            wsl = sl;
          }
        }
      }
    }
  }
  __syncthreads();
#pragma unroll
  for (int s = 0; s < NK; s++) {
    mD[pt * 80 + qt * 20 + s] = bd[s];
    mI[pt * 80 + qt * 20 + s] = bi[s];
  }
  __syncthreads();
  if (tid < 128) {
    const int pt2 = tid >> 1, h = tid & 1;
    const int base = pt2 * 80 + h * 40;
    float cd[40];
    int ci[40];
#pragma unroll
    for (int a = 0; a < 40; a++) {
      cd[a] = mD[base + a];
      ci[a] = mI[base + a];
    }
    int rank[40];
#pragma unroll
    for (int a = 0; a < 40; a++) rank[a] = 0;
#pragma unroll
    for (int a = 0; a < 40; a++)
#pragma unroll
      for (int b = a + 1; b < 40; b++) {
        const bool abet = (cd[a] < cd[b]) || (cd[a] == cd[b] && ci[a] < ci[b]);
        if (abet)
          rank[b]++;
        else
          rank[a]++;
      }
#pragma unroll
    for (int a = 0; a < 40; a++)
      if (rank[a] < NK) {
        mD[base + rank[a]] = cd[a];
        mI[base + rank[a]] = ci[a];
      }
  }
  __syncthreads();
  if (tid < 64) {
    const int base = tid * 80;
    float cd[40];
    int ci[40];
#pragma unroll
    for (int a = 0; a < 20; a++) {
      cd[a] = mD[base + a];
      ci[a] = mI[base + a];
      cd[20 + a] = mD[base + 40 + a];
      ci[20 + a] = mI[base + 40 + a];
    }
    int rank[40];
#pragma unroll
    for (int a = 0; a < 40; a++) rank[a] = 0;
#pragma unroll
    for (int a = 0; a < 40; a++)
#pragma unroll
      for (int b = a + 1; b < 40; b++) {
        const bool abet = (cd[a] < cd[b]) || (cd[a] == cd[b] && ci[a] < ci[b]);
        if (abet)
          rank[b]++;
        else
          rank[a]++;
      }
    const int po = cloud * 1024 + blk * 64 + tid;
#pragma unroll
    for (int a = 0; a < 40; a++)
      if (rank[a] < NK) idxo[(size_t)po * NK + rank[a]] = ci[a];
  }
}

// ---------------------------------------------------------------------------
// Edge moments, atomic-free.
// ---------------------------------------------------------------------------
__global__ __launch_bounds__(256) void kstats(const float* __restrict__ pos,
                                              const int* __restrict__ idx,
                                              double* __restrict__ Spart) {
  __shared__ float red[4][42];
  const int tid = threadIdx.x;
  const int w = tid >> 6;
  int p = blockIdx.x * 256 + tid;
  float xi0 = pos[p * 3], xi1 = pos[p * 3 + 1], xi2 = pos[p * 3 + 2];
  float s1[6];
  float s2[36];
#pragma unroll
  for (int a = 0; a < 6; a++) s1[a] = 0.f;
#pragma unroll
  for (int a = 0; a < 36; a++) s2[a] = 0.f;
  for (int k = 0; k < NK; k++) {
    int j = idx[p * NK + k];
    float e[6];
    e[0] = xi0;
    e[1] = xi1;
    e[2] = xi2;
    e[3] = pos[j * 3] - xi0;
    e[4] = pos[j * 3 + 1] - xi1;
    e[5] = pos[j * 3 + 2] - xi2;
#pragma unroll
    for (int a = 0; a < 6; a++) {
      s1[a] += e[a];
#pragma unroll
      for (int b = 0; b < 6; b++) s2[a * 6 + b] = fmaf(e[a], e[b], s2[a * 6 + b]);
    }
  }
#pragma unroll
  for (int a = 0; a < 6; a++) {
#pragma unroll
    for (int m = 1; m < 64; m <<= 1) s1[a] += __shfl_xor(s1[a], m, 64);
  }
#pragma unroll
  for (int a = 0; a < 36; a++) {
#pragma unroll
    for (int m = 1; m < 64; m <<= 1) s2[a] += __shfl_xor(s2[a], m, 64);
  }
  if ((tid & 63) == 0) {
#pragma unroll
    for (int a = 0; a < 6; a++) red[w][a] = s1[a];
#pragma unroll
    for (int a = 0; a < 36; a++) red[w][6 + a] = s2[a];
  }
  __syncthreads();
  if (tid < 42) {
    double t = (double)red[0][tid] + (double)red[1][tid] + (double)red[2][tid] +
               (double)red[3][tid];
    Spart[(size_t)blockIdx.x * 42 + tid] = t;
  }
}

// ---------------------------------------------------------------------------
// kbn: stats reduce -> BN scale/shift; W1b pre-swizzle to B-frag bf16 hi/lo.
// ---------------------------------------------------------------------------
__global__ void kbn(const double* __restrict__ Spart, const float* __restrict__ W1a,
                    const float* __restrict__ b1a, const float* __restrict__ g1,
                    const float* __restrict__ be1, const float* __restrict__ W1b,
                    float* __restrict__ ss, unsigned short* __restrict__ Bh,
                    unsigned short* __restrict__ Bl) {
  __shared__ double S[42];
  const int c = threadIdx.x;  // 256 threads
  if (c < 42) {
    double t = 0.0;
    for (int b = 0; b < 128; b++) t += Spart[(size_t)b * 42 + c];
    S[c] = t;
  }
  for (int t = c; t < 4096; t += 256) {
    const int j = t & 7, L = (t >> 3) & 63, f = t >> 9;  // f = nt*2+ks
    const int nt = f >> 1, ks = f & 1;
    const int k = ks * 32 + (L >> 4) * 8 + j;
    const int n = nt * 16 + (L & 15);
    const float wv = W1b[k * 64 + n];
    const unsigned u = __float_as_uint(wv);
    const unsigned hb = (u + 0x7fffu + ((u >> 16) & 1u)) & 0xffff0000u;  // RNE bf16
    Bh[t] = (unsigned short)(hb >> 16);
    Bl[t] = (unsigned short)bf16rne(wv - __uint_as_float(hb));
  }
  __syncthreads();
  if (c < 64) {
    double w[6];
#pragma unroll
    for (int d = 0; d < 6; d++) w[d] = (double)W1a[d * 64 + c];
    double b = (double)b1a[c];
    const double invN = 1.0 / (double)((size_t)NPTS * NK);
    double m1 = 0.0;
#pragma unroll
    for (int d = 0; d < 6; d++) m1 += w[d] * S[d];
    m1 *= invN;
    double q = 0.0;
#pragma unroll
    for (int a = 0; a < 6; a++)
#pragma unroll
      for (int d = 0; d < 6; d++) q += w[a] * w[d] * S[6 + a * 6 + d];
    q *= invN;
    double mu = m1 + b;
    double eh2 = q + 2.0 * b * m1 + b * b;
    double var = eh2 - mu * mu;
    if (var < 0.0) var = 0.0;
    double inv = 1.0 / sqrt(var + 1e-5);
    double sc = (double)g1[c] * inv;
    ss[c] = (float)sc;
    ss[64 + c] = (float)((double)be1[c] - mu * sc);
  }
}

// ---------------------------------------------------------------------------
// EdgeConv1 fused — MFMA (verified R12: absmax 1.95e-3).
// ---------------------------------------------------------------------------
#define EC1P 8
__global__ __launch_bounds__(256) void kec1(const float* __restrict__ pos,
                                            const int* __restrict__ idx,
                                            const float* __restrict__ ss,
                                            const float* __restrict__ W1a,
                                            const float* __restrict__ b1a,
                                            const unsigned short* __restrict__ Bh,
                                            const unsigned short* __restrict__ Bl,
                                            const float* __restrict__ b1b,
                                            float* __restrict__ x1) {
  __shared__ __align__(16) unsigned short Ah[4][3072];
  __shared__ __align__(16) unsigned short Al[4][3072];
  __shared__ float nbr[4][160];
  const int tid = threadIdx.x;
  const int lane = tid & 63;
  const int w = tid >> 6;
  const int p0 = blockIdx.x * EC1P + w * 2;  // this wave's 2 points

  unsigned short* ah = Ah[w];
  unsigned short* al = Al[w];
  float* nb = nbr[w];

  if (lane < 40) {
    const int j = idx[(size_t)p0 * NK + lane];
    nb[lane * 4 + 0] = pos[j * 3 + 0];
    nb[lane * 4 + 1] = pos[j * 3 + 1];
    nb[lane * 4 + 2] = pos[j * 3 + 2];
  }

  float wdf[3], wbt[3];
#pragma unroll
  for (int d = 0; d < 3; d++) {
    const float top = W1a[d * 64 + lane];
    const float bot = W1a[(3 + d) * 64 + lane];
    wdf[d] = top - bot;
    wbt[d] = bot;
  }
  const float b1 = b1a[lane];
  const float sc = ss[lane];
  const float sh = ss[64 + lane];
  const int lanepart = ((lane >> 5) * 512) + (((lane & 31) >> 3) * 128) + (lane & 7);
  __builtin_amdgcn_wave_barrier();

#pragma unroll
  for (int pp = 0; pp < 2; pp++) {
    const int p = p0 + pp;
    const float xi0 = pos[p * 3], xi1 = pos[p * 3 + 1], xi2 = pos[p * 3 + 2];
    const float pu = fmaf(xi2, wdf[2], fmaf(xi1, wdf[1], fmaf(xi0, wdf[0], b1)));
    for (int k = 0; k < NK; k++) {
      const int row = pp * NK + k;
      const float4 nbv = *(const float4*)&nb[row * 4];  // broadcast
      const float pv = fmaf(nbv.z, wbt[2], fmaf(nbv.y, wbt[1], nbv.x * wbt[0]));
      const float z = fmaxf(fmaf(pu + pv, sc, sh), 0.f);
      const unsigned u = __float_as_uint(z);
      const unsigned hb = (u + 0x7fffu + ((u >> 16) & 1u)) & 0xffff0000u;
      const int off = (row >> 4) * 1024 + (row & 15) * 8 + lanepart;
      ah[off] = (unsigned short)(hb >> 16);
      al[off] = (unsigned short)bf16rne(z - __uint_as_float(hb));
    }
  }
  __builtin_amdgcn_wave_barrier();

  bf16x8 bh[4][2], bl[4][2];
#pragma unroll
  for (int nt = 0; nt < 4; nt++)
#pragma unroll
    for (int ks = 0; ks < 2; ks++) {
      const int base = ((nt * 2 + ks) * 64 + lane) * 8;
      bh[nt][ks] = *(const bf16x8*)&Bh[base];
      bl[nt][ks] = *(const bf16x8*)&Bl[base];
    }

  float pA[4], pB[4];
#pragma unroll
  for (int nt = 0; nt < 4; nt++) {
    pA[nt] = -FLT_MAX;
    pB[nt] = -FLT_MAX;
  }
  const int q4 = (lane >> 4) * 4;

#pragma unroll
  for (int mt = 0; mt < 3; mt++) {
    const bf16x8 a_h0 = *(const bf16x8*)&ah[mt * 1024 + lane * 8];
    const bf16x8 a_l0 = *(const bf16x8*)&al[mt * 1024 + lane * 8];
    const bf16x8 a_h1 = *(const bf16x8*)&ah[mt * 1024 + 512 + lane * 8];
    const bf16x8 a_l1 = *(const bf16x8*)&al[mt * 1024 + 512 + lane * 8];
#pragma unroll
    for (int nt = 0; nt < 4; nt++) {
      f32x4 C = {0.f, 0.f, 0.f, 0.f};
      C = __builtin_amdgcn_mfma_f32_16x16x32_bf16(a_h0, bh[nt][0], C, 0, 0, 0);
      C = __builtin_amdgcn_mfma_f32_16x16x32_bf16(a_h0, bl[nt][0], C, 0, 0, 0);
      C = __builtin_amdgcn_mfma_f32_16x16x32_bf16(a_l0, bh[nt][0], C, 0, 0, 0);
      C = __builtin_amdgcn_mfma_f32_16x16x32_bf16(a_h1, bh[nt][1], C, 0, 0, 0);
      C = __builtin_amdgcn_mfma_f32_16x16x32_bf16(a_h1, bl[nt][1], C, 0, 0, 0);
      C = __builtin_amdgcn_mfma_f32_16x16x32_bf16(a_l1, bh[nt][1], C, 0, 0, 0);
#pragma unroll
      for (int r = 0; r < 4; r++) {
        const int row = mt * 16 + q4 + r;
        const float vv = C[r];
        if (row < NK) pA[nt] = fmaxf(pA[nt], vv);
        if (row >= NK && row < 2 * NK) pB[nt] = fmaxf(pB[nt], vv);
      }
    }
  }
#pragma unroll
  for (int s = 16; s < 64; s <<= 1) {
#pragma unroll
    for (int nt = 0; nt < 4; nt++) {
      pA[nt] = fmaxf(pA[nt], __shfl_xor(pA[nt], s, 64));
      pB[nt] = fmaxf(pB[nt], __shfl_xor(pB[nt], s, 64));
    }
  }
  if (lane < 16) {
#pragma unroll
    for (int nt = 0; nt < 4; nt++) {
      const float bb = b1b[nt * 16 + lane];
      x1[(size_t)p0 * 64 + nt * 16 + lane] = pA[nt] + bb;
      x1[(size_t)(p0 + 1) * 64 + nt * 16 + lane] = pB[nt] + bb;
    }
  }
}

// v[j,c] = x1_j . W2[64+d][c]
__global__ __launch_bounds__(256) void kv(const float* __restrict__ x1,
                                          const float* __restrict__ W2,
                                          float* __restrict__ v) {
  const int c = threadIdx.x & 127;
  const int sub = threadIdx.x >> 7;
  float wv[64];
#pragma unroll
  for (int d = 0; d < 64; d++) wv[d] = W2[(64 + d) * 128 + c];
  const int pbase = blockIdx.x * 64 + sub * 32;
  for (int i = 0; i < 32; i++) {
    const int p = pbase + i;
    const float4* xr = (const float4*)(x1 + (size_t)p * 64);
    float a0 = 0.f, a1 = 0.f;
#pragma unroll
    for (int dq = 0; dq < 16; dq++) {
      float4 xv = xr[dq];
      a0 = fmaf(xv.x, wv[dq * 4 + 0], a0);
      a1 = fmaf(xv.y, wv[dq * 4 + 1], a1);
      a0 = fmaf(xv.z, wv[dq * 4 + 2], a0);
      a1 = fmaf(xv.w, wv[dq * 4 + 3], a1);
    }
    v[(size_t)p * 128 + c] = a0 + a1;
  }
}

// Bc (192x128) and const bias cb (128)
__global__ __launch_bounds__(256) void kprep(const float* __restrict__ W2,
                                             const float* __restrict__ Wl,
                                             const float* __restrict__ b2,
                                             const float* __restrict__ bl,
                                             float* __restrict__ Bc,
                                             float* __restrict__ cb) {
  const int t = blockIdx.x * 256 + threadIdx.x;  // 8192
  const int d = t >> 7, c = t & 127;
  float s = Wl[d * 128 + c];
  for (int e = 0; e < 128; e++)
    s = fmaf(W2[d * 128 + e] - W2[(64 + d) * 128 + e], Wl[(64 + e) * 128 + c], s);
  Bc[d * 128 + c] = s;
  Bc[(64 + 2 * d) * 128 + c] = Wl[(64 + 2 * d) * 128 + c];
  Bc[(64 + 2 * d + 1) * 128 + c] = Wl[(64 + 2 * d + 1) * 128 + c];
  if (d == 0) {
    float sb = bl[c];
    for (int e = 0; e < 128; e++) sb = fmaf(b2[e], Wl[(64 + e) * 128 + c], sb);
    cb[c] = sb;
  }
}

// Final fused: AT = [x1^T ; maxgather(v)^T], GEMM with Bc, per-tile max.
#define ATS 72
#define BSS 132
__global__ __launch_bounds__(256) void kgemm(const float* __restrict__ x1,
                                             const float* __restrict__ v,
                                             const int* __restrict__ idx,
                                             const float* __restrict__ Bc,
                                             float* __restrict__ partial) {
  __shared__ float AT[192 * ATS];
  __shared__ float BS[16 * BSS];
  int* idxs = (int*)BS;
  const int tid = threadIdx.x;
  const int cloud = blockIdx.x & 31;  // XCD-local cloud assignment
  const int mb = blockIdx.x >> 5;
  const int pbase = cloud * 1024 + mb * 64;

#pragma unroll
  for (int r = 0; r < 5; r++) {
    int id = r * 256 + tid;
    idxs[id] = idx[(size_t)pbase * NK + id];
  }
#pragma unroll
  for (int r = 0; r < 16; r++) {
    int id = r * 256 + tid;
    int m = id >> 6, k = id & 63;
    AT[k * ATS + m] = x1[(size_t)(pbase + m) * 64 + k];
  }
  __syncthreads();
#pragma unroll
  for (int r = 0; r < 32; r++) {
    int id = r * 256 + tid;
    int m = id >> 7, kk = id & 127;
    const int* ip = &idxs[m * NK];
    float mx = -FLT_MAX;
#pragma unroll
    for (int k = 0; k < NK; k++) mx = fmaxf(mx, v[(size_t)ip[k] * 128 + kk]);
    AT[(64 + kk) * ATS + m] = mx;
  }
  __syncthreads();

  const int tr = tid >> 4, tc = tid & 15;
  float acc[4][8];
#pragma unroll
  for (int i = 0; i < 4; i++)
#pragma unroll
    for (int n = 0; n < 8; n++) acc[i][n] = 0.f;
  for (int kc = 0; kc < 12; kc++) {
#pragma unroll
    for (int r = 0; r < 8; r++) {
      int id = r * 256 + tid;
      int row = id >> 7, col = id & 127;
      BS[row * BSS + col] = Bc[(size_t)(kc * 16 + row) * 128 + col];
    }
    __syncthreads();
#pragma unroll
    for (int k = 0; k < 16; k++) {
      int kg = kc * 16 + k;
      float4 a = *(const float4*)&AT[kg * ATS + tr * 4];
      float4 b0 = *(const float4*)&BS[k * BSS + tc * 8];
      float4 b1 = *(const float4*)&BS[k * BSS + tc * 8 + 4];
      float av[4] = {a.x, a.y, a.z, a.w};
      float bv[8] = {b0.x, b0.y, b0.z, b0.w, b1.x, b1.y, b1.z, b1.w};
#pragma unroll
      for (int i = 0; i < 4; i++)
#pragma unroll
        for (int n = 0; n < 8; n++) acc[i][n] = fmaf(av[i], bv[n], acc[i][n]);
    }
    __syncthreads();
  }
#pragma unroll
  for (int n = 0; n < 8; n++) {
    float m4 = fmaxf(fmaxf(acc[0][n], acc[1][n]), fmaxf(acc[2][n], acc[3][n]));
    BS[tr * BSS + tc * 8 + n] = m4;
  }
  __syncthreads();
  if (tid < 128) {
    float m = -FLT_MAX;
#pragma unroll
    for (int rr = 0; rr < 16; rr++) m = fmaxf(m, BS[rr * BSS + tid]);
    partial[(size_t)(cloud * 16 + mb) * 128 + tid] = m;
  }
}

__global__ __launch_bounds__(256) void kred(const float* __restrict__ partial,
                                            const float* __restrict__ cb,
                                            float* __restrict__ out) {
  int t = blockIdx.x * 256 + threadIdx.x;  // 4096
  int b = t >> 7, c = t & 127;
  float m = -FLT_MAX;
#pragma unroll
  for (int mb = 0; mb < 16; mb++) m = fmaxf(m, partial[(size_t)(b * 16 + mb) * 128 + c]);
  out[t] = m + cb[c];
}

// ---------------------------------------------------------------------------
extern "C" void kernel_launch(void* const* d_in, const int* in_sizes, int n_in,
                              void* d_out, int out_size, void* d_ws, size_t ws_size,
                              hipStream_t stream) {
  const float* pos = (const float*)d_in[0];
  const float* W1a = (const float*)d_in[1];
  const float* b1a = (const float*)d_in[2];
  const float* g1 = (const float*)d_in[3];
  const float* be1 = (const float*)d_in[4];
  const float* W1b = (const float*)d_in[5];
  const float* b1b = (const float*)d_in[6];
  const float* W2 = (const float*)d_in[7];
  const float* b2 = (const float*)d_in[8];
  const float* Wl = (const float*)d_in[9];
  const float* bl = (const float*)d_in[10];
  float* out = (float*)d_out;

  // Base workspace (floats). D-matrix chunk after it.
  float* ws = (float*)d_ws;
  float* x1 = ws;                                        // 2,097,152
  float* v = ws + 2097152;                               // 4,194,304
  int* idx = (int*)(ws + 6291456);                       // 655,360
  float* d2b = ws + 6946816;                             // 32,768
  double* Spart = (double*)(ws + 6979584);               // 10,752
  float* Bc = ws + 6990336;                              // 24,576
  float* cb = ws + 7014912;                              // 128
  float* ss = ws + 7015040;                              // 128
  unsigned short* Bh = (unsigned short*)(ws + 7015168);  // 2048 fl
  unsigned short* Bl = (unsigned short*)(ws + 7017216);  // 2048 fl
  float* partial = ws + 7019264;                         // 65,536
  unsigned short* Xfh = (unsigned short*)(ws + 7084800); // 1,048,576 fl
  unsigned short* Xfl = (unsigned short*)(ws + 8133376); // 1,048,576 fl
  const size_t base = 9181952;
  float* D = ws + base;

  if (ws_size < base * sizeof(float)) return;  // fail soft

  // D chunk: largest power-of-2 cloud count that fits (<= 32).
  size_t avail = ws_size / sizeof(float) - base;
  int nc = 0;
  for (int c = 32; c >= 1; c >>= 1)
    if ((size_t)c * 1024 * 1024 <= avail) {
      nc = c;
      break;
    }

  // --- layer 1: kNN on pos (3D) ---
  kd2<<<128, 256, 0, stream>>>(pos, 3, d2b);
  if (nc > 0) {
    for (int c0 = 0; c0 < NB; c0 += nc) {
      kdist<3><<<nc * 64, 256, 0, stream>>>(pos, d2b, c0, nc, D);
      kselect<<<nc * 256, 256, 0, stream>>>(D, c0, idx);
    }
  } else {
    kknn<3><<<512, 256, 0, stream>>>(pos, d2b, idx);
  }

  // --- EdgeConv1 (analytic BN + MFMA edge-GEMM) ---
  kstats<<<128, 256, 0, stream>>>(pos, idx, Spart);
  kbn<<<1, 256, 0, stream>>>(Spart, W1a, b1a, g1, be1, W1b, ss, Bh, Bl);
  kec1<<<NPTS / EC1P, 256, 0, stream>>>(pos, idx, ss, W1a, b1a, Bh, Bl, b1b, x1);

  // --- layer 2: kNN on x1 (64D) — MFMA distance matrix ---
  kd2<<<128, 256, 0, stream>>>(x1, 64, d2b);
  if (nc > 0) {
    kxprep<<<1024, 256, 0, stream>>>(x1, Xfh, Xfl);
    for (int c0 = 0; c0 < NB; c0 += nc) {
      kdistm<<<nc * 64, 256, 0, stream>>>(Xfh, Xfl, d2b, c0, nc, D);
      kselect<<<nc * 256, 256, 0, stream>>>(D, c0, idx);
    }
  } else {
    kknn<64><<<512, 256, 0, stream>>>(x1, d2b, idx);
  }

  // --- EdgeConv2 factored + fused final linear + pool ---
  kv<<<512, 256, 0, stream>>>(x1, W2, v);
  kprep<<<32, 256, 0, stream>>>(W2, Wl, b2, bl, Bc, cb);
  kgemm<<<512, 256, 0, stream>>>(x1, v, idx, Bc, partial);
  kred<<<16, 256, 0, stream>>>(partial, cb, out);
}